// Round 1
// baseline (12174.410 us; speedup 1.0000x reference)
//
#include <hip/hip_runtime.h>

#define D 64

__global__ __launch_bounds__(256) void axcopy_kernel(float* __restrict__ dst,
                                                     const float* __restrict__ src,
                                                     long long n4, float s) {
  long long i = (long long)blockIdx.x * blockDim.x + threadIdx.x;
  long long stride = (long long)gridDim.x * blockDim.x;
  for (; i < n4; i += stride) {
    float4 v = ((const float4*)src)[i];
    v.x *= s; v.y *= s; v.z *= s; v.w *= s;
    ((float4*)dst)[i] = v;
  }
}

// One edge handled by 16 threads; thread j covers feature dims [4j, 4j+4).
__global__ __launch_bounds__(256) void spmm_atomic_kernel(
    const int* __restrict__ rows, const int* __restrict__ cols,
    const float* __restrict__ vals, const float* __restrict__ feat,
    float* __restrict__ outp, long long ne) {
  long long t = (long long)blockIdx.x * blockDim.x + threadIdx.x;
  long long e = t >> 4;
  if (e >= ne) return;
  int lane = (int)(t & 15);
  int r = rows[e];
  int c = cols[e];
  float v = vals[e];
  const float4 f = *(const float4*)(feat + (long long)c * D + lane * 4);
  float* o = outp + (long long)r * D + lane * 4;
  atomicAdd(o + 0, v * f.x);
  atomicAdd(o + 1, v * f.y);
  atomicAdd(o + 2, v * f.z);
  atomicAdd(o + 3, v * f.w);
}

// One wave (64 lanes) per row: acc[row] += feat[row] / max(||feat[row]||, 1e-12)
__global__ __launch_bounds__(256) void norm_acc_kernel(const float* __restrict__ feat,
                                                       float* __restrict__ acc,
                                                       int nrows) {
  int row = blockIdx.x * 4 + (threadIdx.x >> 6);
  if (row >= nrows) return;
  int lane = threadIdx.x & 63;
  float x = feat[(long long)row * D + lane];
  float s = x * x;
  #pragma unroll
  for (int off = 32; off; off >>= 1) s += __shfl_xor(s, off);
  float n = sqrtf(s);
  float sc = 1.0f / fmaxf(n, 1e-12f);
  acc[(long long)row * D + lane] += x * sc;
}

extern "C" void kernel_launch(void* const* d_in, const int* in_sizes, int n_in,
                              void* d_out, int out_size, void* d_ws, size_t ws_size,
                              hipStream_t stream) {
  const float* learners = (const float*)d_in[0];
  const float* courses  = (const float*)d_in[1];
  const float* concepts = (const float*)d_in[2];
  const int*   cg_rows  = (const int*)d_in[3];
  const int*   cg_cols  = (const int*)d_in[4];
  const float* cg_vals  = (const float*)d_in[5];
  const int*   kg_rows  = (const int*)d_in[6];
  const int*   kg_cols  = (const int*)d_in[7];
  const float* kg_vals  = (const float*)d_in[8];
  const int*   ca_rows  = (const int*)d_in[9];
  const int*   ca_cols  = (const int*)d_in[10];
  const float* ca_vals  = (const float*)d_in[11];

  const long long Lr  = in_sizes[0] / D;  // 100000 learners
  const long long Cr  = in_sizes[1] / D;  // 20000 courses
  const long long Kr  = in_sizes[2] / D;  // 10000 concepts
  const long long Ecg = in_sizes[3];      // 3,000,000
  const long long Ekg = in_sizes[6];      // 4,000,000
  const long long Eca = in_sizes[9];      // 200,000
  const long long Ncg = Lr + Cr;          // 120000
  const long long Nkg = Lr + Kr;          // 110000

  float* out  = (float*)d_out;
  float* buf0 = (float*)d_ws;
  float* buf1 = buf0 + Ncg * D;
  float* acck = buf1 + Ncg * D;   // K x D concept accumulator

  auto axcopy = [&](float* dst, const float* src, long long n, float s) {
    long long n4 = n / 4;
    long long b = (n4 + 255) / 256;
    int blocks = (int)(b < 2048 ? b : 2048);
    hipLaunchKernelGGL(axcopy_kernel, dim3(blocks), dim3(256), 0, stream, dst, src, n4, s);
  };
  auto spmm = [&](const int* r, const int* c, const float* v, const float* f,
                  float* o, long long ne) {
    long long threads = ne * 16;
    int blocks = (int)((threads + 255) / 256);
    hipLaunchKernelGGL(spmm_atomic_kernel, dim3(blocks), dim3(256), 0, stream,
                       r, c, v, f, o, ne);
  };
  auto normacc = [&](const float* f, float* a, long long nrows) {
    int blocks = (int)((nrows + 3) / 4);
    hipLaunchKernelGGL(norm_acc_kernel, dim3(blocks), dim3(256), 0, stream,
                       f, a, (int)nrows);
  };

  // ---------- course-grained view (learner-course graph, Ncg nodes) ----------
  // feat0 in buf0; acc directly in d_out (learners counted twice: once per view)
  axcopy(buf0, learners, Lr * D, 1.f);
  axcopy(buf0 + Lr * D, courses, Cr * D, 1.f);
  axcopy(out, learners, Lr * D, 2.f);               // feat0 contribution of BOTH views
  axcopy(out + Lr * D, courses, Cr * D, 1.f);

  hipMemsetAsync(buf1, 0, (size_t)(Ncg * D) * sizeof(float), stream);
  spmm(cg_rows, cg_cols, cg_vals, buf0, buf1, Ecg); // feat1 = S * feat0
  normacc(buf1, out, Ncg);                          // acc += unit(feat1)

  hipMemsetAsync(buf0, 0, (size_t)(Ncg * D) * sizeof(float), stream);
  spmm(cg_rows, cg_cols, cg_vals, buf1, buf0, Ecg); // feat2 = S * feat1
  normacc(buf0, out, Ncg);                          // acc += unit(feat2)

  // ---------- concept-grained view (learner-concept graph, Nkg nodes) ----------
  axcopy(buf0, learners, Lr * D, 1.f);
  axcopy(buf0 + Lr * D, concepts, Kr * D, 1.f);
  axcopy(acck, concepts, Kr * D, 1.f);              // concept part of feat0

  hipMemsetAsync(buf1, 0, (size_t)(Nkg * D) * sizeof(float), stream);
  spmm(kg_rows, kg_cols, kg_vals, buf0, buf1, Ekg);
  normacc(buf1, out, Lr);                           // learner rows -> d_out
  normacc(buf1 + Lr * D, acck, Kr);                 // concept rows -> acck

  hipMemsetAsync(buf0, 0, (size_t)(Nkg * D) * sizeof(float), stream);
  spmm(kg_rows, kg_cols, kg_vals, buf1, buf0, Ekg);
  normacc(buf0, out, Lr);
  normacc(buf0 + Lr * D, acck, Kr);

  // ---------- aggregate concept features into course rows ----------
  spmm(ca_rows, ca_cols, ca_vals, acck, out + Lr * D, Eca);
}

// Round 2
// 1876.270 us; speedup vs baseline: 6.4886x; 6.4886x over previous
//
#include <hip/hip_runtime.h>

#define D 64

// ============================ element-wise utils ============================

__global__ __launch_bounds__(256) void axcopy_kernel(float* __restrict__ dst,
                                                     const float* __restrict__ src,
                                                     long long n4, float s) {
  long long i = (long long)blockIdx.x * blockDim.x + threadIdx.x;
  long long stride = (long long)gridDim.x * blockDim.x;
  for (; i < n4; i += stride) {
    float4 v = ((const float4*)src)[i];
    v.x *= s; v.y *= s; v.z *= s; v.w *= s;
    ((float4*)dst)[i] = v;
  }
}

__global__ __launch_bounds__(256) void icopy_kernel(int* __restrict__ dst,
                                                    const int* __restrict__ src,
                                                    long long n) {
  long long i = (long long)blockIdx.x * blockDim.x + threadIdx.x;
  long long stride = (long long)gridDim.x * blockDim.x;
  for (; i < n; i += stride) dst[i] = src[i];
}

// ============================ CSR build ============================

__global__ __launch_bounds__(256) void hist_kernel(const int* __restrict__ rows,
                                                   int* __restrict__ cnt, long long ne) {
  long long i = (long long)blockIdx.x * blockDim.x + threadIdx.x;
  long long stride = (long long)gridDim.x * blockDim.x;
  for (; i < ne; i += stride) atomicAdd(&cnt[rows[i]], 1);
}

// exclusive scan of cnt[0..n) -> outp[0..n), tile = 1024 elems/block
__global__ __launch_bounds__(256) void scan1_kernel(const int* __restrict__ cnt,
                                                    int* __restrict__ outp,
                                                    int* __restrict__ partials, int n) {
  __shared__ int lds[256];
  int b = blockIdx.x, t = threadIdx.x;
  int base = b * 1024 + t * 4;
  int v[4]; int s = 0;
  #pragma unroll
  for (int j = 0; j < 4; j++) { int idx = base + j; v[j] = (idx < n) ? cnt[idx] : 0; s += v[j]; }
  lds[t] = s;
  __syncthreads();
  for (int off = 1; off < 256; off <<= 1) {
    int x = (t >= off) ? lds[t - off] : 0;
    __syncthreads();
    lds[t] += x;
    __syncthreads();
  }
  int run = (t == 0) ? 0 : lds[t - 1];
  if (t == 255) partials[b] = lds[255];
  #pragma unroll
  for (int j = 0; j < 4; j++) { int idx = base + j; if (idx < n) outp[idx] = run; run += v[j]; }
}

__global__ __launch_bounds__(256) void scan2_kernel(int* __restrict__ partials, int nb) {
  __shared__ int lds[256];
  int t = threadIdx.x;
  lds[t] = (t < nb) ? partials[t] : 0;
  __syncthreads();
  for (int off = 1; off < 256; off <<= 1) {
    int x = (t >= off) ? lds[t - off] : 0;
    __syncthreads();
    lds[t] += x;
    __syncthreads();
  }
  if (t < nb) partials[t] = (t == 0) ? 0 : lds[t - 1];
}

__global__ __launch_bounds__(256) void scan3_kernel(int* __restrict__ outp,
                                                    const int* __restrict__ partials,
                                                    int n, int total) {
  int b = blockIdx.x, t = threadIdx.x;
  int add = partials[b];
  int base = b * 1024 + t * 4;
  #pragma unroll
  for (int j = 0; j < 4; j++) { int idx = base + j; if (idx < n) outp[idx] += add; }
  if (b == 0 && t == 0) outp[n] = total;
}

__global__ __launch_bounds__(256) void scatter_kernel(const int* __restrict__ rows,
                                                      const int* __restrict__ cols,
                                                      const float* __restrict__ vals,
                                                      int* __restrict__ cursor,
                                                      int2* __restrict__ cv, long long ne) {
  long long e = (long long)blockIdx.x * blockDim.x + threadIdx.x;
  if (e >= ne) return;
  int r = rows[e];
  int p = atomicAdd(&cursor[r], 1);
  cv[p] = make_int2(cols[e], __float_as_int(vals[e]));
}

// ============================ pull SpMM ============================
// One wave per row, lane = feature dim. No atomics: wave owns the row.
// Writes feat_out[row] = sum, and acc += unit(sum) fused (6-step shfl reduce).
__global__ __launch_bounds__(256) void spmm_pull_norm_kernel(
    const int* __restrict__ rowptr, const int2* __restrict__ cv,
    const float* __restrict__ feat, float* __restrict__ feat_out,
    float* __restrict__ accA, float* __restrict__ accB, int split, int nrows) {
  int row = blockIdx.x * 4 + (threadIdx.x >> 6);
  if (row >= nrows) return;
  int lane = threadIdx.x & 63;
  int e0 = rowptr[row], e1 = rowptr[row + 1];
  float s = 0.f;
  int e = e0;
  for (; e + 1 < e1; e += 2) {
    int2 a = cv[e];
    int2 b = cv[e + 1];
    s += __int_as_float(a.y) * feat[(long long)a.x * D + lane];
    s += __int_as_float(b.y) * feat[(long long)b.x * D + lane];
  }
  if (e < e1) {
    int2 a = cv[e];
    s += __int_as_float(a.y) * feat[(long long)a.x * D + lane];
  }
  feat_out[(long long)row * D + lane] = s;
  float q = s * s;
  #pragma unroll
  for (int off = 32; off; off >>= 1) q += __shfl_xor(q, off);
  float sc = 1.0f / fmaxf(sqrtf(q), 1e-12f);
  float* acc = (row < split) ? accA + (long long)row * D
                             : accB + (long long)(row - split) * D;
  acc[lane] += s * sc;
}

// pull SpMM, accumulate raw sum into acc (no norm, no feat_out) — for ca graph
__global__ __launch_bounds__(256) void spmm_pull_acc_kernel(
    const int* __restrict__ rowptr, const int2* __restrict__ cv,
    const float* __restrict__ feat, float* __restrict__ acc, int nrows) {
  int row = blockIdx.x * 4 + (threadIdx.x >> 6);
  if (row >= nrows) return;
  int lane = threadIdx.x & 63;
  int e0 = rowptr[row], e1 = rowptr[row + 1];
  float s = 0.f;
  for (int e = e0; e < e1; ++e) {
    int2 a = cv[e];
    s += __int_as_float(a.y) * feat[(long long)a.x * D + lane];
  }
  acc[(long long)row * D + lane] += s;
}

// ============================ fallback (R1 atomic path) ============================

__global__ __launch_bounds__(256) void spmm_atomic_kernel(
    const int* __restrict__ rows, const int* __restrict__ cols,
    const float* __restrict__ vals, const float* __restrict__ feat,
    float* __restrict__ outp, long long ne) {
  long long t = (long long)blockIdx.x * blockDim.x + threadIdx.x;
  long long e = t >> 4;
  if (e >= ne) return;
  int lane = (int)(t & 15);
  int r = rows[e];
  int c = cols[e];
  float v = vals[e];
  const float4 f = *(const float4*)(feat + (long long)c * D + lane * 4);
  float* o = outp + (long long)r * D + lane * 4;
  atomicAdd(o + 0, v * f.x);
  atomicAdd(o + 1, v * f.y);
  atomicAdd(o + 2, v * f.z);
  atomicAdd(o + 3, v * f.w);
}

__global__ __launch_bounds__(256) void norm_acc_kernel(const float* __restrict__ feat,
                                                       float* __restrict__ acc,
                                                       int nrows) {
  int row = blockIdx.x * 4 + (threadIdx.x >> 6);
  if (row >= nrows) return;
  int lane = threadIdx.x & 63;
  float x = feat[(long long)row * D + lane];
  float s = x * x;
  #pragma unroll
  for (int off = 32; off; off >>= 1) s += __shfl_xor(s, off);
  float sc = 1.0f / fmaxf(sqrtf(s), 1e-12f);
  acc[(long long)row * D + lane] += x * sc;
}

// ============================ launch ============================

extern "C" void kernel_launch(void* const* d_in, const int* in_sizes, int n_in,
                              void* d_out, int out_size, void* d_ws, size_t ws_size,
                              hipStream_t stream) {
  const float* learners = (const float*)d_in[0];
  const float* courses  = (const float*)d_in[1];
  const float* concepts = (const float*)d_in[2];
  const int*   cg_rows  = (const int*)d_in[3];
  const int*   cg_cols  = (const int*)d_in[4];
  const float* cg_vals  = (const float*)d_in[5];
  const int*   kg_rows  = (const int*)d_in[6];
  const int*   kg_cols  = (const int*)d_in[7];
  const float* kg_vals  = (const float*)d_in[8];
  const int*   ca_rows  = (const int*)d_in[9];
  const int*   ca_cols  = (const int*)d_in[10];
  const float* ca_vals  = (const float*)d_in[11];

  const long long Lr  = in_sizes[0] / D;
  const long long Cr  = in_sizes[1] / D;
  const long long Kr  = in_sizes[2] / D;
  const long long Ecg = in_sizes[3];
  const long long Ekg = in_sizes[6];
  const long long Eca = in_sizes[9];
  const long long Ncg = Lr + Cr;
  const long long Nkg = Lr + Kr;

  float* out = (float*)d_out;

  // ---- workspace layout (units: 4-byte words, 16B-aligned chunks) ----
  size_t need = 0;
  auto walloc = [&](long long elems) { size_t off = need; need += ((size_t)elems + 3) & ~(size_t)3; return off; };
  int* wsbase = (int*)d_ws;
  size_t o_buf0  = walloc(Ncg * D);
  size_t o_buf1  = walloc(Ncg * D);
  size_t o_acck  = walloc(Kr * D);
  size_t o_cgrp  = walloc(Ncg + 1);
  size_t o_kgrp  = walloc(Nkg + 1);
  size_t o_carp  = walloc(Cr + 1);
  size_t o_cgcv  = walloc(2 * Ecg);
  size_t o_kgcv  = walloc(2 * Ekg);
  size_t o_cacv  = walloc(2 * Eca);
  size_t o_curs  = walloc(Ncg);
  size_t o_part  = walloc(256);

  auto axcopy = [&](float* dst, const float* src, long long n, float s) {
    long long n4 = n / 4;
    long long b = (n4 + 255) / 256;
    int blocks = (int)(b < 2048 ? b : 2048);
    axcopy_kernel<<<blocks, 256, 0, stream>>>(dst, src, n4, s);
  };

  if (need * 4 > ws_size) {
    // -------- fallback: R1 atomic path (needs 64MB) --------
    float* buf0 = (float*)d_ws;
    float* buf1 = buf0 + Ncg * D;
    float* acck = buf1 + Ncg * D;
    auto spmm = [&](const int* r, const int* c, const float* v, const float* f,
                    float* o, long long ne) {
      long long threads = ne * 16;
      int blocks = (int)((threads + 255) / 256);
      spmm_atomic_kernel<<<blocks, 256, 0, stream>>>(r, c, v, f, o, ne);
    };
    auto normacc = [&](const float* f, float* a, long long nrows) {
      int blocks = (int)((nrows + 3) / 4);
      norm_acc_kernel<<<blocks, 256, 0, stream>>>(f, a, (int)nrows);
    };
    axcopy(buf0, learners, Lr * D, 1.f);
    axcopy(buf0 + Lr * D, courses, Cr * D, 1.f);
    axcopy(out, learners, Lr * D, 2.f);
    axcopy(out + Lr * D, courses, Cr * D, 1.f);
    hipMemsetAsync(buf1, 0, (size_t)(Ncg * D) * sizeof(float), stream);
    spmm(cg_rows, cg_cols, cg_vals, buf0, buf1, Ecg);
    normacc(buf1, out, Ncg);
    hipMemsetAsync(buf0, 0, (size_t)(Ncg * D) * sizeof(float), stream);
    spmm(cg_rows, cg_cols, cg_vals, buf1, buf0, Ecg);
    normacc(buf0, out, Ncg);
    axcopy(buf0, learners, Lr * D, 1.f);
    axcopy(buf0 + Lr * D, concepts, Kr * D, 1.f);
    axcopy(acck, concepts, Kr * D, 1.f);
    hipMemsetAsync(buf1, 0, (size_t)(Nkg * D) * sizeof(float), stream);
    spmm(kg_rows, kg_cols, kg_vals, buf0, buf1, Ekg);
    normacc(buf1, out, Lr);
    normacc(buf1 + Lr * D, acck, Kr);
    hipMemsetAsync(buf0, 0, (size_t)(Nkg * D) * sizeof(float), stream);
    spmm(kg_rows, kg_cols, kg_vals, buf1, buf0, Ekg);
    normacc(buf0, out, Lr);
    normacc(buf0 + Lr * D, acck, Kr);
    spmm(ca_rows, ca_cols, ca_vals, acck, out + Lr * D, Eca);
    return;
  }

  float* buf0 = (float*)(wsbase + o_buf0);
  float* buf1 = (float*)(wsbase + o_buf1);
  float* acck = (float*)(wsbase + o_acck);
  int*   cgrp = wsbase + o_cgrp;
  int*   kgrp = wsbase + o_kgrp;
  int*   carp = wsbase + o_carp;
  int2*  cgcv = (int2*)(wsbase + o_cgcv);
  int2*  kgcv = (int2*)(wsbase + o_kgcv);
  int2*  cacv = (int2*)(wsbase + o_cacv);
  int*   curs = wsbase + o_curs;
  int*   part = wsbase + o_part;

  auto build_csr = [&](const int* rows, const int* cols, const float* vals,
                       long long ne, int n, int* rowptr, int2* cv) {
    hipMemsetAsync(curs, 0, (size_t)n * sizeof(int), stream);
    long long gb = (ne + 255) / 256;
    int hb = (int)(gb < 4096 ? gb : 4096);
    hist_kernel<<<hb, 256, 0, stream>>>(rows, curs, ne);
    int nb = (n + 1023) / 1024;   // <= 256 for n <= 256K
    scan1_kernel<<<nb, 256, 0, stream>>>(curs, rowptr, part, n);
    scan2_kernel<<<1, 256, 0, stream>>>(part, nb);
    scan3_kernel<<<nb, 256, 0, stream>>>(rowptr, part, n, (int)ne);
    long long cb = (n + 255) / 256;
    icopy_kernel<<<(int)(cb < 4096 ? cb : 4096), 256, 0, stream>>>(curs, rowptr, n);
    scatter_kernel<<<(int)((ne + 255) / 256), 256, 0, stream>>>(rows, cols, vals, curs, cv, ne);
  };

  // ---- build CSR for all three graphs ----
  build_csr(cg_rows, cg_cols, cg_vals, Ecg, (int)Ncg, cgrp, cgcv);
  build_csr(kg_rows, kg_cols, kg_vals, Ekg, (int)Nkg, kgrp, kgcv);
  build_csr(ca_rows, ca_cols, ca_vals, Eca, (int)Cr,  carp, cacv);

  // ---- init accumulators: out[:L] = 2*learners (feat0 of both views), out[L:] = courses, acck = concepts ----
  axcopy(out, learners, Lr * D, 2.f);
  axcopy(out + Lr * D, courses, Cr * D, 1.f);
  axcopy(acck, concepts, Kr * D, 1.f);

  auto pull_norm = [&](const int* rowptr, const int2* cv, const float* fin, float* fout,
                       float* accA, float* accB, long long split, long long nrows) {
    int blocks = (int)((nrows + 3) / 4);
    spmm_pull_norm_kernel<<<blocks, 256, 0, stream>>>(rowptr, cv, fin, fout,
                                                      accA, accB, (int)split, (int)nrows);
  };

  // ---- course-grained view: nodes [learners; courses] align with out rows ----
  axcopy(buf0, learners, Lr * D, 1.f);
  axcopy(buf0 + Lr * D, courses, Cr * D, 1.f);
  pull_norm(cgrp, cgcv, buf0, buf1, out, out, Ncg, Ncg);   // layer 1
  pull_norm(cgrp, cgcv, buf1, buf0, out, out, Ncg, Ncg);   // layer 2

  // ---- concept-grained view: learner rows -> out, concept rows -> acck ----
  axcopy(buf0, learners, Lr * D, 1.f);
  axcopy(buf0 + Lr * D, concepts, Kr * D, 1.f);
  pull_norm(kgrp, kgcv, buf0, buf1, out, acck, Lr, Nkg);   // layer 1
  pull_norm(kgrp, kgcv, buf1, buf0, out, acck, Lr, Nkg);   // layer 2

  // ---- aggregate concept features into course rows of out ----
  {
    int blocks = (int)((Cr + 3) / 4);
    spmm_pull_acc_kernel<<<blocks, 256, 0, stream>>>(carp, cacv, acck, out + Lr * D, (int)Cr);
  }
}

// Round 4
// 1612.568 us; speedup vs baseline: 7.5497x; 1.1635x over previous
//
#include <hip/hip_runtime.h>

#define D 64

// ============================ element-wise utils ============================

__global__ __launch_bounds__(256) void axcopy_kernel(float* __restrict__ dst,
                                                     const float* __restrict__ src,
                                                     long long n4, float s) {
  long long i = (long long)blockIdx.x * blockDim.x + threadIdx.x;
  long long stride = (long long)gridDim.x * blockDim.x;
  for (; i < n4; i += stride) {
    float4 v = ((const float4*)src)[i];
    v.x *= s; v.y *= s; v.z *= s; v.w *= s;
    ((float4*)dst)[i] = v;
  }
}

// dst[row] = src[row] * scale[row], float4-wide; row = i>>4 (16 float4 per row)
__global__ __launch_bounds__(256) void scale_copy_kernel(float* __restrict__ dst,
                                                         const float* __restrict__ src,
                                                         const float* __restrict__ scale,
                                                         long long n4) {
  long long i = (long long)blockIdx.x * blockDim.x + threadIdx.x;
  long long stride = (long long)gridDim.x * blockDim.x;
  for (; i < n4; i += stride) {
    float sc = scale[i >> 4];
    float4 v = ((const float4*)src)[i];
    v.x *= sc; v.y *= sc; v.z *= sc; v.w *= sc;
    ((float4*)dst)[i] = v;
  }
}

// ============================ combined CSR build ============================

struct CsrParams {
  const int* rows0; const int* cols0; long long ne0;
  const int* rows1; const int* cols1; long long ne1;
  const int* rows2; const int* cols2; long long ne2;
  int n0, n1, n2;
  int* cnt;            // [n0+n1+n2] degree counts, later reused as cursors
  float* scales;       // [n0+n1+n2] sigma (graphs 0,1) / inv-deg (graph 2)
  int* rp0; int* rp1; int* rp2;   // rowptr arrays (n+1 each)
  int* cv0; int* cv1; int* cv2;   // CSR col arrays
  int* part;           // scan partials, segmented
  int nb0, nb1, nb2;   // scan blocks per graph
};

__global__ __launch_bounds__(256) void hist_all_kernel(CsrParams P) {
  long long i = (long long)blockIdx.x * blockDim.x + threadIdx.x;
  long long stride = (long long)gridDim.x * blockDim.x;
  long long t01 = P.ne0 + P.ne1, tot = t01 + P.ne2;
  for (; i < tot; i += stride) {
    const int* rw; long long e; int off;
    if (i < P.ne0)      { rw = P.rows0; e = i;        off = 0; }
    else if (i < t01)   { rw = P.rows1; e = i - P.ne0; off = P.n0; }
    else                { rw = P.rows2; e = i - t01;   off = P.n0 + P.n1; }
    atomicAdd(&P.cnt[off + rw[e]], 1);
  }
}

__global__ __launch_bounds__(256) void scale_all_kernel(CsrParams P) {
  int ntot = P.n0 + P.n1 + P.n2;
  int nlap = P.n0 + P.n1;
  int i = blockIdx.x * blockDim.x + threadIdx.x;
  int stride = gridDim.x * blockDim.x;
  for (; i < ntot; i += stride) {
    float c = (float)P.cnt[i];
    P.scales[i] = (i < nlap) ? 1.0f / (sqrtf(c) + 1e-8f)
                             : 1.0f / (c + 1e-8f);
  }
}

// segmented exclusive scan, 1024 elems per block
__global__ __launch_bounds__(256) void scan1_seg_kernel(CsrParams P) {
  __shared__ int lds[256];
  int b = blockIdx.x, t = threadIdx.x;
  int lb, n, coff, poff; int* rp;
  if (b < P.nb0)               { lb = b;                 n = P.n0; coff = 0;           poff = 0;             rp = P.rp0; }
  else if (b < P.nb0 + P.nb1)  { lb = b - P.nb0;         n = P.n1; coff = P.n0;        poff = P.nb0;         rp = P.rp1; }
  else                         { lb = b - P.nb0 - P.nb1; n = P.n2; coff = P.n0 + P.n1; poff = P.nb0 + P.nb1; rp = P.rp2; }
  int base = lb * 1024 + t * 4;
  int v[4]; int s = 0;
  #pragma unroll
  for (int j = 0; j < 4; j++) { int idx = base + j; v[j] = (idx < n) ? P.cnt[coff + idx] : 0; s += v[j]; }
  lds[t] = s;
  __syncthreads();
  for (int off = 1; off < 256; off <<= 1) {
    int x = (t >= off) ? lds[t - off] : 0;
    __syncthreads();
    lds[t] += x;
    __syncthreads();
  }
  int run = (t == 0) ? 0 : lds[t - 1];
  if (t == 255) P.part[poff + lb] = lds[255];
  #pragma unroll
  for (int j = 0; j < 4; j++) { int idx = base + j; if (idx < n) rp[idx] = run; run += v[j]; }
}

__global__ __launch_bounds__(256) void scan2_seg_kernel(CsrParams P) {
  __shared__ int lds[256];
  int g = blockIdx.x, t = threadIdx.x;
  int nb = (g == 0) ? P.nb0 : (g == 1) ? P.nb1 : P.nb2;
  int poff = (g == 0) ? 0 : (g == 1) ? P.nb0 : P.nb0 + P.nb1;
  lds[t] = (t < nb) ? P.part[poff + t] : 0;
  __syncthreads();
  for (int off = 1; off < 256; off <<= 1) {
    int x = (t >= off) ? lds[t - off] : 0;
    __syncthreads();
    lds[t] += x;
    __syncthreads();
  }
  if (t < nb) P.part[poff + t] = (t == 0) ? 0 : lds[t - 1];
}

__global__ __launch_bounds__(256) void scan3_seg_kernel(CsrParams P) {
  int b = blockIdx.x, t = threadIdx.x;
  int lb, n, poff; int* rp; long long ne;
  if (b < P.nb0)               { lb = b;                 n = P.n0; poff = 0;             rp = P.rp0; ne = P.ne0; }
  else if (b < P.nb0 + P.nb1)  { lb = b - P.nb0;         n = P.n1; poff = P.nb0;         rp = P.rp1; ne = P.ne1; }
  else                         { lb = b - P.nb0 - P.nb1; n = P.n2; poff = P.nb0 + P.nb1; rp = P.rp2; ne = P.ne2; }
  int add = P.part[poff + lb];
  int base = lb * 1024 + t * 4;
  #pragma unroll
  for (int j = 0; j < 4; j++) { int idx = base + j; if (idx < n) rp[idx] += add; }
  if (lb == 0 && t == 0) rp[n] = (int)ne;
}

// cursors = rowptr (per graph), combined
__global__ __launch_bounds__(256) void cursor_init_kernel(CsrParams P) {
  int ntot = P.n0 + P.n1 + P.n2;
  int i = blockIdx.x * blockDim.x + threadIdx.x;
  int stride = gridDim.x * blockDim.x;
  for (; i < ntot; i += stride) {
    const int* rp; int il;
    if (i < P.n0)            { rp = P.rp0; il = i; }
    else if (i < P.n0+P.n1)  { rp = P.rp1; il = i - P.n0; }
    else                     { rp = P.rp2; il = i - P.n0 - P.n1; }
    P.cnt[i] = rp[il];
  }
}

__global__ __launch_bounds__(256) void scatter_all_kernel(CsrParams P) {
  long long i = (long long)blockIdx.x * blockDim.x + threadIdx.x;
  long long stride = (long long)gridDim.x * blockDim.x;
  long long t01 = P.ne0 + P.ne1, tot = t01 + P.ne2;
  for (; i < tot; i += stride) {
    const int* rw; const int* cl; long long e; int off; int* cv;
    if (i < P.ne0)      { rw = P.rows0; cl = P.cols0; e = i;        off = 0;           cv = P.cv0; }
    else if (i < t01)   { rw = P.rows1; cl = P.cols1; e = i - P.ne0; off = P.n0;       cv = P.cv1; }
    else                { rw = P.rows2; cl = P.cols2; e = i - t01;   off = P.n0+P.n1;  cv = P.cv2; }
    int p = atomicAdd(&P.cnt[off + rw[e]], 1);
    cv[p] = cl[e];
  }
}

// ============================ pull SpMM ============================
// One wave per row, lane = feature dim. sraw = sum of h_in[col] over row's edges.
// MODE 0: h_out[row] = scale[row]^2 * sraw; acc += unit(sraw)
// MODE 1: acc += unit(sraw)                         (last layer, no h_out)
// MODE 2: acc[row] += scale[row] * sraw             (ca aggregation)
template <int MODE>
__global__ __launch_bounds__(256) void pull_kernel(
    const int* __restrict__ rowptr, const int* __restrict__ cols,
    const float* __restrict__ scale, const float* __restrict__ h_in,
    float* __restrict__ h_out, float* __restrict__ accA, float* __restrict__ accB,
    int split, int nrows) {
  int row = blockIdx.x * 4 + (threadIdx.x >> 6);
  if (row >= nrows) return;
  int lane = threadIdx.x & 63;
  int e0 = rowptr[row], e1 = rowptr[row + 1];
  float s = 0.f;
  int e = e0;
  for (; e + 3 < e1; e += 4) {
    int c0 = cols[e], c1 = cols[e + 1], c2 = cols[e + 2], c3 = cols[e + 3];
    s += h_in[(long long)c0 * D + lane];
    s += h_in[(long long)c1 * D + lane];
    s += h_in[(long long)c2 * D + lane];
    s += h_in[(long long)c3 * D + lane];
  }
  for (; e < e1; ++e) s += h_in[(long long)cols[e] * D + lane];

  if (MODE == 2) {
    float sc = scale[row];
    accA[(long long)row * D + lane] += sc * s;
    return;
  }
  if (MODE == 0) {
    float sc = scale[row];
    h_out[(long long)row * D + lane] = sc * sc * s;
  }
  float q = s * s;
  #pragma unroll
  for (int off = 32; off; off >>= 1) q += __shfl_xor(q, off);
  float r = 1.0f / fmaxf(sqrtf(q), 1e-12f);
  float* acc = (row < split) ? accA + (long long)row * D
                             : accB + (long long)(row - split) * D;
  acc[lane] += s * r;
}

// ============================ fallback (R1 atomic path) ============================

__global__ __launch_bounds__(256) void spmm_atomic_kernel(
    const int* __restrict__ rows, const int* __restrict__ cols,
    const float* __restrict__ vals, const float* __restrict__ feat,
    float* __restrict__ outp, long long ne) {
  long long t = (long long)blockIdx.x * blockDim.x + threadIdx.x;
  long long e = t >> 4;
  if (e >= ne) return;
  int lane = (int)(t & 15);
  int r = rows[e];
  int c = cols[e];
  float v = vals[e];
  const float4 f = *(const float4*)(feat + (long long)c * D + lane * 4);
  float* o = outp + (long long)r * D + lane * 4;
  atomicAdd(o + 0, v * f.x);
  atomicAdd(o + 1, v * f.y);
  atomicAdd(o + 2, v * f.z);
  atomicAdd(o + 3, v * f.w);
}

__global__ __launch_bounds__(256) void norm_acc_kernel(const float* __restrict__ feat,
                                                       float* __restrict__ acc,
                                                       int nrows) {
  int row = blockIdx.x * 4 + (threadIdx.x >> 6);
  if (row >= nrows) return;
  int lane = threadIdx.x & 63;
  float x = feat[(long long)row * D + lane];
  float s = x * x;
  #pragma unroll
  for (int off = 32; off; off >>= 1) s += __shfl_xor(s, off);
  float sc = 1.0f / fmaxf(sqrtf(s), 1e-12f);
  acc[(long long)row * D + lane] += x * sc;
}

// ============================ launch ============================

extern "C" void kernel_launch(void* const* d_in, const int* in_sizes, int n_in,
                              void* d_out, int out_size, void* d_ws, size_t ws_size,
                              hipStream_t stream) {
  const float* learners = (const float*)d_in[0];
  const float* courses  = (const float*)d_in[1];
  const float* concepts = (const float*)d_in[2];
  const int*   cg_rows  = (const int*)d_in[3];
  const int*   cg_cols  = (const int*)d_in[4];
  const float* cg_vals  = (const float*)d_in[5];
  const int*   kg_rows  = (const int*)d_in[6];
  const int*   kg_cols  = (const int*)d_in[7];
  const float* kg_vals  = (const float*)d_in[8];
  const int*   ca_rows  = (const int*)d_in[9];
  const int*   ca_cols  = (const int*)d_in[10];
  const float* ca_vals  = (const float*)d_in[11];

  const long long Lr  = in_sizes[0] / D;
  const long long Cr  = in_sizes[1] / D;
  const long long Kr  = in_sizes[2] / D;
  const long long Ecg = in_sizes[3];
  const long long Ekg = in_sizes[6];
  const long long Eca = in_sizes[9];
  const long long Ncg = Lr + Cr;
  const long long Nkg = Lr + Kr;

  float* out = (float*)d_out;

  // ---- workspace layout ----
  size_t need = 0;
  auto walloc = [&](long long elems) { size_t off = need; need += ((size_t)elems + 3) & ~(size_t)3; return off; };
  int* wsbase = (int*)d_ws;
  size_t o_buf0  = walloc(Ncg * D);
  size_t o_buf1  = walloc(Ncg * D);
  size_t o_acck  = walloc(Kr * D);
  size_t o_cgrp  = walloc(Ncg + 1);
  size_t o_kgrp  = walloc(Nkg + 1);
  size_t o_carp  = walloc(Cr + 1);
  size_t o_cgcv  = walloc(Ecg);
  size_t o_kgcv  = walloc(Ekg);
  size_t o_cacv  = walloc(Eca);
  size_t o_cnt   = walloc(Ncg + Nkg + Cr);
  size_t o_scal  = walloc(Ncg + Nkg + Cr);
  size_t o_part  = walloc(512);

  auto axcopy = [&](float* dst, const float* src, long long n, float s) {
    long long n4 = n / 4;
    long long b = (n4 + 255) / 256;
    int blocks = (int)(b < 2048 ? b : 2048);
    axcopy_kernel<<<blocks, 256, 0, stream>>>(dst, src, n4, s);
  };

  if (need * 4 > ws_size) {
    // -------- fallback: atomic push path --------
    float* buf0 = (float*)d_ws;
    float* buf1 = buf0 + Ncg * D;
    float* acck = buf1 + Ncg * D;
    auto spmm = [&](const int* r, const int* c, const float* v, const float* f,
                    float* o, long long ne) {
      long long threads = ne * 16;
      int blocks = (int)((threads + 255) / 256);
      spmm_atomic_kernel<<<blocks, 256, 0, stream>>>(r, c, v, f, o, ne);
    };
    auto normacc = [&](const float* f, float* a, long long nrows) {
      int blocks = (int)((nrows + 3) / 4);
      norm_acc_kernel<<<blocks, 256, 0, stream>>>(f, a, (int)nrows);
    };
    axcopy(buf0, learners, Lr * D, 1.f);
    axcopy(buf0 + Lr * D, courses, Cr * D, 1.f);
    axcopy(out, learners, Lr * D, 2.f);
    axcopy(out + Lr * D, courses, Cr * D, 1.f);
    hipMemsetAsync(buf1, 0, (size_t)(Ncg * D) * sizeof(float), stream);
    spmm(cg_rows, cg_cols, cg_vals, buf0, buf1, Ecg);
    normacc(buf1, out, Ncg);
    hipMemsetAsync(buf0, 0, (size_t)(Ncg * D) * sizeof(float), stream);
    spmm(cg_rows, cg_cols, cg_vals, buf1, buf0, Ecg);
    normacc(buf0, out, Ncg);
    axcopy(buf0, learners, Lr * D, 1.f);
    axcopy(buf0 + Lr * D, concepts, Kr * D, 1.f);
    axcopy(acck, concepts, Kr * D, 1.f);
    hipMemsetAsync(buf1, 0, (size_t)(Nkg * D) * sizeof(float), stream);
    spmm(kg_rows, kg_cols, kg_vals, buf0, buf1, Ekg);
    normacc(buf1, out, Lr);
    normacc(buf1 + Lr * D, acck, Kr);
    hipMemsetAsync(buf0, 0, (size_t)(Nkg * D) * sizeof(float), stream);
    spmm(kg_rows, kg_cols, kg_vals, buf1, buf0, Ekg);
    normacc(buf0, out, Lr);
    normacc(buf0 + Lr * D, acck, Kr);
    spmm(ca_rows, ca_cols, ca_vals, acck, out + Lr * D, Eca);
    return;
  }

  float* buf0 = (float*)(wsbase + o_buf0);
  float* buf1 = (float*)(wsbase + o_buf1);
  float* acck = (float*)(wsbase + o_acck);

  CsrParams P;
  P.rows0 = cg_rows; P.cols0 = cg_cols; P.ne0 = Ecg;
  P.rows1 = kg_rows; P.cols1 = kg_cols; P.ne1 = Ekg;
  P.rows2 = ca_rows; P.cols2 = ca_cols; P.ne2 = Eca;
  P.n0 = (int)Ncg; P.n1 = (int)Nkg; P.n2 = (int)Cr;
  P.cnt = wsbase + o_cnt;
  P.scales = (float*)(wsbase + o_scal);
  P.rp0 = wsbase + o_cgrp; P.rp1 = wsbase + o_kgrp; P.rp2 = wsbase + o_carp;
  P.cv0 = wsbase + o_cgcv; P.cv1 = wsbase + o_kgcv; P.cv2 = wsbase + o_cacv;
  P.part = wsbase + o_part;
  P.nb0 = (P.n0 + 1023) / 1024;
  P.nb1 = (P.n1 + 1023) / 1024;
  P.nb2 = (P.n2 + 1023) / 1024;

  const long long ntot = Ncg + Nkg + Cr;
  const long long etot = Ecg + Ekg + Eca;
  const int eb = (int)((etot + 255) / 256);
  const int nb = (int)((ntot + 255) / 256);

  // ---- build: 8 dispatches ----
  hipMemsetAsync(P.cnt, 0, (size_t)ntot * sizeof(int), stream);
  hist_all_kernel<<<eb, 256, 0, stream>>>(P);
  scale_all_kernel<<<nb, 256, 0, stream>>>(P);
  scan1_seg_kernel<<<P.nb0 + P.nb1 + P.nb2, 256, 0, stream>>>(P);
  scan2_seg_kernel<<<3, 256, 0, stream>>>(P);
  scan3_seg_kernel<<<P.nb0 + P.nb1 + P.nb2, 256, 0, stream>>>(P);
  cursor_init_kernel<<<nb, 256, 0, stream>>>(P);
  scatter_all_kernel<<<eb, 256, 0, stream>>>(P);

  // ---- init accumulators ----
  axcopy(out, learners, Lr * D, 2.f);            // feat0 of both views for learner rows
  axcopy(out + Lr * D, courses, Cr * D, 1.f);
  axcopy(acck, concepts, Kr * D, 1.f);

  const float* sig_cg = P.scales;                // Ncg sigmas
  const float* sig_kg = P.scales + Ncg;          // Nkg sigmas
  const float* inv_ca = P.scales + Ncg + Nkg;    // Cr inverse degrees

  auto scale_copy = [&](float* dst, const float* src, const float* sc, long long nrows) {
    long long n4 = nrows * (D / 4);
    long long b = (n4 + 255) / 256;
    int blocks = (int)(b < 4096 ? b : 4096);
    scale_copy_kernel<<<blocks, 256, 0, stream>>>(dst, src, sc, n4);
  };

  // ---- course-grained view ----
  scale_copy(buf0, learners, sig_cg, Lr);
  scale_copy(buf0 + Lr * D, courses, sig_cg + Lr, Cr);
  {
    int blocks = (int)((Ncg + 3) / 4);
    pull_kernel<0><<<blocks, 256, 0, stream>>>(P.rp0, P.cv0, sig_cg, buf0, buf1,
                                               out, out, (int)Ncg, (int)Ncg);
    pull_kernel<1><<<blocks, 256, 0, stream>>>(P.rp0, P.cv0, sig_cg, buf1, nullptr,
                                               out, out, (int)Ncg, (int)Ncg);
  }

  // ---- concept-grained view ----
  scale_copy(buf0, learners, sig_kg, Lr);
  scale_copy(buf0 + Lr * D, concepts, sig_kg + Lr, Kr);
  {
    int blocks = (int)((Nkg + 3) / 4);
    pull_kernel<0><<<blocks, 256, 0, stream>>>(P.rp1, P.cv1, sig_kg, buf0, buf1,
                                               out, acck, (int)Lr, (int)Nkg);
    pull_kernel<1><<<blocks, 256, 0, stream>>>(P.rp1, P.cv1, sig_kg, buf1, nullptr,
                                               out, acck, (int)Lr, (int)Nkg);
  }

  // ---- aggregate concept features into course rows ----
  {
    int blocks = (int)((Cr + 3) / 4);
    pull_kernel<2><<<blocks, 256, 0, stream>>>(P.rp2, P.cv2, inv_ca, acck, nullptr,
                                               out + Lr * D, nullptr, (int)Cr, (int)Cr);
  }
}

// Round 5
// 1444.383 us; speedup vs baseline: 8.4288x; 1.1164x over previous
//
#include <hip/hip_runtime.h>

#define D 64
#define S0 11           // learner-side bucket shift (2048 rows/bucket)
#define SPLITLOG 4      // 16 slices per bucket in fine pass
#define BCHUNK 8        // edges per thread in bin pass

// ============================ element-wise utils ============================

__global__ __launch_bounds__(256) void axcopy_kernel(float* __restrict__ dst,
                                                     const float* __restrict__ src,
                                                     long long n4, float s) {
  long long i = (long long)blockIdx.x * blockDim.x + threadIdx.x;
  long long stride = (long long)gridDim.x * blockDim.x;
  for (; i < n4; i += stride) {
    float4 v = ((const float4*)src)[i];
    v.x *= s; v.y *= s; v.z *= s; v.w *= s;
    ((float4*)dst)[i] = v;
  }
}

// ============================ build: hist / scale / scan ============================

// Degrees from HALF the symmetric COO (mirror structure: rows=[a,b+L], cols=[b+L,a]):
// each first-half edge (a, c) increments both endpoints. ca graph: rows only.
__global__ __launch_bounds__(256) void hist2_kernel(
    const int* __restrict__ cgr, const int* __restrict__ cgc, long long EcgH,
    const int* __restrict__ kgr, const int* __restrict__ kgc, long long EkgH,
    const int* __restrict__ car, long long Eca,
    int* __restrict__ cnt, int offKg, int offCa) {
  long long i = (long long)blockIdx.x * blockDim.x + threadIdx.x;
  long long stride = (long long)gridDim.x * blockDim.x;
  long long t01 = EcgH + EkgH, tot = t01 + Eca;
  for (; i < tot; i += stride) {
    if (i < EcgH) {
      atomicAdd(&cnt[cgr[i]], 1);
      atomicAdd(&cnt[cgc[i]], 1);
    } else if (i < t01) {
      long long j = i - EcgH;
      atomicAdd(&cnt[offKg + kgr[j]], 1);
      atomicAdd(&cnt[offKg + kgc[j]], 1);
    } else {
      long long j = i - t01;
      atomicAdd(&cnt[offCa + car[j]], 1);
    }
  }
}

struct ScanParams {
  int n0, n1, n2;
  int* cnt;
  float* scales;
  int* rp0; int* rp1; int* rp2;
  int* part;
  int nb0, nb1, nb2;
  long long ne0, ne1, ne2;
};

__global__ __launch_bounds__(256) void scale_all_kernel(ScanParams P) {
  int ntot = P.n0 + P.n1 + P.n2;
  int nlap = P.n0 + P.n1;
  int i = blockIdx.x * blockDim.x + threadIdx.x;
  int stride = gridDim.x * blockDim.x;
  for (; i < ntot; i += stride) {
    float c = (float)P.cnt[i];
    P.scales[i] = (i < nlap) ? 1.0f / (sqrtf(c) + 1e-8f)
                             : 1.0f / (c + 1e-8f);
  }
}

__global__ __launch_bounds__(256) void scan1_seg_kernel(ScanParams P) {
  __shared__ int lds[256];
  int b = blockIdx.x, t = threadIdx.x;
  int lb, n, coff, poff; int* rp;
  if (b < P.nb0)               { lb = b;                 n = P.n0; coff = 0;           poff = 0;             rp = P.rp0; }
  else if (b < P.nb0 + P.nb1)  { lb = b - P.nb0;         n = P.n1; coff = P.n0;        poff = P.nb0;         rp = P.rp1; }
  else                         { lb = b - P.nb0 - P.nb1; n = P.n2; coff = P.n0 + P.n1; poff = P.nb0 + P.nb1; rp = P.rp2; }
  int base = lb * 1024 + t * 4;
  int v[4]; int s = 0;
  #pragma unroll
  for (int j = 0; j < 4; j++) { int idx = base + j; v[j] = (idx < n) ? P.cnt[coff + idx] : 0; s += v[j]; }
  lds[t] = s;
  __syncthreads();
  for (int off = 1; off < 256; off <<= 1) {
    int x = (t >= off) ? lds[t - off] : 0;
    __syncthreads();
    lds[t] += x;
    __syncthreads();
  }
  int run = (t == 0) ? 0 : lds[t - 1];
  if (t == 255) P.part[poff + lb] = lds[255];
  #pragma unroll
  for (int j = 0; j < 4; j++) { int idx = base + j; if (idx < n) rp[idx] = run; run += v[j]; }
}

__global__ __launch_bounds__(256) void scan2_seg_kernel(ScanParams P) {
  __shared__ int lds[256];
  int g = blockIdx.x, t = threadIdx.x;
  int nb = (g == 0) ? P.nb0 : (g == 1) ? P.nb1 : P.nb2;
  int poff = (g == 0) ? 0 : (g == 1) ? P.nb0 : P.nb0 + P.nb1;
  lds[t] = (t < nb) ? P.part[poff + t] : 0;
  __syncthreads();
  for (int off = 1; off < 256; off <<= 1) {
    int x = (t >= off) ? lds[t - off] : 0;
    __syncthreads();
    lds[t] += x;
    __syncthreads();
  }
  if (t < nb) P.part[poff + t] = (t == 0) ? 0 : lds[t - 1];
}

__global__ __launch_bounds__(256) void scan3_seg_kernel(ScanParams P) {
  int b = blockIdx.x, t = threadIdx.x;
  int lb, n, poff; int* rp; long long ne;
  if (b < P.nb0)               { lb = b;                 n = P.n0; poff = 0;             rp = P.rp0; ne = P.ne0; }
  else if (b < P.nb0 + P.nb1)  { lb = b - P.nb0;         n = P.n1; poff = P.nb0;         rp = P.rp1; ne = P.ne1; }
  else                         { lb = b - P.nb0 - P.nb1; n = P.n2; poff = P.nb0 + P.nb1; rp = P.rp2; ne = P.ne2; }
  int add = P.part[poff + lb];
  int base = lb * 1024 + t * 4;
  #pragma unroll
  for (int j = 0; j < 4; j++) { int idx = base + j; if (idx < n) rp[idx] += add; }
  if (lb == 0 && t == 0) rp[n] = (int)ne;
}

// rowcur[i] = rp[i] for all rows of all graphs (reuses cnt array)
__global__ __launch_bounds__(256) void rowcur_init_kernel(ScanParams P) {
  int ntot = P.n0 + P.n1 + P.n2;
  int i = blockIdx.x * blockDim.x + threadIdx.x;
  int stride = gridDim.x * blockDim.x;
  for (; i < ntot; i += stride) {
    const int* rp; int il;
    if (i < P.n0)              { rp = P.rp0; il = i; }
    else if (i < P.n0 + P.n1)  { rp = P.rp1; il = i - P.n0; }
    else                       { rp = P.rp2; il = i - P.n0 - P.n1; }
    P.cnt[i] = rp[il];
  }
}

// bucket cursors: bcur[b] = rp[rowbase(b)]
__global__ __launch_bounds__(256) void bucket_init_kernel(
    const int* __restrict__ rp0, const int* __restrict__ rp1, int* __restrict__ bcur,
    int L, int NB0, int s1cg, int NBcg, int s1kg, int NBkg) {
  int i = blockIdx.x * blockDim.x + threadIdx.x;
  if (i < NBcg) {
    int rowbase = (i < NB0) ? (i << S0) : (L + ((i - NB0) << s1cg));
    bcur[i] = rp0[rowbase];
  } else if (i < NBcg + NBkg) {
    int j = i - NBcg;
    int rowbase = (j < NB0) ? (j << S0) : (L + ((j - NB0) << s1kg));
    bcur[i] = rp1[rowbase];
  }
}

// ============================ pass 1: LDS-aggregated binning ============================
// Reads the FIRST HALF of the symmetric COO; emits two packed entries per edge:
//   side0 bucket of a: (a&2047)<<17 | c       side1 bucket of c: ((c-L)&mask)<<17 | a
__global__ __launch_bounds__(256) void bin_kernel(
    const int* __restrict__ rowsA, const int* __restrict__ colsA, long long E,
    int L, int s1, int NB0, int NBtot,
    int* __restrict__ gcur, int* __restrict__ binned) {
  __shared__ int cnt[256];
  __shared__ int gbase[256];
  int t = threadIdx.x;
  long long base = (long long)blockIdx.x * (256 * BCHUNK);
  cnt[t] = 0;
  __syncthreads();
  int av[BCHUNK], cv_[BCHUNK], l0[BCHUNK], l1[BCHUNK];
  #pragma unroll
  for (int k = 0; k < BCHUNK; k++) {
    long long i = base + (long long)k * 256 + t;
    bool ok = i < E;
    int a = ok ? rowsA[i] : 0;
    int c = ok ? colsA[i] : L;
    av[k] = a; cv_[k] = c;
    if (ok) {
      int b0 = a >> S0;
      int b1 = NB0 + ((c - L) >> s1);
      l0[k] = atomicAdd(&cnt[b0], 1);
      l1[k] = atomicAdd(&cnt[b1], 1);
    } else { l0[k] = 0; l1[k] = 0; }
  }
  __syncthreads();
  if (t < NBtot) gbase[t] = cnt[t] ? atomicAdd(&gcur[t], cnt[t]) : 0;
  __syncthreads();
  #pragma unroll
  for (int k = 0; k < BCHUNK; k++) {
    long long i = base + (long long)k * 256 + t;
    if (i < E) {
      int a = av[k], c = cv_[k];
      int b0 = a >> S0;
      int b1 = NB0 + ((c - L) >> s1);
      binned[gbase[b0] + l0[k]] = ((a & ((1 << S0) - 1)) << 17) | c;
      binned[gbase[b1] + l1[k]] = (((c - L) & ((1 << s1) - 1)) << 17) | a;
    }
  }
}

// ============================ pass 2: fine scatter within L2-sized windows ============================
__global__ __launch_bounds__(256) void fine_kernel(
    const int* __restrict__ binned, const int* __restrict__ rp,
    int* __restrict__ rowcur, int* __restrict__ cvout,
    int L, int sideEnd, int s1, int NB0, int goff) {
  int bucket = blockIdx.x >> SPLITLOG;
  int j = blockIdx.x & ((1 << SPLITLOG) - 1);
  int rowbase, rowend;
  if (bucket < NB0) { rowbase = bucket << S0; rowend = min(rowbase + (1 << S0), L); }
  else { int bb = bucket - NB0; rowbase = L + (bb << s1); rowend = min(rowbase + (1 << s1), sideEnd); }
  int start = rp[rowbase], end = rp[rowend];
  int len = end - start;
  int per = (len + (1 << SPLITLOG) - 1) >> SPLITLOG;
  int is = start + j * per;
  int ie = min(is + per, end);
  for (int i = is + threadIdx.x; i < ie; i += 256) {
    int w = binned[i];
    int col = w & 0x1FFFF;
    int row = rowbase + (w >> 17);
    int p = atomicAdd(&rowcur[goff + row], 1);
    cvout[p] = col;
  }
}

// direct scatter for the small ca graph
__global__ __launch_bounds__(256) void scatter_ca_kernel(
    const int* __restrict__ rows, const int* __restrict__ cols,
    int* __restrict__ rowcur, int* __restrict__ cv, long long ne, int goff) {
  long long e = (long long)blockIdx.x * blockDim.x + threadIdx.x;
  if (e >= ne) return;
  int p = atomicAdd(&rowcur[goff + rows[e]], 1);
  cv[p] = cols[e];
}

// ============================ pull SpMM ============================
// One wave per row, lane = feature dim.
// MODE 0: h_out[row] = scaleRow[row]^2 * sraw; acc += unit(sraw)
// MODE 1: acc += unit(sraw)
// MODE 2: accA[row] += scaleRow[row] * sraw
// FUSE 1: sraw terms = sigCol[c] * raw_feat(c)  (raw feats split at Lsplit into fA/fB)
template <int MODE, int FUSE>
__global__ __launch_bounds__(256) void pull_kernel(
    const int* __restrict__ rowptr, const int* __restrict__ cols,
    const float* __restrict__ scaleRow, const float* __restrict__ sigCol,
    const float* __restrict__ fA, const float* __restrict__ fB, int Lsplit,
    float* __restrict__ h_out, float* __restrict__ accA, float* __restrict__ accB,
    int splitAcc, int nrows) {
  int row = blockIdx.x * 4 + (threadIdx.x >> 6);
  if (row >= nrows) return;
  int lane = threadIdx.x & 63;
  int e0 = rowptr[row], e1 = rowptr[row + 1];
  float s = 0.f;
  int e = e0;
  #define FETCH(c) (FUSE ? (sigCol[c] * ((c) < Lsplit ? fA[(long long)(c) * D + lane] \
                                                      : fB[(long long)((c) - Lsplit) * D + lane])) \
                         : fA[(long long)(c) * D + lane])
  for (; e + 3 < e1; e += 4) {
    int c0 = cols[e], c1 = cols[e + 1], c2 = cols[e + 2], c3 = cols[e + 3];
    s += FETCH(c0); s += FETCH(c1); s += FETCH(c2); s += FETCH(c3);
  }
  for (; e < e1; ++e) { int c = cols[e]; s += FETCH(c); }
  #undef FETCH

  if (MODE == 2) {
    accA[(long long)row * D + lane] += scaleRow[row] * s;
    return;
  }
  if (MODE == 0) {
    float sc = scaleRow[row];
    h_out[(long long)row * D + lane] = sc * sc * s;
  }
  float q = s * s;
  #pragma unroll
  for (int off = 32; off; off >>= 1) q += __shfl_xor(q, off);
  float r = 1.0f / fmaxf(sqrtf(q), 1e-12f);
  float* acc = (row < splitAcc) ? accA + (long long)row * D
                                : accB + (long long)(row - splitAcc) * D;
  acc[lane] += s * r;
}

// ============================ fallback (atomic push path) ============================

__global__ __launch_bounds__(256) void spmm_atomic_kernel(
    const int* __restrict__ rows, const int* __restrict__ cols,
    const float* __restrict__ vals, const float* __restrict__ feat,
    float* __restrict__ outp, long long ne) {
  long long t = (long long)blockIdx.x * blockDim.x + threadIdx.x;
  long long e = t >> 4;
  if (e >= ne) return;
  int lane = (int)(t & 15);
  int r = rows[e];
  int c = cols[e];
  float v = vals[e];
  const float4 f = *(const float4*)(feat + (long long)c * D + lane * 4);
  float* o = outp + (long long)r * D + lane * 4;
  atomicAdd(o + 0, v * f.x);
  atomicAdd(o + 1, v * f.y);
  atomicAdd(o + 2, v * f.z);
  atomicAdd(o + 3, v * f.w);
}

__global__ __launch_bounds__(256) void norm_acc_kernel(const float* __restrict__ feat,
                                                       float* __restrict__ acc,
                                                       int nrows) {
  int row = blockIdx.x * 4 + (threadIdx.x >> 6);
  if (row >= nrows) return;
  int lane = threadIdx.x & 63;
  float x = feat[(long long)row * D + lane];
  float s = x * x;
  #pragma unroll
  for (int off = 32; off; off >>= 1) s += __shfl_xor(s, off);
  float sc = 1.0f / fmaxf(sqrtf(s), 1e-12f);
  acc[(long long)row * D + lane] += x * sc;
}

// ============================ launch ============================

extern "C" void kernel_launch(void* const* d_in, const int* in_sizes, int n_in,
                              void* d_out, int out_size, void* d_ws, size_t ws_size,
                              hipStream_t stream) {
  const float* learners = (const float*)d_in[0];
  const float* courses  = (const float*)d_in[1];
  const float* concepts = (const float*)d_in[2];
  const int*   cg_rows  = (const int*)d_in[3];
  const int*   cg_cols  = (const int*)d_in[4];
  const int*   kg_rows  = (const int*)d_in[6];
  const int*   kg_cols  = (const int*)d_in[7];
  const int*   ca_rows  = (const int*)d_in[9];
  const int*   ca_cols  = (const int*)d_in[10];
  const float* cg_vals  = (const float*)d_in[5];
  const float* kg_vals  = (const float*)d_in[8];
  const float* ca_vals  = (const float*)d_in[11];

  const long long Lr  = in_sizes[0] / D;
  const long long Cr  = in_sizes[1] / D;
  const long long Kr  = in_sizes[2] / D;
  const long long Ecg = in_sizes[3];      // full (2x bipartite)
  const long long Ekg = in_sizes[6];
  const long long Eca = in_sizes[9];
  const long long EcgH = Ecg / 2;
  const long long EkgH = Ekg / 2;
  const long long Ncg = Lr + Cr;
  const long long Nkg = Lr + Kr;

  float* out = (float*)d_out;

  // ---- workspace layout (words) ----
  long long maxE2 = (Ecg > Ekg ? Ecg : Ekg);
  long long shareW = Ncg * D > maxE2 ? Ncg * D : maxE2;   // h1 buffer / binned scratch
  size_t need = 0;
  auto walloc = [&](long long elems) { size_t off = need; need += ((size_t)elems + 3) & ~(size_t)3; return off; };
  int* wsbase = (int*)d_ws;
  size_t o_share = walloc(shareW);
  size_t o_acck  = walloc(Kr * D);
  size_t o_rp0   = walloc(Ncg + 1);
  size_t o_rp1   = walloc(Nkg + 1);
  size_t o_rp2   = walloc(Cr + 1);
  size_t o_cv0   = walloc(Ecg);
  size_t o_cv1   = walloc(Ekg);
  size_t o_cv2   = walloc(Eca);
  size_t o_cnt   = walloc(Ncg + Nkg + Cr);
  size_t o_scal  = walloc(Ncg + Nkg + Cr);
  size_t o_part  = walloc(512);
  size_t o_bcur  = walloc(512);

  auto axcopy = [&](float* dst, const float* src, long long n, float s) {
    long long n4 = n / 4;
    long long b = (n4 + 255) / 256;
    int blocks = (int)(b < 2048 ? b : 2048);
    axcopy_kernel<<<blocks, 256, 0, stream>>>(dst, src, n4, s);
  };

  bool packable = (Ncg <= 131072) && (Nkg <= 131072) && (Lr % 2 == 0);
  if (need * 4 > ws_size || !packable) {
    // -------- fallback: atomic push path (correct for any shape) --------
    float* buf0 = (float*)d_ws;
    float* buf1 = buf0 + Ncg * D;
    float* acck = buf1 + Ncg * D;
    auto spmm = [&](const int* r, const int* c, const float* v, const float* f,
                    float* o, long long ne) {
      long long threads = ne * 16;
      int blocks = (int)((threads + 255) / 256);
      spmm_atomic_kernel<<<blocks, 256, 0, stream>>>(r, c, v, f, o, ne);
    };
    auto normacc = [&](const float* f, float* a, long long nrows) {
      int blocks = (int)((nrows + 3) / 4);
      norm_acc_kernel<<<blocks, 256, 0, stream>>>(f, a, (int)nrows);
    };
    axcopy(buf0, learners, Lr * D, 1.f);
    axcopy(buf0 + Lr * D, courses, Cr * D, 1.f);
    axcopy(out, learners, Lr * D, 2.f);
    axcopy(out + Lr * D, courses, Cr * D, 1.f);
    hipMemsetAsync(buf1, 0, (size_t)(Ncg * D) * sizeof(float), stream);
    spmm(cg_rows, cg_cols, cg_vals, buf0, buf1, Ecg);
    normacc(buf1, out, Ncg);
    hipMemsetAsync(buf0, 0, (size_t)(Ncg * D) * sizeof(float), stream);
    spmm(cg_rows, cg_cols, cg_vals, buf1, buf0, Ecg);
    normacc(buf0, out, Ncg);
    axcopy(buf0, learners, Lr * D, 1.f);
    axcopy(buf0 + Lr * D, concepts, Kr * D, 1.f);
    axcopy(acck, concepts, Kr * D, 1.f);
    hipMemsetAsync(buf1, 0, (size_t)(Nkg * D) * sizeof(float), stream);
    spmm(kg_rows, kg_cols, kg_vals, buf0, buf1, Ekg);
    normacc(buf1, out, Lr);
    normacc(buf1 + Lr * D, acck, Kr);
    hipMemsetAsync(buf0, 0, (size_t)(Nkg * D) * sizeof(float), stream);
    spmm(kg_rows, kg_cols, kg_vals, buf1, buf0, Ekg);
    normacc(buf0, out, Lr);
    normacc(buf0 + Lr * D, acck, Kr);
    spmm(ca_rows, ca_cols, ca_vals, acck, out + Lr * D, Eca);
    return;
  }

  float* h1     = (float*)(wsbase + o_share);   // also binned scratch (disjoint lifetime)
  int*   binned = wsbase + o_share;
  float* acck   = (float*)(wsbase + o_acck);
  int*   rp0    = wsbase + o_rp0;
  int*   rp1    = wsbase + o_rp1;
  int*   rp2    = wsbase + o_rp2;
  int*   cv0    = wsbase + o_cv0;
  int*   cv1    = wsbase + o_cv1;
  int*   cv2    = wsbase + o_cv2;
  int*   cnt    = wsbase + o_cnt;               // degrees, then row cursors
  float* scal   = (float*)(wsbase + o_scal);
  int*   part   = wsbase + o_part;
  int*   bcur   = wsbase + o_bcur;

  // bucket geometry
  const int NB0   = (int)((Lr + (1 << S0) - 1) >> S0);
  const int s1cg  = 8;   // 256 course rows / bucket
  const int s1kg  = 6;   // 64 concept rows / bucket
  const int NBcg  = NB0 + (int)((Cr + (1 << s1cg) - 1) >> s1cg);
  const int NBkg  = NB0 + (int)((Kr + (1 << s1kg) - 1) >> s1kg);

  ScanParams P;
  P.n0 = (int)Ncg; P.n1 = (int)Nkg; P.n2 = (int)Cr;
  P.cnt = cnt; P.scales = scal;
  P.rp0 = rp0; P.rp1 = rp1; P.rp2 = rp2;
  P.part = part;
  P.nb0 = (P.n0 + 1023) / 1024;
  P.nb1 = (P.n1 + 1023) / 1024;
  P.nb2 = (P.n2 + 1023) / 1024;
  P.ne0 = Ecg; P.ne1 = Ekg; P.ne2 = Eca;

  const long long ntot = Ncg + Nkg + Cr;
  const long long htot = EcgH + EkgH + Eca;
  const int hb = (int)(((htot + 255) / 256) < 4096 ? ((htot + 255) / 256) : 4096);
  const int nb = (int)((ntot + 255) / 256);

  // ---- build ----
  hipMemsetAsync(cnt, 0, (size_t)ntot * sizeof(int), stream);
  hist2_kernel<<<hb, 256, 0, stream>>>(cg_rows, cg_cols, EcgH, kg_rows, kg_cols, EkgH,
                                       ca_rows, Eca, cnt, (int)Ncg, (int)(Ncg + Nkg));
  scale_all_kernel<<<nb, 256, 0, stream>>>(P);
  scan1_seg_kernel<<<P.nb0 + P.nb1 + P.nb2, 256, 0, stream>>>(P);
  scan2_seg_kernel<<<3, 256, 0, stream>>>(P);
  scan3_seg_kernel<<<P.nb0 + P.nb1 + P.nb2, 256, 0, stream>>>(P);
  rowcur_init_kernel<<<nb, 256, 0, stream>>>(P);
  bucket_init_kernel<<<2, 256, 0, stream>>>(rp0, rp1, bcur, (int)Lr, NB0, s1cg, NBcg, s1kg, NBkg);

  // pass 1+2 for cg, then kg (binned scratch shared sequentially)
  {
    int blocks = (int)((EcgH + 256 * BCHUNK - 1) / (256 * BCHUNK));
    bin_kernel<<<blocks, 256, 0, stream>>>(cg_rows, cg_cols, EcgH, (int)Lr, s1cg, NB0, NBcg, bcur, binned);
    fine_kernel<<<NBcg << SPLITLOG, 256, 0, stream>>>(binned, rp0, cnt, cv0,
                                                      (int)Lr, (int)Ncg, s1cg, NB0, 0);
  }
  {
    int blocks = (int)((EkgH + 256 * BCHUNK - 1) / (256 * BCHUNK));
    bin_kernel<<<blocks, 256, 0, stream>>>(kg_rows, kg_cols, EkgH, (int)Lr, s1kg, NB0, NBkg, bcur + NBcg, binned);
    fine_kernel<<<NBkg << SPLITLOG, 256, 0, stream>>>(binned, rp1, cnt, cv1,
                                                      (int)Lr, (int)Nkg, s1kg, NB0, (int)Ncg);
  }
  scatter_ca_kernel<<<(int)((Eca + 255) / 256), 256, 0, stream>>>(ca_rows, ca_cols, cnt, cv2,
                                                                  Eca, (int)(Ncg + Nkg));

  // ---- init accumulators ----
  axcopy(out, learners, Lr * D, 2.f);            // feat0 of BOTH views for learner rows
  axcopy(out + Lr * D, courses, Cr * D, 1.f);
  axcopy(acck, concepts, Kr * D, 1.f);

  const float* sig_cg = scal;
  const float* sig_kg = scal + Ncg;
  const float* inv_ca = scal + Ncg + Nkg;

  // ---- course-grained view ----
  {
    int blocks = (int)((Ncg + 3) / 4);
    pull_kernel<0, 1><<<blocks, 256, 0, stream>>>(rp0, cv0, sig_cg, sig_cg,
                                                  learners, courses, (int)Lr,
                                                  h1, out, out, (int)Ncg, (int)Ncg);
    pull_kernel<1, 0><<<blocks, 256, 0, stream>>>(rp0, cv0, nullptr, nullptr,
                                                  h1, nullptr, 0,
                                                  nullptr, out, out, (int)Ncg, (int)Ncg);
  }

  // ---- concept-grained view ----
  {
    int blocks = (int)((Nkg + 3) / 4);
    pull_kernel<0, 1><<<blocks, 256, 0, stream>>>(rp1, cv1, sig_kg, sig_kg,
                                                  learners, concepts, (int)Lr,
                                                  h1, out, acck, (int)Lr, (int)Nkg);
    pull_kernel<1, 0><<<blocks, 256, 0, stream>>>(rp1, cv1, nullptr, nullptr,
                                                  h1, nullptr, 0,
                                                  nullptr, out, acck, (int)Lr, (int)Nkg);
  }

  // ---- aggregate concept features into course rows ----
  {
    int blocks = (int)((Cr + 3) / 4);
    pull_kernel<2, 0><<<blocks, 256, 0, stream>>>(rp2, cv2, inv_ca, nullptr,
                                                  acck, nullptr, 0,
                                                  nullptr, out + Lr * D, nullptr, (int)Cr, (int)Cr);
  }
}

// Round 6
// 1157.601 us; speedup vs baseline: 10.5169x; 1.2477x over previous
//
#include <hip/hip_runtime.h>

#define D 64
#define S0 10           // learner-side bucket shift (1024 rows/bucket)
#define BCHUNK 8        // edges per thread in bin pass
#define NHIST 8         // per-XCD private histogram copies

// ============================ element-wise utils ============================

__global__ __launch_bounds__(256) void axcopy_kernel(float* __restrict__ dst,
                                                     const float* __restrict__ src,
                                                     long long n4, float s) {
  long long i = (long long)blockIdx.x * blockDim.x + threadIdx.x;
  long long stride = (long long)gridDim.x * blockDim.x;
  for (; i < n4; i += stride) {
    float4 v = ((const float4*)src)[i];
    v.x *= s; v.y *= s; v.z *= s; v.w *= s;
    ((float4*)dst)[i] = v;
  }
}

// ============================ build: hist / scale / scan ============================

// Degrees from HALF the symmetric COO (mirror structure: rows=[a,b+L], cols=[b+L,a]).
// Atomics go to a per-XCD private copy (blockIdx&7 tracks round-robin XCD dispatch)
// so counter lines stay in ONE XCD's L2 instead of bouncing through HBM.
__global__ __launch_bounds__(256) void hist2_kernel(
    const int* __restrict__ cgr, const int* __restrict__ cgc, long long EcgH,
    const int* __restrict__ kgr, const int* __restrict__ kgc, long long EkgH,
    const int* __restrict__ car, long long Eca,
    int* __restrict__ cnt, int offKg, int offCa, int ntot) {
  int* mycnt = cnt + (long long)(blockIdx.x & (NHIST - 1)) * ntot;
  long long i = (long long)blockIdx.x * blockDim.x + threadIdx.x;
  long long stride = (long long)gridDim.x * blockDim.x;
  long long t01 = EcgH + EkgH, tot = t01 + Eca;
  for (; i < tot; i += stride) {
    if (i < EcgH) {
      atomicAdd(&mycnt[cgr[i]], 1);
      atomicAdd(&mycnt[cgc[i]], 1);
    } else if (i < t01) {
      long long j = i - EcgH;
      atomicAdd(&mycnt[offKg + kgr[j]], 1);
      atomicAdd(&mycnt[offKg + kgc[j]], 1);
    } else {
      long long j = i - t01;
      atomicAdd(&mycnt[offCa + car[j]], 1);
    }
  }
}

struct ScanParams {
  int n0, n1, n2;
  int* cnt;
  float* scales;
  int* rp0; int* rp1; int* rp2;
  int* part;
  int nb0, nb1, nb2;
  long long ne0, ne1, ne2;
};

// sum NHIST copies into copy 0; compute scales from the summed degree
__global__ __launch_bounds__(256) void scale_all_kernel(ScanParams P) {
  int ntot = P.n0 + P.n1 + P.n2;
  int nlap = P.n0 + P.n1;
  int i = blockIdx.x * blockDim.x + threadIdx.x;
  int stride = gridDim.x * blockDim.x;
  for (; i < ntot; i += stride) {
    int deg = 0;
    #pragma unroll
    for (int h = 0; h < NHIST; h++) deg += P.cnt[i + (long long)h * ntot];
    P.cnt[i] = deg;
    float c = (float)deg;
    P.scales[i] = (i < nlap) ? 1.0f / (sqrtf(c) + 1e-8f)
                             : 1.0f / (c + 1e-8f);
  }
}

__global__ __launch_bounds__(256) void scan1_seg_kernel(ScanParams P) {
  __shared__ int lds[256];
  int b = blockIdx.x, t = threadIdx.x;
  int lb, n, coff, poff; int* rp;
  if (b < P.nb0)               { lb = b;                 n = P.n0; coff = 0;           poff = 0;             rp = P.rp0; }
  else if (b < P.nb0 + P.nb1)  { lb = b - P.nb0;         n = P.n1; coff = P.n0;        poff = P.nb0;         rp = P.rp1; }
  else                         { lb = b - P.nb0 - P.nb1; n = P.n2; coff = P.n0 + P.n1; poff = P.nb0 + P.nb1; rp = P.rp2; }
  int base = lb * 1024 + t * 4;
  int v[4]; int s = 0;
  #pragma unroll
  for (int j = 0; j < 4; j++) { int idx = base + j; v[j] = (idx < n) ? P.cnt[coff + idx] : 0; s += v[j]; }
  lds[t] = s;
  __syncthreads();
  for (int off = 1; off < 256; off <<= 1) {
    int x = (t >= off) ? lds[t - off] : 0;
    __syncthreads();
    lds[t] += x;
    __syncthreads();
  }
  int run = (t == 0) ? 0 : lds[t - 1];
  if (t == 255) P.part[poff + lb] = lds[255];
  #pragma unroll
  for (int j = 0; j < 4; j++) { int idx = base + j; if (idx < n) rp[idx] = run; run += v[j]; }
}

__global__ __launch_bounds__(256) void scan2_seg_kernel(ScanParams P) {
  __shared__ int lds[256];
  int g = blockIdx.x, t = threadIdx.x;
  int nb = (g == 0) ? P.nb0 : (g == 1) ? P.nb1 : P.nb2;
  int poff = (g == 0) ? 0 : (g == 1) ? P.nb0 : P.nb0 + P.nb1;
  lds[t] = (t < nb) ? P.part[poff + t] : 0;
  __syncthreads();
  for (int off = 1; off < 256; off <<= 1) {
    int x = (t >= off) ? lds[t - off] : 0;
    __syncthreads();
    lds[t] += x;
    __syncthreads();
  }
  if (t < nb) P.part[poff + t] = (t == 0) ? 0 : lds[t - 1];
}

__global__ __launch_bounds__(256) void scan3_seg_kernel(ScanParams P) {
  int b = blockIdx.x, t = threadIdx.x;
  int lb, n, poff; int* rp; long long ne;
  if (b < P.nb0)               { lb = b;                 n = P.n0; poff = 0;             rp = P.rp0; ne = P.ne0; }
  else if (b < P.nb0 + P.nb1)  { lb = b - P.nb0;         n = P.n1; poff = P.nb0;         rp = P.rp1; ne = P.ne1; }
  else                         { lb = b - P.nb0 - P.nb1; n = P.n2; poff = P.nb0 + P.nb1; rp = P.rp2; ne = P.ne2; }
  int add = P.part[poff + lb];
  int base = lb * 1024 + t * 4;
  #pragma unroll
  for (int j = 0; j < 4; j++) { int idx = base + j; if (idx < n) rp[idx] += add; }
  if (lb == 0 && t == 0) rp[n] = (int)ne;
}

// ca-graph row cursors (only graph still needing global cursors)
__global__ __launch_bounds__(256) void rowcur_ca_kernel(const int* __restrict__ rp2,
                                                        int* __restrict__ cur, int n2) {
  int i = blockIdx.x * blockDim.x + threadIdx.x;
  if (i < n2) cur[i] = rp2[i];
}

// bin-pass bucket cursors: bcur[b] = rp[rowbase(b)]
__global__ __launch_bounds__(256) void bucket_init_kernel(
    const int* __restrict__ rp0, const int* __restrict__ rp1, int* __restrict__ bcur,
    int L, int NB0, int s1cg, int NBcg, int s1kg, int NBkg) {
  int i = blockIdx.x * blockDim.x + threadIdx.x;
  if (i < NBcg) {
    int rowbase = (i < NB0) ? (i << S0) : (L + ((i - NB0) << s1cg));
    bcur[i] = rp0[rowbase];
  } else if (i < NBcg + NBkg) {
    int j = i - NBcg;
    int rowbase = (j < NB0) ? (j << S0) : (L + ((j - NB0) << s1kg));
    bcur[i] = rp1[rowbase];
  }
}

// ============================ pass 1: LDS-aggregated binning ============================
// Reads the FIRST HALF of the symmetric COO; emits two packed entries per edge:
//   side0 bucket of a: (a&1023)<<17 | c       side1 bucket of c: ((c-L)&mask)<<17 | a
__global__ __launch_bounds__(256) void bin_kernel(
    const int* __restrict__ rowsA, const int* __restrict__ colsA, long long E,
    int L, int s1, int NB0, int NBtot,
    int* __restrict__ gcur, int* __restrict__ binned) {
  __shared__ int cnt[256];
  __shared__ int gbase[256];
  int t = threadIdx.x;
  long long base = (long long)blockIdx.x * (256 * BCHUNK);
  cnt[t] = 0;
  __syncthreads();
  int av[BCHUNK], cv_[BCHUNK], l0[BCHUNK], l1[BCHUNK];
  #pragma unroll
  for (int k = 0; k < BCHUNK; k++) {
    long long i = base + (long long)k * 256 + t;
    bool ok = i < E;
    int a = ok ? rowsA[i] : 0;
    int c = ok ? colsA[i] : L;
    av[k] = a; cv_[k] = c;
    if (ok) {
      int b0 = a >> S0;
      int b1 = NB0 + ((c - L) >> s1);
      l0[k] = atomicAdd(&cnt[b0], 1);
      l1[k] = atomicAdd(&cnt[b1], 1);
    } else { l0[k] = 0; l1[k] = 0; }
  }
  __syncthreads();
  if (t < NBtot) gbase[t] = cnt[t] ? atomicAdd(&gcur[t], cnt[t]) : 0;
  __syncthreads();
  #pragma unroll
  for (int k = 0; k < BCHUNK; k++) {
    long long i = base + (long long)k * 256 + t;
    if (i < E) {
      int a = av[k], c = cv_[k];
      int b0 = a >> S0;
      int b1 = NB0 + ((c - L) >> s1);
      binned[gbase[b0] + l0[k]] = ((a & ((1 << S0) - 1)) << 17) | c;
      binned[gbase[b1] + l1[k]] = (((c - L) & ((1 << s1) - 1)) << 17) | a;
    }
  }
}

// ============================ pass 2: fine scatter, one block per bucket ============================
// Row cursors live in LDS (bucket <= 1024 rows): zero global cursor atomics,
// data writes confined to the bucket's L2-resident CSR window.
__global__ __launch_bounds__(1024) void fine_kernel(
    const int* __restrict__ binned, const int* __restrict__ rp,
    int* __restrict__ cvout, int L, int sideEnd, int s1, int NB0) {
  __shared__ int cur[1 << S0];
  int bucket = blockIdx.x;
  int rowbase, rowend;
  if (bucket < NB0) { rowbase = bucket << S0; rowend = min(rowbase + (1 << S0), L); }
  else { int bb = bucket - NB0; rowbase = L + (bb << s1); rowend = min(rowbase + (1 << s1), sideEnd); }
  int nrows = rowend - rowbase;
  for (int r = threadIdx.x; r < nrows; r += 1024) cur[r] = rp[rowbase + r];
  __syncthreads();
  int start = rp[rowbase], end = rp[rowend];
  for (int i = start + threadIdx.x; i < end; i += 1024) {
    int w = binned[i];
    int p = atomicAdd(&cur[w >> 17], 1);
    cvout[p] = w & 0x1FFFF;
  }
}

// direct scatter for the small ca graph
__global__ __launch_bounds__(256) void scatter_ca_kernel(
    const int* __restrict__ rows, const int* __restrict__ cols,
    int* __restrict__ rowcur, int* __restrict__ cv, long long ne) {
  long long e = (long long)blockIdx.x * blockDim.x + threadIdx.x;
  if (e >= ne) return;
  int p = atomicAdd(&rowcur[rows[e]], 1);
  cv[p] = cols[e];
}

// ============================ pull SpMM ============================
// One wave per row, lane = feature dim.
// MODE 0: h_out[row] = scaleRow[row]^2 * sraw; acc += unit(sraw)
// MODE 1: acc += unit(sraw)
// MODE 2: accA[row] += scaleRow[row] * sraw
// FUSE 1: sraw terms = sigCol[c] * raw_feat(c)  (raw feats split at Lsplit into fA/fB)
template <int MODE, int FUSE>
__global__ __launch_bounds__(256) void pull_kernel(
    const int* __restrict__ rowptr, const int* __restrict__ cols,
    const float* __restrict__ scaleRow, const float* __restrict__ sigCol,
    const float* __restrict__ fA, const float* __restrict__ fB, int Lsplit,
    float* __restrict__ h_out, float* __restrict__ accA, float* __restrict__ accB,
    int splitAcc, int nrows) {
  int row = blockIdx.x * 4 + (threadIdx.x >> 6);
  if (row >= nrows) return;
  int lane = threadIdx.x & 63;
  int e0 = rowptr[row], e1 = rowptr[row + 1];
  float s = 0.f;
  int e = e0;
  #define FETCH(c) (FUSE ? (sigCol[c] * ((c) < Lsplit ? fA[(long long)(c) * D + lane] \
                                                      : fB[(long long)((c) - Lsplit) * D + lane])) \
                         : fA[(long long)(c) * D + lane])
  for (; e + 3 < e1; e += 4) {
    int c0 = cols[e], c1 = cols[e + 1], c2 = cols[e + 2], c3 = cols[e + 3];
    s += FETCH(c0); s += FETCH(c1); s += FETCH(c2); s += FETCH(c3);
  }
  for (; e < e1; ++e) { int c = cols[e]; s += FETCH(c); }
  #undef FETCH

  if (MODE == 2) {
    accA[(long long)row * D + lane] += scaleRow[row] * s;
    return;
  }
  if (MODE == 0) {
    float sc = scaleRow[row];
    h_out[(long long)row * D + lane] = sc * sc * s;
  }
  float q = s * s;
  #pragma unroll
  for (int off = 32; off; off >>= 1) q += __shfl_xor(q, off);
  float r = 1.0f / fmaxf(sqrtf(q), 1e-12f);
  float* acc = (row < splitAcc) ? accA + (long long)row * D
                                : accB + (long long)(row - splitAcc) * D;
  acc[lane] += s * r;
}

// ============================ fallback (atomic push path) ============================

__global__ __launch_bounds__(256) void spmm_atomic_kernel(
    const int* __restrict__ rows, const int* __restrict__ cols,
    const float* __restrict__ vals, const float* __restrict__ feat,
    float* __restrict__ outp, long long ne) {
  long long t = (long long)blockIdx.x * blockDim.x + threadIdx.x;
  long long e = t >> 4;
  if (e >= ne) return;
  int lane = (int)(t & 15);
  int r = rows[e];
  int c = cols[e];
  float v = vals[e];
  const float4 f = *(const float4*)(feat + (long long)c * D + lane * 4);
  float* o = outp + (long long)r * D + lane * 4;
  atomicAdd(o + 0, v * f.x);
  atomicAdd(o + 1, v * f.y);
  atomicAdd(o + 2, v * f.z);
  atomicAdd(o + 3, v * f.w);
}

__global__ __launch_bounds__(256) void norm_acc_kernel(const float* __restrict__ feat,
                                                       float* __restrict__ acc,
                                                       int nrows) {
  int row = blockIdx.x * 4 + (threadIdx.x >> 6);
  if (row >= nrows) return;
  int lane = threadIdx.x & 63;
  float x = feat[(long long)row * D + lane];
  float s = x * x;
  #pragma unroll
  for (int off = 32; off; off >>= 1) s += __shfl_xor(s, off);
  float sc = 1.0f / fmaxf(sqrtf(s), 1e-12f);
  acc[(long long)row * D + lane] += x * sc;
}

// ============================ launch ============================

extern "C" void kernel_launch(void* const* d_in, const int* in_sizes, int n_in,
                              void* d_out, int out_size, void* d_ws, size_t ws_size,
                              hipStream_t stream) {
  const float* learners = (const float*)d_in[0];
  const float* courses  = (const float*)d_in[1];
  const float* concepts = (const float*)d_in[2];
  const int*   cg_rows  = (const int*)d_in[3];
  const int*   cg_cols  = (const int*)d_in[4];
  const int*   kg_rows  = (const int*)d_in[6];
  const int*   kg_cols  = (const int*)d_in[7];
  const int*   ca_rows  = (const int*)d_in[9];
  const int*   ca_cols  = (const int*)d_in[10];
  const float* cg_vals  = (const float*)d_in[5];
  const float* kg_vals  = (const float*)d_in[8];
  const float* ca_vals  = (const float*)d_in[11];

  const long long Lr  = in_sizes[0] / D;
  const long long Cr  = in_sizes[1] / D;
  const long long Kr  = in_sizes[2] / D;
  const long long Ecg = in_sizes[3];      // full (2x bipartite)
  const long long Ekg = in_sizes[6];
  const long long Eca = in_sizes[9];
  const long long EcgH = Ecg / 2;
  const long long EkgH = Ekg / 2;
  const long long Ncg = Lr + Cr;
  const long long Nkg = Lr + Kr;

  float* out = (float*)d_out;

  // bucket geometry
  const int NB0   = (int)((Lr + (1 << S0) - 1) >> S0);
  const int s1cg  = 8;   // 256 course rows / bucket
  const int s1kg  = 6;   // 64 concept rows / bucket
  const int NBcg  = NB0 + (int)((Cr + (1 << s1cg) - 1) >> s1cg);
  const int NBkg  = NB0 + (int)((Kr + (1 << s1kg) - 1) >> s1kg);

  // ---- workspace layout (words) ----
  long long maxE2 = (Ecg > Ekg ? Ecg : Ekg);
  long long shareW = Ncg * D > maxE2 ? Ncg * D : maxE2;   // h1 buffer / binned scratch
  size_t need = 0;
  auto walloc = [&](long long elems) { size_t off = need; need += ((size_t)elems + 3) & ~(size_t)3; return off; };
  int* wsbase = (int*)d_ws;
  size_t o_share = walloc(shareW);
  size_t o_acck  = walloc(Kr * D);
  size_t o_rp0   = walloc(Ncg + 1);
  size_t o_rp1   = walloc(Nkg + 1);
  size_t o_rp2   = walloc(Cr + 1);
  size_t o_cv0   = walloc(Ecg);
  size_t o_cv1   = walloc(Ekg);
  size_t o_cv2   = walloc(Eca);
  size_t o_cnt   = walloc((Ncg + Nkg + Cr) * NHIST);
  size_t o_scal  = walloc(Ncg + Nkg + Cr);
  size_t o_part  = walloc(512);
  size_t o_bcur  = walloc(512);
  size_t o_cacur = walloc(Cr);

  auto axcopy = [&](float* dst, const float* src, long long n, float s) {
    long long n4 = n / 4;
    long long b = (n4 + 255) / 256;
    int blocks = (int)(b < 2048 ? b : 2048);
    axcopy_kernel<<<blocks, 256, 0, stream>>>(dst, src, n4, s);
  };

  bool packable = (Ncg <= 131072) && (Nkg <= 131072) && (Lr % 2 == 0) &&
                  (NBcg <= 256) && (NBkg <= 256);
  if (need * 4 > ws_size || !packable) {
    // -------- fallback: atomic push path (correct for any shape) --------
    float* buf0 = (float*)d_ws;
    float* buf1 = buf0 + Ncg * D;
    float* acck = buf1 + Ncg * D;
    auto spmm = [&](const int* r, const int* c, const float* v, const float* f,
                    float* o, long long ne) {
      long long threads = ne * 16;
      int blocks = (int)((threads + 255) / 256);
      spmm_atomic_kernel<<<blocks, 256, 0, stream>>>(r, c, v, f, o, ne);
    };
    auto normacc = [&](const float* f, float* a, long long nrows) {
      int blocks = (int)((nrows + 3) / 4);
      norm_acc_kernel<<<blocks, 256, 0, stream>>>(f, a, (int)nrows);
    };
    axcopy(buf0, learners, Lr * D, 1.f);
    axcopy(buf0 + Lr * D, courses, Cr * D, 1.f);
    axcopy(out, learners, Lr * D, 2.f);
    axcopy(out + Lr * D, courses, Cr * D, 1.f);
    hipMemsetAsync(buf1, 0, (size_t)(Ncg * D) * sizeof(float), stream);
    spmm(cg_rows, cg_cols, cg_vals, buf0, buf1, Ecg);
    normacc(buf1, out, Ncg);
    hipMemsetAsync(buf0, 0, (size_t)(Ncg * D) * sizeof(float), stream);
    spmm(cg_rows, cg_cols, cg_vals, buf1, buf0, Ecg);
    normacc(buf0, out, Ncg);
    axcopy(buf0, learners, Lr * D, 1.f);
    axcopy(buf0 + Lr * D, concepts, Kr * D, 1.f);
    axcopy(acck, concepts, Kr * D, 1.f);
    hipMemsetAsync(buf1, 0, (size_t)(Nkg * D) * sizeof(float), stream);
    spmm(kg_rows, kg_cols, kg_vals, buf0, buf1, Ekg);
    normacc(buf1, out, Lr);
    normacc(buf1 + Lr * D, acck, Kr);
    hipMemsetAsync(buf0, 0, (size_t)(Nkg * D) * sizeof(float), stream);
    spmm(kg_rows, kg_cols, kg_vals, buf1, buf0, Ekg);
    normacc(buf0, out, Lr);
    normacc(buf0 + Lr * D, acck, Kr);
    spmm(ca_rows, ca_cols, ca_vals, acck, out + Lr * D, Eca);
    return;
  }

  float* h1     = (float*)(wsbase + o_share);   // also binned scratch (disjoint lifetime)
  int*   binned = wsbase + o_share;
  float* acck   = (float*)(wsbase + o_acck);
  int*   rp0    = wsbase + o_rp0;
  int*   rp1    = wsbase + o_rp1;
  int*   rp2    = wsbase + o_rp2;
  int*   cv0    = wsbase + o_cv0;
  int*   cv1    = wsbase + o_cv1;
  int*   cv2    = wsbase + o_cv2;
  int*   cnt    = wsbase + o_cnt;
  float* scal   = (float*)(wsbase + o_scal);
  int*   part   = wsbase + o_part;
  int*   bcur   = wsbase + o_bcur;
  int*   cacur  = wsbase + o_cacur;

  ScanParams P;
  P.n0 = (int)Ncg; P.n1 = (int)Nkg; P.n2 = (int)Cr;
  P.cnt = cnt; P.scales = scal;
  P.rp0 = rp0; P.rp1 = rp1; P.rp2 = rp2;
  P.part = part;
  P.nb0 = (P.n0 + 1023) / 1024;
  P.nb1 = (P.n1 + 1023) / 1024;
  P.nb2 = (P.n2 + 1023) / 1024;
  P.ne0 = Ecg; P.ne1 = Ekg; P.ne2 = Eca;

  const long long ntot = Ncg + Nkg + Cr;
  const long long htot = EcgH + EkgH + Eca;
  const int hb = (int)(((htot + 255) / 256) < 4096 ? ((htot + 255) / 256) : 4096);
  const int nb = (int)((ntot + 255) / 256);

  // ---- build ----
  hipMemsetAsync(cnt, 0, (size_t)ntot * NHIST * sizeof(int), stream);
  hist2_kernel<<<hb, 256, 0, stream>>>(cg_rows, cg_cols, EcgH, kg_rows, kg_cols, EkgH,
                                       ca_rows, Eca, cnt, (int)Ncg, (int)(Ncg + Nkg), (int)ntot);
  scale_all_kernel<<<nb, 256, 0, stream>>>(P);
  scan1_seg_kernel<<<P.nb0 + P.nb1 + P.nb2, 256, 0, stream>>>(P);
  scan2_seg_kernel<<<3, 256, 0, stream>>>(P);
  scan3_seg_kernel<<<P.nb0 + P.nb1 + P.nb2, 256, 0, stream>>>(P);
  rowcur_ca_kernel<<<(int)((Cr + 255) / 256), 256, 0, stream>>>(rp2, cacur, (int)Cr);
  bucket_init_kernel<<<2, 256, 0, stream>>>(rp0, rp1, bcur, (int)Lr, NB0, s1cg, NBcg, s1kg, NBkg);

  // pass 1+2 for cg, then kg (binned scratch shared sequentially)
  {
    int blocks = (int)((EcgH + 256 * BCHUNK - 1) / (256 * BCHUNK));
    bin_kernel<<<blocks, 256, 0, stream>>>(cg_rows, cg_cols, EcgH, (int)Lr, s1cg, NB0, NBcg, bcur, binned);
    fine_kernel<<<NBcg, 1024, 0, stream>>>(binned, rp0, cv0, (int)Lr, (int)Ncg, s1cg, NB0);
  }
  {
    int blocks = (int)((EkgH + 256 * BCHUNK - 1) / (256 * BCHUNK));
    bin_kernel<<<blocks, 256, 0, stream>>>(kg_rows, kg_cols, EkgH, (int)Lr, s1kg, NB0, NBkg, bcur + NBcg, binned);
    fine_kernel<<<NBkg, 1024, 0, stream>>>(binned, rp1, cv1, (int)Lr, (int)Nkg, s1kg, NB0);
  }
  scatter_ca_kernel<<<(int)((Eca + 255) / 256), 256, 0, stream>>>(ca_rows, ca_cols, cacur, cv2, Eca);

  // ---- init accumulators ----
  axcopy(out, learners, Lr * D, 2.f);            // feat0 of BOTH views for learner rows
  axcopy(out + Lr * D, courses, Cr * D, 1.f);
  axcopy(acck, concepts, Kr * D, 1.f);

  const float* sig_cg = scal;
  const float* sig_kg = scal + Ncg;
  const float* inv_ca = scal + Ncg + Nkg;

  // ---- course-grained view ----
  {
    int blocks = (int)((Ncg + 3) / 4);
    pull_kernel<0, 1><<<blocks, 256, 0, stream>>>(rp0, cv0, sig_cg, sig_cg,
                                                  learners, courses, (int)Lr,
                                                  h1, out, out, (int)Ncg, (int)Ncg);
    pull_kernel<1, 0><<<blocks, 256, 0, stream>>>(rp0, cv0, nullptr, nullptr,
                                                  h1, nullptr, 0,
                                                  nullptr, out, out, (int)Ncg, (int)Ncg);
  }

  // ---- concept-grained view ----
  {
    int blocks = (int)((Nkg + 3) / 4);
    pull_kernel<0, 1><<<blocks, 256, 0, stream>>>(rp1, cv1, sig_kg, sig_kg,
                                                  learners, concepts, (int)Lr,
                                                  h1, out, acck, (int)Lr, (int)Nkg);
    pull_kernel<1, 0><<<blocks, 256, 0, stream>>>(rp1, cv1, nullptr, nullptr,
                                                  h1, nullptr, 0,
                                                  nullptr, out, acck, (int)Lr, (int)Nkg);
  }

  // ---- aggregate concept features into course rows ----
  {
    int blocks = (int)((Cr + 3) / 4);
    pull_kernel<2, 0><<<blocks, 256, 0, stream>>>(rp2, cv2, inv_ca, nullptr,
                                                  acck, nullptr, 0,
                                                  nullptr, out + Lr * D, nullptr, (int)Cr, (int)Cr);
  }
}

// Round 7
// 908.996 us; speedup vs baseline: 13.3932x; 1.2735x over previous
//
#include <hip/hip_runtime.h>

#define D 64
#define S0 10           // learner-side bucket shift (1024 rows/bucket)
#define BCHUNK 8        // edges per thread in bin pass

// bkt[] layout (ints): [0,256) cg bucket counts | [256,512) kg bucket counts |
// [512,772) cg bucket bases (+sentinel) | [772,1032) kg bases (+sentinel) |
// [1032,1288) cg bin cursors | [1288,1544) kg bin cursors
#define BKT_CNTCG 0
#define BKT_CNTKG 256
#define BKT_BASECG 512
#define BKT_BASEKG 772
#define BKT_CURCG 1032
#define BKT_CURKG 1288
#define BKT_WORDS 2048

// ============================ element-wise utils ============================

__global__ __launch_bounds__(256) void axcopy_kernel(float* __restrict__ dst,
                                                     const float* __restrict__ src,
                                                     long long n4, float s) {
  long long i = (long long)blockIdx.x * blockDim.x + threadIdx.x;
  long long stride = (long long)gridDim.x * blockDim.x;
  for (; i < n4; i += stride) {
    float4 v = ((const float4*)src)[i];
    v.x *= s; v.y *= s; v.z *= s; v.w *= s;
    ((float4*)dst)[i] = v;
  }
}

// ============================ build ============================

// Pass A: bucket-occupancy counts in LDS (512 bins), one flush per block.
// Reads HALF the symmetric COO (mirror structure: rows=[a,b+L], cols=[b+L,a]).
// ca degrees counted with direct global atomics (only 200K of them).
__global__ __launch_bounds__(1024) void bincnt_kernel(
    const int* __restrict__ cgr, const int* __restrict__ cgc, long long EcgH,
    const int* __restrict__ kgr, const int* __restrict__ kgc, long long EkgH,
    const int* __restrict__ car, long long Eca,
    int* __restrict__ bkt, int* __restrict__ cadeg,
    int L, int NB0, int s1cg, int s1kg) {
  __shared__ int h[512];
  int t = threadIdx.x;
  if (t < 512) h[t] = 0;
  __syncthreads();
  long long i = (long long)blockIdx.x * blockDim.x + t;
  long long stride = (long long)gridDim.x * blockDim.x;
  long long t01 = EcgH + EkgH, tot = t01 + Eca;
  for (; i < tot; i += stride) {
    if (i < EcgH) {
      int a = cgr[i], c = cgc[i];
      atomicAdd(&h[a >> S0], 1);
      atomicAdd(&h[NB0 + ((c - L) >> s1cg)], 1);
    } else if (i < t01) {
      long long j = i - EcgH;
      int a = kgr[j], c = kgc[j];
      atomicAdd(&h[256 + (a >> S0)], 1);
      atomicAdd(&h[256 + NB0 + ((c - L) >> s1kg)], 1);
    } else {
      long long j = i - t01;
      atomicAdd(&cadeg[car[j]], 1);
    }
  }
  __syncthreads();
  if (t < 512 && h[t]) atomicAdd(&bkt[t], h[t]);
}

// Single-block exclusive scan of bucket counts -> bases (+sentinel) + bin cursors.
__global__ __launch_bounds__(256) void bktscan_kernel(int* __restrict__ bkt,
                                                      int NBcg, int NBkg) {
  __shared__ int lds[256];
  int t = threadIdx.x;
  #pragma unroll
  for (int g = 0; g < 2; ++g) {
    int NB      = g ? NBkg : NBcg;
    int cntoff  = g ? BKT_CNTKG : BKT_CNTCG;
    int baseoff = g ? BKT_BASEKG : BKT_BASECG;
    int curoff  = g ? BKT_CURKG : BKT_CURCG;
    lds[t] = (t < NB) ? bkt[cntoff + t] : 0;
    __syncthreads();
    for (int off = 1; off < 256; off <<= 1) {
      int x = (t >= off) ? lds[t - off] : 0;
      __syncthreads();
      lds[t] += x;
      __syncthreads();
    }
    int excl = (t == 0) ? 0 : lds[t - 1];
    if (t < NB) { bkt[baseoff + t] = excl; bkt[curoff + t] = excl; }
    if (t == NB - 1) bkt[baseoff + NB] = lds[t];
    __syncthreads();
  }
}

// ca scans (rowptr + inv-degree scale + cursors), tile = 1024
__global__ __launch_bounds__(256) void ca_scan1_kernel(const int* __restrict__ deg,
                                                       int* __restrict__ rp,
                                                       float* __restrict__ scal,
                                                       int* __restrict__ part, int n) {
  __shared__ int lds[256];
  int b = blockIdx.x, t = threadIdx.x;
  int base = b * 1024 + t * 4;
  int v[4]; int s = 0;
  #pragma unroll
  for (int j = 0; j < 4; j++) {
    int idx = base + j;
    v[j] = (idx < n) ? deg[idx] : 0;
    if (idx < n) scal[idx] = 1.0f / ((float)v[j] + 1e-8f);
    s += v[j];
  }
  lds[t] = s;
  __syncthreads();
  for (int off = 1; off < 256; off <<= 1) {
    int x = (t >= off) ? lds[t - off] : 0;
    __syncthreads();
    lds[t] += x;
    __syncthreads();
  }
  int run = (t == 0) ? 0 : lds[t - 1];
  if (t == 255) part[b] = lds[255];
  #pragma unroll
  for (int j = 0; j < 4; j++) { int idx = base + j; if (idx < n) rp[idx] = run; run += v[j]; }
}

__global__ __launch_bounds__(256) void ca_scan2_kernel(int* __restrict__ part, int nb) {
  __shared__ int lds[256];
  int t = threadIdx.x;
  lds[t] = (t < nb) ? part[t] : 0;
  __syncthreads();
  for (int off = 1; off < 256; off <<= 1) {
    int x = (t >= off) ? lds[t - off] : 0;
    __syncthreads();
    lds[t] += x;
    __syncthreads();
  }
  if (t < nb) part[t] = (t == 0) ? 0 : lds[t - 1];
}

__global__ __launch_bounds__(256) void ca_scan3_kernel(int* __restrict__ rp,
                                                       const int* __restrict__ part,
                                                       int* __restrict__ cacur,
                                                       int n, int total) {
  int b = blockIdx.x, t = threadIdx.x;
  int add = part[b];
  int base = b * 1024 + t * 4;
  #pragma unroll
  for (int j = 0; j < 4; j++) {
    int idx = base + j;
    if (idx < n) { int f = rp[idx] + add; rp[idx] = f; cacur[idx] = f; }
  }
  if (b == 0 && t == 0) rp[n] = total;
}

// Pass B: LDS-aggregated binning. Reads half-COO, emits two packed entries/edge:
//   side0 bucket of a: (a&1023)<<17 | c       side1 bucket of c: ((c-L)&mask)<<17 | a
__global__ __launch_bounds__(256) void bin_kernel(
    const int* __restrict__ rowsA, const int* __restrict__ colsA, long long E,
    int L, int s1, int NB0, int NBtot,
    int* __restrict__ gcur, int* __restrict__ binned) {
  __shared__ int cnt[256];
  __shared__ int gbase[256];
  int t = threadIdx.x;
  long long base = (long long)blockIdx.x * (256 * BCHUNK);
  cnt[t] = 0;
  __syncthreads();
  int av[BCHUNK], cv_[BCHUNK], l0[BCHUNK], l1[BCHUNK];
  #pragma unroll
  for (int k = 0; k < BCHUNK; k++) {
    long long i = base + (long long)k * 256 + t;
    bool ok = i < E;
    int a = ok ? rowsA[i] : 0;
    int c = ok ? colsA[i] : L;
    av[k] = a; cv_[k] = c;
    if (ok) {
      int b0 = a >> S0;
      int b1 = NB0 + ((c - L) >> s1);
      l0[k] = atomicAdd(&cnt[b0], 1);
      l1[k] = atomicAdd(&cnt[b1], 1);
    } else { l0[k] = 0; l1[k] = 0; }
  }
  __syncthreads();
  if (t < NBtot) gbase[t] = cnt[t] ? atomicAdd(&gcur[t], cnt[t]) : 0;
  __syncthreads();
  #pragma unroll
  for (int k = 0; k < BCHUNK; k++) {
    long long i = base + (long long)k * 256 + t;
    if (i < E) {
      int a = av[k], c = cv_[k];
      int b0 = a >> S0;
      int b1 = NB0 + ((c - L) >> s1);
      binned[gbase[b0] + l0[k]] = ((a & ((1 << S0) - 1)) << 17) | c;
      binned[gbase[b1] + l1[k]] = (((c - L) & ((1 << s1) - 1)) << 17) | a;
    }
  }
}

// Pass C: per-bucket finalize. Counts per-row degrees in LDS, LDS-scans to get
// rowptr (+ writes Laplacian sigma), then scatters with LDS cursors.
// Zero global atomics. bktbase[b] is both binned offset AND CSR offset.
__global__ __launch_bounds__(1024) void fine2_kernel(
    const int* __restrict__ binned, const int* __restrict__ bktbase,
    int* __restrict__ rp, int* __restrict__ cvout, float* __restrict__ scal,
    int L, int sideEnd, int s1, int NB0, int nfull) {
  __shared__ int cnt[1 << S0];
  int b = blockIdx.x, t = threadIdx.x;
  int rowbase, rowend;
  if (b < NB0) { rowbase = b << S0; rowend = min(rowbase + (1 << S0), L); }
  else { int bb = b - NB0; rowbase = L + (bb << s1); rowend = min(rowbase + (1 << s1), sideEnd); }
  int nrows = rowend - rowbase;
  int base = bktbase[b], end = bktbase[b + 1];
  cnt[t] = 0;
  __syncthreads();
  for (int i = base + t; i < end; i += 1024) atomicAdd(&cnt[binned[i] >> 17], 1);
  __syncthreads();
  int deg = cnt[t];
  for (int off = 1; off < 1024; off <<= 1) {
    int x = (t >= off) ? cnt[t - off] : 0;
    __syncthreads();
    cnt[t] += x;
    __syncthreads();
  }
  int excl = (t == 0) ? 0 : cnt[t - 1];
  int pos = base + excl;
  __syncthreads();
  cnt[t] = pos;            // reuse as row cursor
  if (t < nrows) {
    rp[rowbase + t] = pos;
    scal[rowbase + t] = 1.0f / (sqrtf((float)deg) + 1e-8f);
  }
  if (b == gridDim.x - 1 && t == 0) rp[nfull] = end;
  __syncthreads();
  for (int i = base + t; i < end; i += 1024) {
    int w = binned[i];
    int p = atomicAdd(&cnt[w >> 17], 1);
    cvout[p] = w & 0x1FFFF;
  }
}

// direct scatter for the small ca graph
__global__ __launch_bounds__(256) void scatter_ca_kernel(
    const int* __restrict__ rows, const int* __restrict__ cols,
    int* __restrict__ rowcur, int* __restrict__ cv, long long ne) {
  long long e = (long long)blockIdx.x * blockDim.x + threadIdx.x;
  if (e >= ne) return;
  int p = atomicAdd(&rowcur[rows[e]], 1);
  cv[p] = cols[e];
}

// ============================ pull SpMM ============================
// One wave per row, lane = feature dim.
// MODE 0: h_out[row] = scaleRow[row]^2 * sraw; acc += unit(sraw)
// MODE 1: acc += unit(sraw)
// MODE 2: accA[row] += scaleRow[row] * sraw
// FUSE 1: sraw terms = sigCol[c] * raw_feat(c)  (raw feats split at Lsplit into fA/fB)
template <int MODE, int FUSE>
__global__ __launch_bounds__(256) void pull_kernel(
    const int* __restrict__ rowptr, const int* __restrict__ cols,
    const float* __restrict__ scaleRow, const float* __restrict__ sigCol,
    const float* __restrict__ fA, const float* __restrict__ fB, int Lsplit,
    float* __restrict__ h_out, float* __restrict__ accA, float* __restrict__ accB,
    int splitAcc, int nrows) {
  int row = blockIdx.x * 4 + (threadIdx.x >> 6);
  if (row >= nrows) return;
  int lane = threadIdx.x & 63;
  int e0 = rowptr[row], e1 = rowptr[row + 1];
  float s = 0.f;
  int e = e0;
  #define FETCH(c) (FUSE ? (sigCol[c] * ((c) < Lsplit ? fA[(long long)(c) * D + lane] \
                                                      : fB[(long long)((c) - Lsplit) * D + lane])) \
                         : fA[(long long)(c) * D + lane])
  for (; e + 3 < e1; e += 4) {
    int c0 = cols[e], c1 = cols[e + 1], c2 = cols[e + 2], c3 = cols[e + 3];
    s += FETCH(c0); s += FETCH(c1); s += FETCH(c2); s += FETCH(c3);
  }
  for (; e < e1; ++e) { int c = cols[e]; s += FETCH(c); }
  #undef FETCH

  if (MODE == 2) {
    accA[(long long)row * D + lane] += scaleRow[row] * s;
    return;
  }
  if (MODE == 0) {
    float sc = scaleRow[row];
    h_out[(long long)row * D + lane] = sc * sc * s;
  }
  float q = s * s;
  #pragma unroll
  for (int off = 32; off; off >>= 1) q += __shfl_xor(q, off);
  float r = 1.0f / fmaxf(sqrtf(q), 1e-12f);
  float* acc = (row < splitAcc) ? accA + (long long)row * D
                                : accB + (long long)(row - splitAcc) * D;
  acc[lane] += s * r;
}

// ============================ fallback (atomic push path) ============================

__global__ __launch_bounds__(256) void spmm_atomic_kernel(
    const int* __restrict__ rows, const int* __restrict__ cols,
    const float* __restrict__ vals, const float* __restrict__ feat,
    float* __restrict__ outp, long long ne) {
  long long t = (long long)blockIdx.x * blockDim.x + threadIdx.x;
  long long e = t >> 4;
  if (e >= ne) return;
  int lane = (int)(t & 15);
  int r = rows[e];
  int c = cols[e];
  float v = vals[e];
  const float4 f = *(const float4*)(feat + (long long)c * D + lane * 4);
  float* o = outp + (long long)r * D + lane * 4;
  atomicAdd(o + 0, v * f.x);
  atomicAdd(o + 1, v * f.y);
  atomicAdd(o + 2, v * f.z);
  atomicAdd(o + 3, v * f.w);
}

__global__ __launch_bounds__(256) void norm_acc_kernel(const float* __restrict__ feat,
                                                       float* __restrict__ acc,
                                                       int nrows) {
  int row = blockIdx.x * 4 + (threadIdx.x >> 6);
  if (row >= nrows) return;
  int lane = threadIdx.x & 63;
  float x = feat[(long long)row * D + lane];
  float s = x * x;
  #pragma unroll
  for (int off = 32; off; off >>= 1) s += __shfl_xor(s, off);
  float sc = 1.0f / fmaxf(sqrtf(s), 1e-12f);
  acc[(long long)row * D + lane] += x * sc;
}

// ============================ launch ============================

extern "C" void kernel_launch(void* const* d_in, const int* in_sizes, int n_in,
                              void* d_out, int out_size, void* d_ws, size_t ws_size,
                              hipStream_t stream) {
  const float* learners = (const float*)d_in[0];
  const float* courses  = (const float*)d_in[1];
  const float* concepts = (const float*)d_in[2];
  const int*   cg_rows  = (const int*)d_in[3];
  const int*   cg_cols  = (const int*)d_in[4];
  const int*   kg_rows  = (const int*)d_in[6];
  const int*   kg_cols  = (const int*)d_in[7];
  const int*   ca_rows  = (const int*)d_in[9];
  const int*   ca_cols  = (const int*)d_in[10];
  const float* cg_vals  = (const float*)d_in[5];
  const float* kg_vals  = (const float*)d_in[8];
  const float* ca_vals  = (const float*)d_in[11];

  const long long Lr  = in_sizes[0] / D;
  const long long Cr  = in_sizes[1] / D;
  const long long Kr  = in_sizes[2] / D;
  const long long Ecg = in_sizes[3];      // full (2x bipartite)
  const long long Ekg = in_sizes[6];
  const long long Eca = in_sizes[9];
  const long long EcgH = Ecg / 2;
  const long long EkgH = Ekg / 2;
  const long long Ncg = Lr + Cr;
  const long long Nkg = Lr + Kr;

  float* out = (float*)d_out;

  // bucket geometry
  const int NB0   = (int)((Lr + (1 << S0) - 1) >> S0);
  const int s1cg  = 8;   // 256 course rows / bucket
  const int s1kg  = 6;   // 64 concept rows / bucket
  const int NBcg  = NB0 + (int)((Cr + (1 << s1cg) - 1) >> s1cg);
  const int NBkg  = NB0 + (int)((Kr + (1 << s1kg) - 1) >> s1kg);

  // ---- workspace layout (words) ----
  long long maxE2 = (Ecg > Ekg ? Ecg : Ekg);
  long long shareW = Ncg * D > maxE2 ? Ncg * D : maxE2;   // h1 buffer / binned scratch
  size_t need = 0;
  auto walloc = [&](long long elems) { size_t off = need; need += ((size_t)elems + 3) & ~(size_t)3; return off; };
  int* wsbase = (int*)d_ws;
  size_t o_share = walloc(shareW);
  size_t o_acck  = walloc(Kr * D);
  size_t o_rp0   = walloc(Ncg + 1);
  size_t o_rp1   = walloc(Nkg + 1);
  size_t o_rp2   = walloc(Cr + 1);
  size_t o_cv0   = walloc(Ecg);
  size_t o_cv1   = walloc(Ekg);
  size_t o_cv2   = walloc(Eca);
  size_t o_bkt   = walloc(BKT_WORDS);
  size_t o_cadeg = walloc(Cr);
  size_t o_scal  = walloc(Ncg + Nkg + Cr);
  size_t o_part  = walloc(512);
  size_t o_cacur = walloc(Cr);

  auto axcopy = [&](float* dst, const float* src, long long n, float s) {
    long long n4 = n / 4;
    long long b = (n4 + 255) / 256;
    int blocks = (int)(b < 2048 ? b : 2048);
    axcopy_kernel<<<blocks, 256, 0, stream>>>(dst, src, n4, s);
  };

  bool packable = (Ncg <= 131072) && (Nkg <= 131072) &&
                  (NBcg <= 256) && (NBkg <= 256) &&
                  (Ecg % 2 == 0) && (Ekg % 2 == 0);
  if (need * 4 > ws_size || !packable) {
    // -------- fallback: atomic push path (correct for any shape) --------
    float* buf0 = (float*)d_ws;
    float* buf1 = buf0 + Ncg * D;
    float* acck = buf1 + Ncg * D;
    auto spmm = [&](const int* r, const int* c, const float* v, const float* f,
                    float* o, long long ne) {
      long long threads = ne * 16;
      int blocks = (int)((threads + 255) / 256);
      spmm_atomic_kernel<<<blocks, 256, 0, stream>>>(r, c, v, f, o, ne);
    };
    auto normacc = [&](const float* f, float* a, long long nrows) {
      int blocks = (int)((nrows + 3) / 4);
      norm_acc_kernel<<<blocks, 256, 0, stream>>>(f, a, (int)nrows);
    };
    axcopy(buf0, learners, Lr * D, 1.f);
    axcopy(buf0 + Lr * D, courses, Cr * D, 1.f);
    axcopy(out, learners, Lr * D, 2.f);
    axcopy(out + Lr * D, courses, Cr * D, 1.f);
    hipMemsetAsync(buf1, 0, (size_t)(Ncg * D) * sizeof(float), stream);
    spmm(cg_rows, cg_cols, cg_vals, buf0, buf1, Ecg);
    normacc(buf1, out, Ncg);
    hipMemsetAsync(buf0, 0, (size_t)(Ncg * D) * sizeof(float), stream);
    spmm(cg_rows, cg_cols, cg_vals, buf1, buf0, Ecg);
    normacc(buf0, out, Ncg);
    axcopy(buf0, learners, Lr * D, 1.f);
    axcopy(buf0 + Lr * D, concepts, Kr * D, 1.f);
    axcopy(acck, concepts, Kr * D, 1.f);
    hipMemsetAsync(buf1, 0, (size_t)(Nkg * D) * sizeof(float), stream);
    spmm(kg_rows, kg_cols, kg_vals, buf0, buf1, Ekg);
    normacc(buf1, out, Lr);
    normacc(buf1 + Lr * D, acck, Kr);
    hipMemsetAsync(buf0, 0, (size_t)(Nkg * D) * sizeof(float), stream);
    spmm(kg_rows, kg_cols, kg_vals, buf1, buf0, Ekg);
    normacc(buf0, out, Lr);
    normacc(buf0 + Lr * D, acck, Kr);
    spmm(ca_rows, ca_cols, ca_vals, acck, out + Lr * D, Eca);
    return;
  }

  float* h1     = (float*)(wsbase + o_share);   // also binned scratch (disjoint lifetime)
  int*   binned = wsbase + o_share;
  float* acck   = (float*)(wsbase + o_acck);
  int*   rp0    = wsbase + o_rp0;
  int*   rp1    = wsbase + o_rp1;
  int*   rp2    = wsbase + o_rp2;
  int*   cv0    = wsbase + o_cv0;
  int*   cv1    = wsbase + o_cv1;
  int*   cv2    = wsbase + o_cv2;
  int*   bkt    = wsbase + o_bkt;
  int*   cadeg  = wsbase + o_cadeg;
  float* scal   = (float*)(wsbase + o_scal);
  int*   part   = wsbase + o_part;
  int*   cacur  = wsbase + o_cacur;

  // ---- build ----
  // bkt + cadeg are contiguous: one memset
  hipMemsetAsync(bkt, 0, (size_t)(BKT_WORDS + ((Cr + 3) & ~3LL)) * sizeof(int), stream);
  bincnt_kernel<<<512, 1024, 0, stream>>>(cg_rows, cg_cols, EcgH, kg_rows, kg_cols, EkgH,
                                          ca_rows, Eca, bkt, cadeg,
                                          (int)Lr, NB0, s1cg, s1kg);
  bktscan_kernel<<<1, 256, 0, stream>>>(bkt, NBcg, NBkg);

  const int nbca = (int)((Cr + 1023) / 1024);
  ca_scan1_kernel<<<nbca, 256, 0, stream>>>(cadeg, rp2, scal + Ncg + Nkg, part, (int)Cr);
  ca_scan2_kernel<<<1, 256, 0, stream>>>(part, nbca);
  ca_scan3_kernel<<<nbca, 256, 0, stream>>>(rp2, part, cacur, (int)Cr, (int)Eca);

  {
    int blocks = (int)((EcgH + 256 * BCHUNK - 1) / (256 * BCHUNK));
    bin_kernel<<<blocks, 256, 0, stream>>>(cg_rows, cg_cols, EcgH, (int)Lr, s1cg, NB0, NBcg,
                                           bkt + BKT_CURCG, binned);
    fine2_kernel<<<NBcg, 1024, 0, stream>>>(binned, bkt + BKT_BASECG, rp0, cv0, scal,
                                            (int)Lr, (int)Ncg, s1cg, NB0, (int)Ncg);
  }
  {
    int blocks = (int)((EkgH + 256 * BCHUNK - 1) / (256 * BCHUNK));
    bin_kernel<<<blocks, 256, 0, stream>>>(kg_rows, kg_cols, EkgH, (int)Lr, s1kg, NB0, NBkg,
                                           bkt + BKT_CURKG, binned);
    fine2_kernel<<<NBkg, 1024, 0, stream>>>(binned, bkt + BKT_BASEKG, rp1, cv1, scal + Ncg,
                                            (int)Lr, (int)Nkg, s1kg, NB0, (int)Nkg);
  }
  scatter_ca_kernel<<<(int)((Eca + 255) / 256), 256, 0, stream>>>(ca_rows, ca_cols, cacur, cv2, Eca);

  // ---- init accumulators ----
  axcopy(out, learners, Lr * D, 2.f);            // feat0 of BOTH views for learner rows
  axcopy(out + Lr * D, courses, Cr * D, 1.f);
  axcopy(acck, concepts, Kr * D, 1.f);

  const float* sig_cg = scal;
  const float* sig_kg = scal + Ncg;
  const float* inv_ca = scal + Ncg + Nkg;

  // ---- course-grained view ----
  {
    int blocks = (int)((Ncg + 3) / 4);
    pull_kernel<0, 1><<<blocks, 256, 0, stream>>>(rp0, cv0, sig_cg, sig_cg,
                                                  learners, courses, (int)Lr,
                                                  h1, out, out, (int)Ncg, (int)Ncg);
    pull_kernel<1, 0><<<blocks, 256, 0, stream>>>(rp0, cv0, nullptr, nullptr,
                                                  h1, nullptr, 0,
                                                  nullptr, out, out, (int)Ncg, (int)Ncg);
  }

  // ---- concept-grained view ----
  {
    int blocks = (int)((Nkg + 3) / 4);
    pull_kernel<0, 1><<<blocks, 256, 0, stream>>>(rp1, cv1, sig_kg, sig_kg,
                                                  learners, concepts, (int)Lr,
                                                  h1, out, acck, (int)Lr, (int)Nkg);
    pull_kernel<1, 0><<<blocks, 256, 0, stream>>>(rp1, cv1, nullptr, nullptr,
                                                  h1, nullptr, 0,
                                                  nullptr, out, acck, (int)Lr, (int)Nkg);
  }

  // ---- aggregate concept features into course rows ----
  {
    int blocks = (int)((Cr + 3) / 4);
    pull_kernel<2, 0><<<blocks, 256, 0, stream>>>(rp2, cv2, inv_ca, nullptr,
                                                  acck, nullptr, 0,
                                                  nullptr, out + Lr * D, nullptr, (int)Cr, (int)Cr);
  }
}

// Round 8
// 844.949 us; speedup vs baseline: 14.4084x; 1.0758x over previous
//
#include <hip/hip_runtime.h>

#define D 64
#define S0 10           // learner-side bucket shift (1024 rows/bucket)
#define BCHUNK 8        // edges per thread in bin pass

// bkt[] layout (ints): see R7
#define BKT_CNTCG 0
#define BKT_CNTKG 256
#define BKT_BASECG 512
#define BKT_BASEKG 772
#define BKT_CURCG 1032
#define BKT_CURKG 1288
#define BKT_WORDS 2048

__device__ __forceinline__ unsigned short f2bf(float x) {
  unsigned int u = __float_as_uint(x);
  return (unsigned short)((u + 0x7FFFu + ((u >> 16) & 1u)) >> 16);
}
__device__ __forceinline__ float bf2f(unsigned short b) {
  return __uint_as_float(((unsigned int)b) << 16);
}

// ============================ element-wise utils (fallback only) ============================

__global__ __launch_bounds__(256) void axcopy_kernel(float* __restrict__ dst,
                                                     const float* __restrict__ src,
                                                     long long n4, float s) {
  long long i = (long long)blockIdx.x * blockDim.x + threadIdx.x;
  long long stride = (long long)gridDim.x * blockDim.x;
  for (; i < n4; i += stride) {
    float4 v = ((const float4*)src)[i];
    v.x *= s; v.y *= s; v.z *= s; v.w *= s;
    ((float4*)dst)[i] = v;
  }
}

// ============================ build ============================

// Pass A: bucket-occupancy counts in LDS (512 bins), one flush per block.
__global__ __launch_bounds__(1024) void bincnt_kernel(
    const int* __restrict__ cgr, const int* __restrict__ cgc, long long EcgH,
    const int* __restrict__ kgr, const int* __restrict__ kgc, long long EkgH,
    const int* __restrict__ car, long long Eca,
    int* __restrict__ bkt, int* __restrict__ cadeg,
    int L, int NB0, int s1cg, int s1kg) {
  __shared__ int h[512];
  int t = threadIdx.x;
  if (t < 512) h[t] = 0;
  __syncthreads();
  long long i = (long long)blockIdx.x * blockDim.x + t;
  long long stride = (long long)gridDim.x * blockDim.x;
  long long t01 = EcgH + EkgH, tot = t01 + Eca;
  for (; i < tot; i += stride) {
    if (i < EcgH) {
      int a = cgr[i], c = cgc[i];
      atomicAdd(&h[a >> S0], 1);
      atomicAdd(&h[NB0 + ((c - L) >> s1cg)], 1);
    } else if (i < t01) {
      long long j = i - EcgH;
      int a = kgr[j], c = kgc[j];
      atomicAdd(&h[256 + (a >> S0)], 1);
      atomicAdd(&h[256 + NB0 + ((c - L) >> s1kg)], 1);
    } else {
      long long j = i - t01;
      atomicAdd(&cadeg[car[j]], 1);
    }
  }
  __syncthreads();
  if (t < 512 && h[t]) atomicAdd(&bkt[t], h[t]);
}

__global__ __launch_bounds__(256) void bktscan_kernel(int* __restrict__ bkt,
                                                      int NBcg, int NBkg) {
  __shared__ int lds[256];
  int t = threadIdx.x;
  #pragma unroll
  for (int g = 0; g < 2; ++g) {
    int NB      = g ? NBkg : NBcg;
    int cntoff  = g ? BKT_CNTKG : BKT_CNTCG;
    int baseoff = g ? BKT_BASEKG : BKT_BASECG;
    int curoff  = g ? BKT_CURKG : BKT_CURCG;
    lds[t] = (t < NB) ? bkt[cntoff + t] : 0;
    __syncthreads();
    for (int off = 1; off < 256; off <<= 1) {
      int x = (t >= off) ? lds[t - off] : 0;
      __syncthreads();
      lds[t] += x;
      __syncthreads();
    }
    int excl = (t == 0) ? 0 : lds[t - 1];
    if (t < NB) { bkt[baseoff + t] = excl; bkt[curoff + t] = excl; }
    if (t == NB - 1) bkt[baseoff + NB] = lds[t];
    __syncthreads();
  }
}

__global__ __launch_bounds__(256) void ca_scan1_kernel(const int* __restrict__ deg,
                                                       int* __restrict__ rp,
                                                       float* __restrict__ scal,
                                                       int* __restrict__ part, int n) {
  __shared__ int lds[256];
  int b = blockIdx.x, t = threadIdx.x;
  int base = b * 1024 + t * 4;
  int v[4]; int s = 0;
  #pragma unroll
  for (int j = 0; j < 4; j++) {
    int idx = base + j;
    v[j] = (idx < n) ? deg[idx] : 0;
    if (idx < n) scal[idx] = 1.0f / ((float)v[j] + 1e-8f);
    s += v[j];
  }
  lds[t] = s;
  __syncthreads();
  for (int off = 1; off < 256; off <<= 1) {
    int x = (t >= off) ? lds[t - off] : 0;
    __syncthreads();
    lds[t] += x;
    __syncthreads();
  }
  int run = (t == 0) ? 0 : lds[t - 1];
  if (t == 255) part[b] = lds[255];
  #pragma unroll
  for (int j = 0; j < 4; j++) { int idx = base + j; if (idx < n) rp[idx] = run; run += v[j]; }
}

__global__ __launch_bounds__(256) void ca_scan2_kernel(int* __restrict__ part, int nb) {
  __shared__ int lds[256];
  int t = threadIdx.x;
  lds[t] = (t < nb) ? part[t] : 0;
  __syncthreads();
  for (int off = 1; off < 256; off <<= 1) {
    int x = (t >= off) ? lds[t - off] : 0;
    __syncthreads();
    lds[t] += x;
    __syncthreads();
  }
  if (t < nb) part[t] = (t == 0) ? 0 : lds[t - 1];
}

__global__ __launch_bounds__(256) void ca_scan3_kernel(int* __restrict__ rp,
                                                       const int* __restrict__ part,
                                                       int* __restrict__ cacur,
                                                       int n, int total) {
  int b = blockIdx.x, t = threadIdx.x;
  int add = part[b];
  int base = b * 1024 + t * 4;
  #pragma unroll
  for (int j = 0; j < 4; j++) {
    int idx = base + j;
    if (idx < n) { int f = rp[idx] + add; rp[idx] = f; cacur[idx] = f; }
  }
  if (b == 0 && t == 0) rp[n] = total;
}

__global__ __launch_bounds__(256) void bin_kernel(
    const int* __restrict__ rowsA, const int* __restrict__ colsA, long long E,
    int L, int s1, int NB0, int NBtot,
    int* __restrict__ gcur, int* __restrict__ binned) {
  __shared__ int cnt[256];
  __shared__ int gbase[256];
  int t = threadIdx.x;
  long long base = (long long)blockIdx.x * (256 * BCHUNK);
  cnt[t] = 0;
  __syncthreads();
  int av[BCHUNK], cv_[BCHUNK], l0[BCHUNK], l1[BCHUNK];
  #pragma unroll
  for (int k = 0; k < BCHUNK; k++) {
    long long i = base + (long long)k * 256 + t;
    bool ok = i < E;
    int a = ok ? rowsA[i] : 0;
    int c = ok ? colsA[i] : L;
    av[k] = a; cv_[k] = c;
    if (ok) {
      int b0 = a >> S0;
      int b1 = NB0 + ((c - L) >> s1);
      l0[k] = atomicAdd(&cnt[b0], 1);
      l1[k] = atomicAdd(&cnt[b1], 1);
    } else { l0[k] = 0; l1[k] = 0; }
  }
  __syncthreads();
  if (t < NBtot) gbase[t] = cnt[t] ? atomicAdd(&gcur[t], cnt[t]) : 0;
  __syncthreads();
  #pragma unroll
  for (int k = 0; k < BCHUNK; k++) {
    long long i = base + (long long)k * 256 + t;
    if (i < E) {
      int a = av[k], c = cv_[k];
      int b0 = a >> S0;
      int b1 = NB0 + ((c - L) >> s1);
      binned[gbase[b0] + l0[k]] = ((a & ((1 << S0) - 1)) << 17) | c;
      binned[gbase[b1] + l1[k]] = (((c - L) & ((1 << s1) - 1)) << 17) | a;
    }
  }
}

__global__ __launch_bounds__(1024) void fine2_kernel(
    const int* __restrict__ binned, const int* __restrict__ bktbase,
    int* __restrict__ rp, int* __restrict__ cvout, float* __restrict__ scal,
    int L, int sideEnd, int s1, int NB0, int nfull) {
  __shared__ int cnt[1 << S0];
  int b = blockIdx.x, t = threadIdx.x;
  int rowbase, rowend;
  if (b < NB0) { rowbase = b << S0; rowend = min(rowbase + (1 << S0), L); }
  else { int bb = b - NB0; rowbase = L + (bb << s1); rowend = min(rowbase + (1 << s1), sideEnd); }
  int nrows = rowend - rowbase;
  int base = bktbase[b], end = bktbase[b + 1];
  cnt[t] = 0;
  __syncthreads();
  for (int i = base + t; i < end; i += 1024) atomicAdd(&cnt[binned[i] >> 17], 1);
  __syncthreads();
  int deg = cnt[t];
  for (int off = 1; off < 1024; off <<= 1) {
    int x = (t >= off) ? cnt[t - off] : 0;
    __syncthreads();
    cnt[t] += x;
    __syncthreads();
  }
  int excl = (t == 0) ? 0 : cnt[t - 1];
  int pos = base + excl;
  __syncthreads();
  cnt[t] = pos;            // reuse as row cursor
  if (t < nrows) {
    rp[rowbase + t] = pos;
    scal[rowbase + t] = 1.0f / (sqrtf((float)deg) + 1e-8f);
  }
  if (b == gridDim.x - 1 && t == 0) rp[nfull] = end;
  __syncthreads();
  for (int i = base + t; i < end; i += 1024) {
    int w = binned[i];
    int p = atomicAdd(&cnt[w >> 17], 1);
    cvout[p] = w & 0x1FFFF;
  }
}

__global__ __launch_bounds__(256) void scatter_ca_kernel(
    const int* __restrict__ rows, const int* __restrict__ cols,
    int* __restrict__ rowcur, int* __restrict__ cv, long long ne) {
  long long e = (long long)blockIdx.x * blockDim.x + threadIdx.x;
  if (e >= ne) return;
  int p = atomicAdd(&rowcur[rows[e]], 1);
  cv[p] = cols[e];
}

// ============================ bf16 table conversion ============================
// g0 (node-ordered, sigma-pre-scaled bf16): rows [0,Ncg) = cg view, [Ncg,Ncg+Nkg) = kg view.
// sigma = scal[row] for the whole range (scal layout is [cg | kg | ca]).
__global__ __launch_bounds__(256) void cvt_all_kernel(
    const float* __restrict__ learners, const float* __restrict__ courses,
    const float* __restrict__ concepts, const float* __restrict__ scal,
    unsigned short* __restrict__ g0, int Lr, int Ncg, int Rtot) {
  long long q = (long long)blockIdx.x * blockDim.x + threadIdx.x;
  long long stride = (long long)gridDim.x * blockDim.x;
  long long nq = (long long)Rtot * 16;   // 4 elems per quad
  for (; q < nq; q += stride) {
    int row = (int)(q >> 4);
    int sub = ((int)q & 15) * 4;
    const float* src;
    if (row < Ncg) src = (row < Lr) ? learners + (long long)row * D
                                    : courses + (long long)(row - Lr) * D;
    else {
      int r = row - Ncg;
      src = (r < Lr) ? learners + (long long)r * D
                     : concepts + (long long)(r - Lr) * D;
    }
    float sg = scal[row];
    float4 v = *(const float4*)(src + sub);
    unsigned short* dst = g0 + (long long)row * D + sub;
    dst[0] = f2bf(v.x * sg); dst[1] = f2bf(v.y * sg);
    dst[2] = f2bf(v.z * sg); dst[3] = f2bf(v.w * sg);
  }
}

// ============================ pull SpMM (bf16 gather) ============================
// One wave per row, lane = feature dim. s = sum of bf16 gt[col] over row's edges.
// MODE 0: g1[row] = bf16(sigma_row^2 * s); epilogue store base + unit(s)
// MODE 1: epilogue store base + unit(s)      (no g1 write)
// base: INITA/INITB select init-from-feat0 vs accumulate-from-acc per side of splitAcc.
template <int MODE, int INITA, int INITB>
__global__ __launch_bounds__(256) void pull2_kernel(
    const int* __restrict__ rowptr, const int* __restrict__ cols,
    const unsigned short* __restrict__ gt, unsigned short* __restrict__ g1,
    const float* __restrict__ sigRow,
    float* __restrict__ accA, float* __restrict__ accB, int splitAcc,
    const float* __restrict__ i0A, const float* __restrict__ i0B, int i0Split,
    float i0ScaleA, float i0ScaleB, int nrows) {
  int row = blockIdx.x * 4 + (threadIdx.x >> 6);
  if (row >= nrows) return;
  int lane = threadIdx.x & 63;
  int e0 = rowptr[row], e1 = rowptr[row + 1];
  float s = 0.f;
  int e = e0;
  for (; e + 3 < e1; e += 4) {
    int c0 = cols[e], c1 = cols[e + 1], c2 = cols[e + 2], c3 = cols[e + 3];
    s += bf2f(gt[((long long)c0 << 6) + lane]);
    s += bf2f(gt[((long long)c1 << 6) + lane]);
    s += bf2f(gt[((long long)c2 << 6) + lane]);
    s += bf2f(gt[((long long)c3 << 6) + lane]);
  }
  for (; e < e1; ++e) s += bf2f(gt[((long long)cols[e] << 6) + lane]);

  if (MODE == 0) {
    float sg = sigRow[row];
    g1[((long long)row << 6) + lane] = f2bf(sg * sg * s);
  }
  float q = s * s;
  #pragma unroll
  for (int off = 32; off; off >>= 1) q += __shfl_xor(q, off);
  float r = 1.0f / fmaxf(sqrtf(q), 1e-12f);

  float base;
  float* dst;
  if (row < splitAcc) {
    dst = accA + ((long long)row << 6);
    if (INITA) {
      bool lo = row < i0Split;
      base = (lo ? i0ScaleA : i0ScaleB) *
             (lo ? i0A[((long long)row << 6) + lane]
                 : i0B[((long long)(row - i0Split) << 6) + lane]);
    } else base = dst[lane];
  } else {
    dst = accB + ((long long)(row - splitAcc) << 6);
    if (INITB) base = i0ScaleB * i0B[((long long)(row - i0Split) << 6) + lane];
    else base = dst[lane];
  }
  dst[lane] = base + s * r;
}

// ca aggregation: out_course += invdeg[row] * sum(acck[col])  (f32 gather, small)
__global__ __launch_bounds__(256) void pull_ca_kernel(
    const int* __restrict__ rowptr, const int* __restrict__ cols,
    const float* __restrict__ invdeg, const float* __restrict__ feat,
    float* __restrict__ acc, int nrows) {
  int row = blockIdx.x * 4 + (threadIdx.x >> 6);
  if (row >= nrows) return;
  int lane = threadIdx.x & 63;
  int e0 = rowptr[row], e1 = rowptr[row + 1];
  float s = 0.f;
  for (int e = e0; e < e1; ++e) s += feat[((long long)cols[e] << 6) + lane];
  acc[((long long)row << 6) + lane] += invdeg[row] * s;
}

// ============================ fallback (atomic push path) ============================

__global__ __launch_bounds__(256) void spmm_atomic_kernel(
    const int* __restrict__ rows, const int* __restrict__ cols,
    const float* __restrict__ vals, const float* __restrict__ feat,
    float* __restrict__ outp, long long ne) {
  long long t = (long long)blockIdx.x * blockDim.x + threadIdx.x;
  long long e = t >> 4;
  if (e >= ne) return;
  int lane = (int)(t & 15);
  int r = rows[e];
  int c = cols[e];
  float v = vals[e];
  const float4 f = *(const float4*)(feat + (long long)c * D + lane * 4);
  float* o = outp + (long long)r * D + lane * 4;
  atomicAdd(o + 0, v * f.x);
  atomicAdd(o + 1, v * f.y);
  atomicAdd(o + 2, v * f.z);
  atomicAdd(o + 3, v * f.w);
}

__global__ __launch_bounds__(256) void norm_acc_kernel(const float* __restrict__ feat,
                                                       float* __restrict__ acc,
                                                       int nrows) {
  int row = blockIdx.x * 4 + (threadIdx.x >> 6);
  if (row >= nrows) return;
  int lane = threadIdx.x & 63;
  float x = feat[(long long)row * D + lane];
  float s = x * x;
  #pragma unroll
  for (int off = 32; off; off >>= 1) s += __shfl_xor(s, off);
  float sc = 1.0f / fmaxf(sqrtf(s), 1e-12f);
  acc[(long long)row * D + lane] += x * sc;
}

// ============================ launch ============================

extern "C" void kernel_launch(void* const* d_in, const int* in_sizes, int n_in,
                              void* d_out, int out_size, void* d_ws, size_t ws_size,
                              hipStream_t stream) {
  const float* learners = (const float*)d_in[0];
  const float* courses  = (const float*)d_in[1];
  const float* concepts = (const float*)d_in[2];
  const int*   cg_rows  = (const int*)d_in[3];
  const int*   cg_cols  = (const int*)d_in[4];
  const int*   kg_rows  = (const int*)d_in[6];
  const int*   kg_cols  = (const int*)d_in[7];
  const int*   ca_rows  = (const int*)d_in[9];
  const int*   ca_cols  = (const int*)d_in[10];
  const float* cg_vals  = (const float*)d_in[5];
  const float* kg_vals  = (const float*)d_in[8];
  const float* ca_vals  = (const float*)d_in[11];

  const long long Lr  = in_sizes[0] / D;
  const long long Cr  = in_sizes[1] / D;
  const long long Kr  = in_sizes[2] / D;
  const long long Ecg = in_sizes[3];
  const long long Ekg = in_sizes[6];
  const long long Eca = in_sizes[9];
  const long long EcgH = Ecg / 2;
  const long long EkgH = Ekg / 2;
  const long long Ncg = Lr + Cr;
  const long long Nkg = Lr + Kr;

  float* out = (float*)d_out;

  const int NB0   = (int)((Lr + (1 << S0) - 1) >> S0);
  const int s1cg  = 8;
  const int s1kg  = 6;
  const int NBcg  = NB0 + (int)((Cr + (1 << s1cg) - 1) >> s1cg);
  const int NBkg  = NB0 + (int)((Kr + (1 << s1kg) - 1) >> s1kg);

  // ---- workspace layout (words) ----
  long long maxE = (Ecg > Ekg ? Ecg : Ekg);
  long long maxN = (Ncg > Nkg ? Ncg : Nkg);
  long long shareW = maxE > maxN * 32 ? maxE : maxN * 32;  // binned (ints) / g1 (ushorts)
  size_t need = 0;
  auto walloc = [&](long long elems) { size_t off = need; need += ((size_t)elems + 3) & ~(size_t)3; return off; };
  int* wsbase = (int*)d_ws;
  size_t o_share = walloc(shareW);                  // binned scratch, then g1
  size_t o_g0    = walloc((Ncg + Nkg) * 32);        // bf16 sigma-scaled feat0 tables
  size_t o_acck  = walloc(Kr * D);
  size_t o_rp0   = walloc(Ncg + 1);
  size_t o_rp1   = walloc(Nkg + 1);
  size_t o_rp2   = walloc(Cr + 1);
  size_t o_cv0   = walloc(Ecg);
  size_t o_cv1   = walloc(Ekg);
  size_t o_cv2   = walloc(Eca);
  size_t o_bkt   = walloc(BKT_WORDS);
  size_t o_cadeg = walloc(Cr);
  size_t o_scal  = walloc(Ncg + Nkg + Cr);
  size_t o_part  = walloc(512);
  size_t o_cacur = walloc(Cr);

  auto axcopy = [&](float* dst, const float* src, long long n, float s) {
    long long n4 = n / 4;
    long long b = (n4 + 255) / 256;
    int blocks = (int)(b < 2048 ? b : 2048);
    axcopy_kernel<<<blocks, 256, 0, stream>>>(dst, src, n4, s);
  };

  bool packable = (Ncg <= 131072) && (Nkg <= 131072) &&
                  (NBcg <= 256) && (NBkg <= 256) &&
                  (Ecg % 2 == 0) && (Ekg % 2 == 0);
  if (need * 4 > ws_size || !packable) {
    // -------- fallback: atomic push path (correct for any shape) --------
    float* buf0 = (float*)d_ws;
    float* buf1 = buf0 + Ncg * D;
    float* acck = buf1 + Ncg * D;
    auto spmm = [&](const int* r, const int* c, const float* v, const float* f,
                    float* o, long long ne) {
      long long threads = ne * 16;
      int blocks = (int)((threads + 255) / 256);
      spmm_atomic_kernel<<<blocks, 256, 0, stream>>>(r, c, v, f, o, ne);
    };
    auto normacc = [&](const float* f, float* a, long long nrows) {
      int blocks = (int)((nrows + 3) / 4);
      norm_acc_kernel<<<blocks, 256, 0, stream>>>(f, a, (int)nrows);
    };
    axcopy(buf0, learners, Lr * D, 1.f);
    axcopy(buf0 + Lr * D, courses, Cr * D, 1.f);
    axcopy(out, learners, Lr * D, 2.f);
    axcopy(out + Lr * D, courses, Cr * D, 1.f);
    hipMemsetAsync(buf1, 0, (size_t)(Ncg * D) * sizeof(float), stream);
    spmm(cg_rows, cg_cols, cg_vals, buf0, buf1, Ecg);
    normacc(buf1, out, Ncg);
    hipMemsetAsync(buf0, 0, (size_t)(Ncg * D) * sizeof(float), stream);
    spmm(cg_rows, cg_cols, cg_vals, buf1, buf0, Ecg);
    normacc(buf0, out, Ncg);
    axcopy(buf0, learners, Lr * D, 1.f);
    axcopy(buf0 + Lr * D, concepts, Kr * D, 1.f);
    axcopy(acck, concepts, Kr * D, 1.f);
    hipMemsetAsync(buf1, 0, (size_t)(Nkg * D) * sizeof(float), stream);
    spmm(kg_rows, kg_cols, kg_vals, buf0, buf1, Ekg);
    normacc(buf1, out, Lr);
    normacc(buf1 + Lr * D, acck, Kr);
    hipMemsetAsync(buf0, 0, (size_t)(Nkg * D) * sizeof(float), stream);
    spmm(kg_rows, kg_cols, kg_vals, buf1, buf0, Ekg);
    normacc(buf0, out, Lr);
    normacc(buf0 + Lr * D, acck, Kr);
    spmm(ca_rows, ca_cols, ca_vals, acck, out + Lr * D, Eca);
    return;
  }

  int*            binned = wsbase + o_share;
  unsigned short* g1     = (unsigned short*)(wsbase + o_share);  // disjoint lifetime
  unsigned short* g0     = (unsigned short*)(wsbase + o_g0);
  float* acck   = (float*)(wsbase + o_acck);
  int*   rp0    = wsbase + o_rp0;
  int*   rp1    = wsbase + o_rp1;
  int*   rp2    = wsbase + o_rp2;
  int*   cv0    = wsbase + o_cv0;
  int*   cv1    = wsbase + o_cv1;
  int*   cv2    = wsbase + o_cv2;
  int*   bkt    = wsbase + o_bkt;
  int*   cadeg  = wsbase + o_cadeg;
  float* scal   = (float*)(wsbase + o_scal);
  int*   part   = wsbase + o_part;
  int*   cacur  = wsbase + o_cacur;

  // ---- build ----
  hipMemsetAsync(bkt, 0, (size_t)(BKT_WORDS + ((Cr + 3) & ~3LL)) * sizeof(int), stream);
  bincnt_kernel<<<512, 1024, 0, stream>>>(cg_rows, cg_cols, EcgH, kg_rows, kg_cols, EkgH,
                                          ca_rows, Eca, bkt, cadeg,
                                          (int)Lr, NB0, s1cg, s1kg);
  bktscan_kernel<<<1, 256, 0, stream>>>(bkt, NBcg, NBkg);

  const int nbca = (int)((Cr + 1023) / 1024);
  ca_scan1_kernel<<<nbca, 256, 0, stream>>>(cadeg, rp2, scal + Ncg + Nkg, part, (int)Cr);
  ca_scan2_kernel<<<1, 256, 0, stream>>>(part, nbca);
  ca_scan3_kernel<<<nbca, 256, 0, stream>>>(rp2, part, cacur, (int)Cr, (int)Eca);

  {
    int blocks = (int)((EcgH + 256 * BCHUNK - 1) / (256 * BCHUNK));
    bin_kernel<<<blocks, 256, 0, stream>>>(cg_rows, cg_cols, EcgH, (int)Lr, s1cg, NB0, NBcg,
                                           bkt + BKT_CURCG, binned);
    fine2_kernel<<<NBcg, 1024, 0, stream>>>(binned, bkt + BKT_BASECG, rp0, cv0, scal,
                                            (int)Lr, (int)Ncg, s1cg, NB0, (int)Ncg);
  }
  {
    int blocks = (int)((EkgH + 256 * BCHUNK - 1) / (256 * BCHUNK));
    bin_kernel<<<blocks, 256, 0, stream>>>(kg_rows, kg_cols, EkgH, (int)Lr, s1kg, NB0, NBkg,
                                           bkt + BKT_CURKG, binned);
    fine2_kernel<<<NBkg, 1024, 0, stream>>>(binned, bkt + BKT_BASEKG, rp1, cv1, scal + Ncg,
                                            (int)Lr, (int)Nkg, s1kg, NB0, (int)Nkg);
  }
  scatter_ca_kernel<<<(int)((Eca + 255) / 256), 256, 0, stream>>>(ca_rows, ca_cols, cacur, cv2, Eca);

  // ---- bf16 sigma-scaled tables (after build: needs scal) ----
  cvt_all_kernel<<<4096, 256, 0, stream>>>(learners, courses, concepts, scal,
                                           g0, (int)Lr, (int)Ncg, (int)(Ncg + Nkg));

  const unsigned short* g0cg = g0;
  const unsigned short* g0kg = g0 + (long long)Ncg * D;
  const float* sig_cg = scal;
  const float* sig_kg = scal + Ncg;
  const float* inv_ca = scal + Ncg + Nkg;

  // ---- course-grained view ----
  {
    int blocks = (int)((Ncg + 3) / 4);
    // L1: out = feat0-init + unit(sraw); g1 = bf16(sigma^2 * sraw)
    pull2_kernel<0, 1, 1><<<blocks, 256, 0, stream>>>(
        rp0, cv0, g0cg, g1, sig_cg,
        out, out, (int)Ncg,
        learners, courses, (int)Lr, 2.0f, 1.0f, (int)Ncg);
    // L2: out += unit(sraw2)
    pull2_kernel<1, 0, 0><<<blocks, 256, 0, stream>>>(
        rp0, cv0, g1, nullptr, nullptr,
        out, out, (int)Ncg,
        nullptr, nullptr, 0, 0.f, 0.f, (int)Ncg);
  }

  // ---- concept-grained view ----
  {
    int blocks = (int)((Nkg + 3) / 4);
    // L1: learner rows out += unit; concept rows acck = concepts + unit; g1 = sigma^2*sraw
    pull2_kernel<0, 0, 1><<<blocks, 256, 0, stream>>>(
        rp1, cv1, g0kg, g1, sig_kg,
        out, acck, (int)Lr,
        nullptr, concepts, (int)Lr, 0.f, 1.0f, (int)Nkg);
    // L2: out += unit; acck += unit
    pull2_kernel<1, 0, 0><<<blocks, 256, 0, stream>>>(
        rp1, cv1, g1, nullptr, nullptr,
        out, acck, (int)Lr,
        nullptr, nullptr, 0, 0.f, 0.f, (int)Nkg);
  }

  // ---- aggregate concept features into course rows ----
  {
    int blocks = (int)((Cr + 3) / 4);
    pull_ca_kernel<<<blocks, 256, 0, stream>>>(rp2, cv2, inv_ca, acck,
                                               out + Lr * D, (int)Cr);
  }
}

// Round 9
// 803.016 us; speedup vs baseline: 15.1609x; 1.0522x over previous
//
#include <hip/hip_runtime.h>

#define D 64
#define S0 10           // learner-side bucket shift (1024 rows/bucket)
#define BCHUNK 8        // edges per thread in bin pass

// bkt[] layout (ints): see R7
#define BKT_CNTCG 0
#define BKT_CNTKG 256
#define BKT_BASECG 512
#define BKT_BASEKG 772
#define BKT_CURCG 1032
#define BKT_CURKG 1288
#define BKT_WORDS 2048

__device__ __forceinline__ unsigned int f2bf(float x) {
  unsigned int u = __float_as_uint(x);
  return (u + 0x7FFFu + ((u >> 16) & 1u)) >> 16;
}
__device__ __forceinline__ float bf2f(unsigned short b) {
  return __uint_as_float(((unsigned int)b) << 16);
}

// ============================ element-wise utils (fallback only) ============================

__global__ __launch_bounds__(256) void axcopy_kernel(float* __restrict__ dst,
                                                     const float* __restrict__ src,
                                                     long long n4, float s) {
  long long i = (long long)blockIdx.x * blockDim.x + threadIdx.x;
  long long stride = (long long)gridDim.x * blockDim.x;
  for (; i < n4; i += stride) {
    float4 v = ((const float4*)src)[i];
    v.x *= s; v.y *= s; v.z *= s; v.w *= s;
    ((float4*)dst)[i] = v;
  }
}

// ============================ build ============================

// Pass A: bucket-occupancy counts in LDS (512 bins), one flush per block.
__global__ __launch_bounds__(1024) void bincnt_kernel(
    const int* __restrict__ cgr, const int* __restrict__ cgc, long long EcgH,
    const int* __restrict__ kgr, const int* __restrict__ kgc, long long EkgH,
    const int* __restrict__ car, long long Eca,
    int* __restrict__ bkt, int* __restrict__ cadeg,
    int L, int NB0, int s1cg, int s1kg) {
  __shared__ int h[512];
  int t = threadIdx.x;
  if (t < 512) h[t] = 0;
  __syncthreads();
  long long i = (long long)blockIdx.x * blockDim.x + t;
  long long stride = (long long)gridDim.x * blockDim.x;
  long long t01 = EcgH + EkgH, tot = t01 + Eca;
  for (; i < tot; i += stride) {
    if (i < EcgH) {
      int a = cgr[i], c = cgc[i];
      atomicAdd(&h[a >> S0], 1);
      atomicAdd(&h[NB0 + ((c - L) >> s1cg)], 1);
    } else if (i < t01) {
      long long j = i - EcgH;
      int a = kgr[j], c = kgc[j];
      atomicAdd(&h[256 + (a >> S0)], 1);
      atomicAdd(&h[256 + NB0 + ((c - L) >> s1kg)], 1);
    } else {
      long long j = i - t01;
      atomicAdd(&cadeg[car[j]], 1);
    }
  }
  __syncthreads();
  if (t < 512 && h[t]) atomicAdd(&bkt[t], h[t]);
}

__global__ __launch_bounds__(256) void bktscan_kernel(int* __restrict__ bkt,
                                                      int NBcg, int NBkg) {
  __shared__ int lds[256];
  int t = threadIdx.x;
  #pragma unroll
  for (int g = 0; g < 2; ++g) {
    int NB      = g ? NBkg : NBcg;
    int cntoff  = g ? BKT_CNTKG : BKT_CNTCG;
    int baseoff = g ? BKT_BASEKG : BKT_BASECG;
    int curoff  = g ? BKT_CURKG : BKT_CURCG;
    lds[t] = (t < NB) ? bkt[cntoff + t] : 0;
    __syncthreads();
    for (int off = 1; off < 256; off <<= 1) {
      int x = (t >= off) ? lds[t - off] : 0;
      __syncthreads();
      lds[t] += x;
      __syncthreads();
    }
    int excl = (t == 0) ? 0 : lds[t - 1];
    if (t < NB) { bkt[baseoff + t] = excl; bkt[curoff + t] = excl; }
    if (t == NB - 1) bkt[baseoff + NB] = lds[t];
    __syncthreads();
  }
}

__global__ __launch_bounds__(256) void ca_scan1_kernel(const int* __restrict__ deg,
                                                       int* __restrict__ rp,
                                                       float* __restrict__ scal,
                                                       int* __restrict__ part, int n) {
  __shared__ int lds[256];
  int b = blockIdx.x, t = threadIdx.x;
  int base = b * 1024 + t * 4;
  int v[4]; int s = 0;
  #pragma unroll
  for (int j = 0; j < 4; j++) {
    int idx = base + j;
    v[j] = (idx < n) ? deg[idx] : 0;
    if (idx < n) scal[idx] = 1.0f / ((float)v[j] + 1e-8f);
    s += v[j];
  }
  lds[t] = s;
  __syncthreads();
  for (int off = 1; off < 256; off <<= 1) {
    int x = (t >= off) ? lds[t - off] : 0;
    __syncthreads();
    lds[t] += x;
    __syncthreads();
  }
  int run = (t == 0) ? 0 : lds[t - 1];
  if (t == 255) part[b] = lds[255];
  #pragma unroll
  for (int j = 0; j < 4; j++) { int idx = base + j; if (idx < n) rp[idx] = run; run += v[j]; }
}

__global__ __launch_bounds__(256) void ca_scan2_kernel(int* __restrict__ part, int nb) {
  __shared__ int lds[256];
  int t = threadIdx.x;
  lds[t] = (t < nb) ? part[t] : 0;
  __syncthreads();
  for (int off = 1; off < 256; off <<= 1) {
    int x = (t >= off) ? lds[t - off] : 0;
    __syncthreads();
    lds[t] += x;
    __syncthreads();
  }
  if (t < nb) part[t] = (t == 0) ? 0 : lds[t - 1];
}

__global__ __launch_bounds__(256) void ca_scan3_kernel(int* __restrict__ rp,
                                                       const int* __restrict__ part,
                                                       int* __restrict__ cacur,
                                                       int n, int total) {
  int b = blockIdx.x, t = threadIdx.x;
  int add = part[b];
  int base = b * 1024 + t * 4;
  #pragma unroll
  for (int j = 0; j < 4; j++) {
    int idx = base + j;
    if (idx < n) { int f = rp[idx] + add; rp[idx] = f; cacur[idx] = f; }
  }
  if (b == 0 && t == 0) rp[n] = total;
}

__global__ __launch_bounds__(256) void bin_kernel(
    const int* __restrict__ rowsA, const int* __restrict__ colsA, long long E,
    int L, int s1, int NB0, int NBtot,
    int* __restrict__ gcur, int* __restrict__ binned) {
  __shared__ int cnt[256];
  __shared__ int gbase[256];
  int t = threadIdx.x;
  long long base = (long long)blockIdx.x * (256 * BCHUNK);
  cnt[t] = 0;
  __syncthreads();
  int av[BCHUNK], cv_[BCHUNK], l0[BCHUNK], l1[BCHUNK];
  #pragma unroll
  for (int k = 0; k < BCHUNK; k++) {
    long long i = base + (long long)k * 256 + t;
    bool ok = i < E;
    int a = ok ? rowsA[i] : 0;
    int c = ok ? colsA[i] : L;
    av[k] = a; cv_[k] = c;
    if (ok) {
      int b0 = a >> S0;
      int b1 = NB0 + ((c - L) >> s1);
      l0[k] = atomicAdd(&cnt[b0], 1);
      l1[k] = atomicAdd(&cnt[b1], 1);
    } else { l0[k] = 0; l1[k] = 0; }
  }
  __syncthreads();
  if (t < NBtot) gbase[t] = cnt[t] ? atomicAdd(&gcur[t], cnt[t]) : 0;
  __syncthreads();
  #pragma unroll
  for (int k = 0; k < BCHUNK; k++) {
    long long i = base + (long long)k * 256 + t;
    if (i < E) {
      int a = av[k], c = cv_[k];
      int b0 = a >> S0;
      int b1 = NB0 + ((c - L) >> s1);
      binned[gbase[b0] + l0[k]] = ((a & ((1 << S0) - 1)) << 17) | c;
      binned[gbase[b1] + l1[k]] = (((c - L) & ((1 << s1) - 1)) << 17) | a;
    }
  }
}

__global__ __launch_bounds__(1024) void fine2_kernel(
    const int* __restrict__ binned, const int* __restrict__ bktbase,
    int* __restrict__ rp, int* __restrict__ cvout, float* __restrict__ scal,
    int L, int sideEnd, int s1, int NB0, int nfull) {
  __shared__ int cnt[1 << S0];
  int b = blockIdx.x, t = threadIdx.x;
  int rowbase, rowend;
  if (b < NB0) { rowbase = b << S0; rowend = min(rowbase + (1 << S0), L); }
  else { int bb = b - NB0; rowbase = L + (bb << s1); rowend = min(rowbase + (1 << s1), sideEnd); }
  int nrows = rowend - rowbase;
  int base = bktbase[b], end = bktbase[b + 1];
  cnt[t] = 0;
  __syncthreads();
  for (int i = base + t; i < end; i += 1024) atomicAdd(&cnt[binned[i] >> 17], 1);
  __syncthreads();
  int deg = cnt[t];
  for (int off = 1; off < 1024; off <<= 1) {
    int x = (t >= off) ? cnt[t - off] : 0;
    __syncthreads();
    cnt[t] += x;
    __syncthreads();
  }
  int excl = (t == 0) ? 0 : cnt[t - 1];
  int pos = base + excl;
  __syncthreads();
  cnt[t] = pos;            // reuse as row cursor
  if (t < nrows) {
    rp[rowbase + t] = pos;
    scal[rowbase + t] = 1.0f / (sqrtf((float)deg) + 1e-8f);
  }
  if (b == gridDim.x - 1 && t == 0) rp[nfull] = end;
  __syncthreads();
  for (int i = base + t; i < end; i += 1024) {
    int w = binned[i];
    int p = atomicAdd(&cnt[w >> 17], 1);
    cvout[p] = w & 0x1FFFF;
  }
}

__global__ __launch_bounds__(256) void scatter_ca_kernel(
    const int* __restrict__ rows, const int* __restrict__ cols,
    int* __restrict__ rowcur, int* __restrict__ cv, long long ne) {
  long long e = (long long)blockIdx.x * blockDim.x + threadIdx.x;
  if (e >= ne) return;
  int p = atomicAdd(&rowcur[rows[e]], 1);
  cv[p] = cols[e];
}

// ============================ bf16 table conversion ============================
__global__ __launch_bounds__(256) void cvt_all_kernel(
    const float* __restrict__ learners, const float* __restrict__ courses,
    const float* __restrict__ concepts, const float* __restrict__ scal,
    unsigned short* __restrict__ g0, int Lr, int Ncg, int Rtot) {
  long long q = (long long)blockIdx.x * blockDim.x + threadIdx.x;
  long long stride = (long long)gridDim.x * blockDim.x;
  long long nq = (long long)Rtot * 16;   // 4 elems per quad
  for (; q < nq; q += stride) {
    int row = (int)(q >> 4);
    int sub = ((int)q & 15) * 4;
    const float* src;
    if (row < Ncg) src = (row < Lr) ? learners + (long long)row * D
                                    : courses + (long long)(row - Lr) * D;
    else {
      int r = row - Ncg;
      src = (r < Lr) ? learners + (long long)r * D
                     : concepts + (long long)(r - Lr) * D;
    }
    float sg = scal[row];
    float4 v = *(const float4*)(src + sub);
    unsigned int lo = f2bf(v.x * sg) | (f2bf(v.y * sg) << 16);
    unsigned int hi = f2bf(v.z * sg) | (f2bf(v.w * sg) << 16);
    *(uint2*)(g0 + (long long)row * D + sub) = make_uint2(lo, hi);
  }
}

// ============================ pull SpMM (4-edge vectorized bf16 gather) ============================
// One wave per row. Wave = 4 groups x 16 lanes: group g handles edges e0+g, e0+g+4, ...
// Lane loads uint2 (4 bf16 dims) -> float4 accumulator. shfl_xor(16,32) combines groups,
// shfl_xor(1..8) forms the row norm. Group 0 does all stores (float4 / packed bf16 uint2).
// MODE 0: g1[row] = bf16(sigma_row^2 * s); MODE 1: no g1 write.
// INITA/INITB: init epilogue base from feat0 (scaled) vs accumulate from acc.
template <int MODE, int INITA, int INITB>
__global__ __launch_bounds__(256) void pull4_kernel(
    const int* __restrict__ rowptr, const int* __restrict__ cols,
    const unsigned short* __restrict__ gt, unsigned short* __restrict__ g1,
    const float* __restrict__ sigRow,
    float* __restrict__ accA, float* __restrict__ accB, int splitAcc,
    const float* __restrict__ i0A, const float* __restrict__ i0B, int i0Split,
    float i0ScaleA, float i0ScaleB, int nrows) {
  int row = blockIdx.x * 4 + (threadIdx.x >> 6);
  if (row >= nrows) return;
  int lane = threadIdx.x & 63;
  int sub = lane & 15;     // dim quad: dims [4*sub, 4*sub+4)
  int grp = lane >> 4;     // edge group 0..3
  int e0 = rowptr[row], e1 = rowptr[row + 1];
  float sx = 0.f, sy = 0.f, sz = 0.f, sw = 0.f;
  for (int e = e0 + grp; e < e1; e += 4) {
    int c = cols[e];
    uint2 v = *(const uint2*)(gt + ((long long)c << 6) + (sub << 2));
    sx += __uint_as_float(v.x << 16);
    sy += __uint_as_float(v.x & 0xFFFF0000u);
    sz += __uint_as_float(v.y << 16);
    sw += __uint_as_float(v.y & 0xFFFF0000u);
  }
  #pragma unroll
  for (int off = 16; off <= 32; off <<= 1) {
    sx += __shfl_xor(sx, off);
    sy += __shfl_xor(sy, off);
    sz += __shfl_xor(sz, off);
    sw += __shfl_xor(sw, off);
  }
  float q = sx * sx + sy * sy + sz * sz + sw * sw;
  #pragma unroll
  for (int off = 1; off <= 8; off <<= 1) q += __shfl_xor(q, off);
  float r = 1.0f / fmaxf(sqrtf(q), 1e-12f);

  if (grp == 0) {
    long long off4 = (long long)(sub << 2);
    if (MODE == 0) {
      float sg = sigRow[row];
      float f = sg * sg;
      unsigned int lo = f2bf(f * sx) | (f2bf(f * sy) << 16);
      unsigned int hi = f2bf(f * sz) | (f2bf(f * sw) << 16);
      *(uint2*)(g1 + ((long long)row << 6) + (sub << 2)) = make_uint2(lo, hi);
    }
    float4 base;
    float* dst;
    if (row < splitAcc) {
      dst = accA + ((long long)row << 6);
      if (INITA) {
        bool lo_ = row < i0Split;
        const float* src = lo_ ? i0A + ((long long)row << 6)
                               : i0B + ((long long)(row - i0Split) << 6);
        float sc = lo_ ? i0ScaleA : i0ScaleB;
        float4 v = *(const float4*)(src + off4);
        base = make_float4(sc * v.x, sc * v.y, sc * v.z, sc * v.w);
      } else base = *(const float4*)(dst + off4);
    } else {
      dst = accB + ((long long)(row - splitAcc) << 6);
      if (INITB) {
        const float* src = i0B + ((long long)(row - i0Split) << 6);
        float4 v = *(const float4*)(src + off4);
        base = make_float4(i0ScaleB * v.x, i0ScaleB * v.y, i0ScaleB * v.z, i0ScaleB * v.w);
      } else base = *(const float4*)(dst + off4);
    }
    *(float4*)(dst + off4) = make_float4(base.x + sx * r, base.y + sy * r,
                                         base.z + sz * r, base.w + sw * r);
  }
}

// ca aggregation: out_course += invdeg[row] * sum(acck[col])  (f32 gather, small)
__global__ __launch_bounds__(256) void pull_ca_kernel(
    const int* __restrict__ rowptr, const int* __restrict__ cols,
    const float* __restrict__ invdeg, const float* __restrict__ feat,
    float* __restrict__ acc, int nrows) {
  int row = blockIdx.x * 4 + (threadIdx.x >> 6);
  if (row >= nrows) return;
  int lane = threadIdx.x & 63;
  int e0 = rowptr[row], e1 = rowptr[row + 1];
  float s = 0.f;
  for (int e = e0; e < e1; ++e) s += feat[((long long)cols[e] << 6) + lane];
  acc[((long long)row << 6) + lane] += invdeg[row] * s;
}

// ============================ fallback (atomic push path) ============================

__global__ __launch_bounds__(256) void spmm_atomic_kernel(
    const int* __restrict__ rows, const int* __restrict__ cols,
    const float* __restrict__ vals, const float* __restrict__ feat,
    float* __restrict__ outp, long long ne) {
  long long t = (long long)blockIdx.x * blockDim.x + threadIdx.x;
  long long e = t >> 4;
  if (e >= ne) return;
  int lane = (int)(t & 15);
  int r = rows[e];
  int c = cols[e];
  float v = vals[e];
  const float4 f = *(const float4*)(feat + (long long)c * D + lane * 4);
  float* o = outp + (long long)r * D + lane * 4;
  atomicAdd(o + 0, v * f.x);
  atomicAdd(o + 1, v * f.y);
  atomicAdd(o + 2, v * f.z);
  atomicAdd(o + 3, v * f.w);
}

__global__ __launch_bounds__(256) void norm_acc_kernel(const float* __restrict__ feat,
                                                       float* __restrict__ acc,
                                                       int nrows) {
  int row = blockIdx.x * 4 + (threadIdx.x >> 6);
  if (row >= nrows) return;
  int lane = threadIdx.x & 63;
  float x = feat[(long long)row * D + lane];
  float s = x * x;
  #pragma unroll
  for (int off = 32; off; off >>= 1) s += __shfl_xor(s, off);
  float sc = 1.0f / fmaxf(sqrtf(s), 1e-12f);
  acc[(long long)row * D + lane] += x * sc;
}

// ============================ launch ============================

extern "C" void kernel_launch(void* const* d_in, const int* in_sizes, int n_in,
                              void* d_out, int out_size, void* d_ws, size_t ws_size,
                              hipStream_t stream) {
  const float* learners = (const float*)d_in[0];
  const float* courses  = (const float*)d_in[1];
  const float* concepts = (const float*)d_in[2];
  const int*   cg_rows  = (const int*)d_in[3];
  const int*   cg_cols  = (const int*)d_in[4];
  const int*   kg_rows  = (const int*)d_in[6];
  const int*   kg_cols  = (const int*)d_in[7];
  const int*   ca_rows  = (const int*)d_in[9];
  const int*   ca_cols  = (const int*)d_in[10];
  const float* cg_vals  = (const float*)d_in[5];
  const float* kg_vals  = (const float*)d_in[8];
  const float* ca_vals  = (const float*)d_in[11];

  const long long Lr  = in_sizes[0] / D;
  const long long Cr  = in_sizes[1] / D;
  const long long Kr  = in_sizes[2] / D;
  const long long Ecg = in_sizes[3];
  const long long Ekg = in_sizes[6];
  const long long Eca = in_sizes[9];
  const long long EcgH = Ecg / 2;
  const long long EkgH = Ekg / 2;
  const long long Ncg = Lr + Cr;
  const long long Nkg = Lr + Kr;

  float* out = (float*)d_out;

  const int NB0   = (int)((Lr + (1 << S0) - 1) >> S0);
  const int s1cg  = 8;
  const int s1kg  = 6;
  const int NBcg  = NB0 + (int)((Cr + (1 << s1cg) - 1) >> s1cg);
  const int NBkg  = NB0 + (int)((Kr + (1 << s1kg) - 1) >> s1kg);

  // ---- workspace layout (words) ----
  long long maxE = (Ecg > Ekg ? Ecg : Ekg);
  long long maxN = (Ncg > Nkg ? Ncg : Nkg);
  long long shareW = maxE > maxN * 32 ? maxE : maxN * 32;  // binned (ints) / g1 (ushorts)
  size_t need = 0;
  auto walloc = [&](long long elems) { size_t off = need; need += ((size_t)elems + 3) & ~(size_t)3; return off; };
  int* wsbase = (int*)d_ws;
  size_t o_share = walloc(shareW);                  // binned scratch, then g1
  size_t o_g0    = walloc((Ncg + Nkg) * 32);        // bf16 sigma-scaled feat0 tables
  size_t o_acck  = walloc(Kr * D);
  size_t o_rp0   = walloc(Ncg + 1);
  size_t o_rp1   = walloc(Nkg + 1);
  size_t o_rp2   = walloc(Cr + 1);
  size_t o_cv0   = walloc(Ecg);
  size_t o_cv1   = walloc(Ekg);
  size_t o_cv2   = walloc(Eca);
  size_t o_bkt   = walloc(BKT_WORDS);
  size_t o_cadeg = walloc(Cr);
  size_t o_scal  = walloc(Ncg + Nkg + Cr);
  size_t o_part  = walloc(512);
  size_t o_cacur = walloc(Cr);

  auto axcopy = [&](float* dst, const float* src, long long n, float s) {
    long long n4 = n / 4;
    long long b = (n4 + 255) / 256;
    int blocks = (int)(b < 2048 ? b : 2048);
    axcopy_kernel<<<blocks, 256, 0, stream>>>(dst, src, n4, s);
  };

  bool packable = (Ncg <= 131072) && (Nkg <= 131072) &&
                  (NBcg <= 256) && (NBkg <= 256) &&
                  (Ecg % 2 == 0) && (Ekg % 2 == 0);
  if (need * 4 > ws_size || !packable) {
    // -------- fallback: atomic push path (correct for any shape) --------
    float* buf0 = (float*)d_ws;
    float* buf1 = buf0 + Ncg * D;
    float* acck = buf1 + Ncg * D;
    auto spmm = [&](const int* r, const int* c, const float* v, const float* f,
                    float* o, long long ne) {
      long long threads = ne * 16;
      int blocks = (int)((threads + 255) / 256);
      spmm_atomic_kernel<<<blocks, 256, 0, stream>>>(r, c, v, f, o, ne);
    };
    auto normacc = [&](const float* f, float* a, long long nrows) {
      int blocks = (int)((nrows + 3) / 4);
      norm_acc_kernel<<<blocks, 256, 0, stream>>>(f, a, (int)nrows);
    };
    axcopy(buf0, learners, Lr * D, 1.f);
    axcopy(buf0 + Lr * D, courses, Cr * D, 1.f);
    axcopy(out, learners, Lr * D, 2.f);
    axcopy(out + Lr * D, courses, Cr * D, 1.f);
    hipMemsetAsync(buf1, 0, (size_t)(Ncg * D) * sizeof(float), stream);
    spmm(cg_rows, cg_cols, cg_vals, buf0, buf1, Ecg);
    normacc(buf1, out, Ncg);
    hipMemsetAsync(buf0, 0, (size_t)(Ncg * D) * sizeof(float), stream);
    spmm(cg_rows, cg_cols, cg_vals, buf1, buf0, Ecg);
    normacc(buf0, out, Ncg);
    axcopy(buf0, learners, Lr * D, 1.f);
    axcopy(buf0 + Lr * D, concepts, Kr * D, 1.f);
    axcopy(acck, concepts, Kr * D, 1.f);
    hipMemsetAsync(buf1, 0, (size_t)(Nkg * D) * sizeof(float), stream);
    spmm(kg_rows, kg_cols, kg_vals, buf0, buf1, Ekg);
    normacc(buf1, out, Lr);
    normacc(buf1 + Lr * D, acck, Kr);
    hipMemsetAsync(buf0, 0, (size_t)(Nkg * D) * sizeof(float), stream);
    spmm(kg_rows, kg_cols, kg_vals, buf1, buf0, Ekg);
    normacc(buf0, out, Lr);
    normacc(buf0 + Lr * D, acck, Kr);
    spmm(ca_rows, ca_cols, ca_vals, acck, out + Lr * D, Eca);
    return;
  }

  int*            binned = wsbase + o_share;
  unsigned short* g1     = (unsigned short*)(wsbase + o_share);  // disjoint lifetime
  unsigned short* g0     = (unsigned short*)(wsbase + o_g0);
  float* acck   = (float*)(wsbase + o_acck);
  int*   rp0    = wsbase + o_rp0;
  int*   rp1    = wsbase + o_rp1;
  int*   rp2    = wsbase + o_rp2;
  int*   cv0    = wsbase + o_cv0;
  int*   cv1    = wsbase + o_cv1;
  int*   cv2    = wsbase + o_cv2;
  int*   bkt    = wsbase + o_bkt;
  int*   cadeg  = wsbase + o_cadeg;
  float* scal   = (float*)(wsbase + o_scal);
  int*   part   = wsbase + o_part;
  int*   cacur  = wsbase + o_cacur;

  // ---- build ----
  hipMemsetAsync(bkt, 0, (size_t)(BKT_WORDS + ((Cr + 3) & ~3LL)) * sizeof(int), stream);
  bincnt_kernel<<<512, 1024, 0, stream>>>(cg_rows, cg_cols, EcgH, kg_rows, kg_cols, EkgH,
                                          ca_rows, Eca, bkt, cadeg,
                                          (int)Lr, NB0, s1cg, s1kg);
  bktscan_kernel<<<1, 256, 0, stream>>>(bkt, NBcg, NBkg);

  const int nbca = (int)((Cr + 1023) / 1024);
  ca_scan1_kernel<<<nbca, 256, 0, stream>>>(cadeg, rp2, scal + Ncg + Nkg, part, (int)Cr);
  ca_scan2_kernel<<<1, 256, 0, stream>>>(part, nbca);
  ca_scan3_kernel<<<nbca, 256, 0, stream>>>(rp2, part, cacur, (int)Cr, (int)Eca);

  {
    int blocks = (int)((EcgH + 256 * BCHUNK - 1) / (256 * BCHUNK));
    bin_kernel<<<blocks, 256, 0, stream>>>(cg_rows, cg_cols, EcgH, (int)Lr, s1cg, NB0, NBcg,
                                           bkt + BKT_CURCG, binned);
    fine2_kernel<<<NBcg, 1024, 0, stream>>>(binned, bkt + BKT_BASECG, rp0, cv0, scal,
                                            (int)Lr, (int)Ncg, s1cg, NB0, (int)Ncg);
  }
  {
    int blocks = (int)((EkgH + 256 * BCHUNK - 1) / (256 * BCHUNK));
    bin_kernel<<<blocks, 256, 0, stream>>>(kg_rows, kg_cols, EkgH, (int)Lr, s1kg, NB0, NBkg,
                                           bkt + BKT_CURKG, binned);
    fine2_kernel<<<NBkg, 1024, 0, stream>>>(binned, bkt + BKT_BASEKG, rp1, cv1, scal + Ncg,
                                            (int)Lr, (int)Nkg, s1kg, NB0, (int)Nkg);
  }
  scatter_ca_kernel<<<(int)((Eca + 255) / 256), 256, 0, stream>>>(ca_rows, ca_cols, cacur, cv2, Eca);

  // ---- bf16 sigma-scaled tables (after build: needs scal) ----
  cvt_all_kernel<<<4096, 256, 0, stream>>>(learners, courses, concepts, scal,
                                           g0, (int)Lr, (int)Ncg, (int)(Ncg + Nkg));

  const unsigned short* g0cg = g0;
  const unsigned short* g0kg = g0 + (long long)Ncg * D;
  const float* sig_cg = scal;
  const float* sig_kg = scal + Ncg;
  const float* inv_ca = scal + Ncg + Nkg;

  // ---- course-grained view ----
  {
    int blocks = (int)((Ncg + 3) / 4);
    // L1: out = feat0-init + unit(sraw); g1 = bf16(sigma^2 * sraw)
    pull4_kernel<0, 1, 1><<<blocks, 256, 0, stream>>>(
        rp0, cv0, g0cg, g1, sig_cg,
        out, out, (int)Ncg,
        learners, courses, (int)Lr, 2.0f, 1.0f, (int)Ncg);
    // L2: out += unit(sraw2)
    pull4_kernel<1, 0, 0><<<blocks, 256, 0, stream>>>(
        rp0, cv0, g1, nullptr, nullptr,
        out, out, (int)Ncg,
        nullptr, nullptr, 0, 0.f, 0.f, (int)Ncg);
  }

  // ---- concept-grained view ----
  {
    int blocks = (int)((Nkg + 3) / 4);
    // L1: learner rows out += unit; concept rows acck = concepts + unit; g1 = sigma^2*sraw
    pull4_kernel<0, 0, 1><<<blocks, 256, 0, stream>>>(
        rp1, cv1, g0kg, g1, sig_kg,
        out, acck, (int)Lr,
        nullptr, concepts, (int)Lr, 0.f, 1.0f, (int)Nkg);
    // L2: out += unit; acck += unit
    pull4_kernel<1, 0, 0><<<blocks, 256, 0, stream>>>(
        rp1, cv1, g1, nullptr, nullptr,
        out, acck, (int)Lr,
        nullptr, nullptr, 0, 0.f, 0.f, (int)Nkg);
  }

  // ---- aggregate concept features into course rows ----
  {
    int blocks = (int)((Cr + 3) / 4);
    pull_ca_kernel<<<blocks, 256, 0, stream>>>(rp2, cv2, inv_ca, acck,
                                               out + Lr * D, (int)Cr);
  }
}

// Round 10
// 660.430 us; speedup vs baseline: 18.4341x; 1.2159x over previous
//
#include <hip/hip_runtime.h>

#define D 64
#define S0 10           // learner-side bucket shift (1024 rows/bucket)
#define BCHUNK 8        // edges per thread in bin pass

// bkt[] layout (ints): see R7
#define BKT_CNTCG 0
#define BKT_CNTKG 256
#define BKT_BASECG 512
#define BKT_BASEKG 772
#define BKT_CURCG 1032
#define BKT_CURKG 1288
#define BKT_WORDS 2048

__device__ __forceinline__ unsigned int f2bf(float x) {
  unsigned int u = __float_as_uint(x);
  return (u + 0x7FFFu + ((u >> 16) & 1u)) >> 16;
}

// ============================ element-wise utils (fallback only) ============================

__global__ __launch_bounds__(256) void axcopy_kernel(float* __restrict__ dst,
                                                     const float* __restrict__ src,
                                                     long long n4, float s) {
  long long i = (long long)blockIdx.x * blockDim.x + threadIdx.x;
  long long stride = (long long)gridDim.x * blockDim.x;
  for (; i < n4; i += stride) {
    float4 v = ((const float4*)src)[i];
    v.x *= s; v.y *= s; v.z *= s; v.w *= s;
    ((float4*)dst)[i] = v;
  }
}

// ============================ build ============================

// Pass A: bucket-occupancy counts in LDS (512 bins), one flush per block.
__global__ __launch_bounds__(1024) void bincnt_kernel(
    const int* __restrict__ cgr, const int* __restrict__ cgc, long long EcgH,
    const int* __restrict__ kgr, const int* __restrict__ kgc, long long EkgH,
    const int* __restrict__ car, long long Eca,
    int* __restrict__ bkt, int* __restrict__ cadeg,
    int L, int NB0, int s1cg, int s1kg) {
  __shared__ int h[512];
  int t = threadIdx.x;
  if (t < 512) h[t] = 0;
  __syncthreads();
  long long i = (long long)blockIdx.x * blockDim.x + t;
  long long stride = (long long)gridDim.x * blockDim.x;
  long long t01 = EcgH + EkgH, tot = t01 + Eca;
  for (; i < tot; i += stride) {
    if (i < EcgH) {
      int a = cgr[i], c = cgc[i];
      atomicAdd(&h[a >> S0], 1);
      atomicAdd(&h[NB0 + ((c - L) >> s1cg)], 1);
    } else if (i < t01) {
      long long j = i - EcgH;
      int a = kgr[j], c = kgc[j];
      atomicAdd(&h[256 + (a >> S0)], 1);
      atomicAdd(&h[256 + NB0 + ((c - L) >> s1kg)], 1);
    } else {
      long long j = i - t01;
      atomicAdd(&cadeg[car[j]], 1);
    }
  }
  __syncthreads();
  if (t < 512 && h[t]) atomicAdd(&bkt[t], h[t]);
}

__global__ __launch_bounds__(256) void bktscan_kernel(int* __restrict__ bkt,
                                                      int NBcg, int NBkg) {
  __shared__ int lds[256];
  int t = threadIdx.x;
  #pragma unroll
  for (int g = 0; g < 2; ++g) {
    int NB      = g ? NBkg : NBcg;
    int cntoff  = g ? BKT_CNTKG : BKT_CNTCG;
    int baseoff = g ? BKT_BASEKG : BKT_BASECG;
    int curoff  = g ? BKT_CURKG : BKT_CURCG;
    lds[t] = (t < NB) ? bkt[cntoff + t] : 0;
    __syncthreads();
    for (int off = 1; off < 256; off <<= 1) {
      int x = (t >= off) ? lds[t - off] : 0;
      __syncthreads();
      lds[t] += x;
      __syncthreads();
    }
    int excl = (t == 0) ? 0 : lds[t - 1];
    if (t < NB) { bkt[baseoff + t] = excl; bkt[curoff + t] = excl; }
    if (t == NB - 1) bkt[baseoff + NB] = lds[t];
    __syncthreads();
  }
}

__global__ __launch_bounds__(256) void ca_scan1_kernel(const int* __restrict__ deg,
                                                       int* __restrict__ rp,
                                                       float* __restrict__ scal,
                                                       int* __restrict__ part, int n) {
  __shared__ int lds[256];
  int b = blockIdx.x, t = threadIdx.x;
  int base = b * 1024 + t * 4;
  int v[4]; int s = 0;
  #pragma unroll
  for (int j = 0; j < 4; j++) {
    int idx = base + j;
    v[j] = (idx < n) ? deg[idx] : 0;
    if (idx < n) scal[idx] = 1.0f / ((float)v[j] + 1e-8f);
    s += v[j];
  }
  lds[t] = s;
  __syncthreads();
  for (int off = 1; off < 256; off <<= 1) {
    int x = (t >= off) ? lds[t - off] : 0;
    __syncthreads();
    lds[t] += x;
    __syncthreads();
  }
  int run = (t == 0) ? 0 : lds[t - 1];
  if (t == 255) part[b] = lds[255];
  #pragma unroll
  for (int j = 0; j < 4; j++) { int idx = base + j; if (idx < n) rp[idx] = run; run += v[j]; }
}

__global__ __launch_bounds__(256) void ca_scan2_kernel(int* __restrict__ part, int nb) {
  __shared__ int lds[256];
  int t = threadIdx.x;
  lds[t] = (t < nb) ? part[t] : 0;
  __syncthreads();
  for (int off = 1; off < 256; off <<= 1) {
    int x = (t >= off) ? lds[t - off] : 0;
    __syncthreads();
    lds[t] += x;
    __syncthreads();
  }
  if (t < nb) part[t] = (t == 0) ? 0 : lds[t - 1];
}

__global__ __launch_bounds__(256) void ca_scan3_kernel(int* __restrict__ rp,
                                                       const int* __restrict__ part,
                                                       int* __restrict__ cacur,
                                                       int n, int total) {
  int b = blockIdx.x, t = threadIdx.x;
  int add = part[b];
  int base = b * 1024 + t * 4;
  #pragma unroll
  for (int j = 0; j < 4; j++) {
    int idx = base + j;
    if (idx < n) { int f = rp[idx] + add; rp[idx] = f; cacur[idx] = f; }
  }
  if (b == 0 && t == 0) rp[n] = total;
}

__global__ __launch_bounds__(256) void bin_kernel(
    const int* __restrict__ rowsA, const int* __restrict__ colsA, long long E,
    int L, int s1, int NB0, int NBtot,
    int* __restrict__ gcur, int* __restrict__ binned) {
  __shared__ int cnt[256];
  __shared__ int gbase[256];
  int t = threadIdx.x;
  long long base = (long long)blockIdx.x * (256 * BCHUNK);
  cnt[t] = 0;
  __syncthreads();
  int av[BCHUNK], cv_[BCHUNK], l0[BCHUNK], l1[BCHUNK];
  #pragma unroll
  for (int k = 0; k < BCHUNK; k++) {
    long long i = base + (long long)k * 256 + t;
    bool ok = i < E;
    int a = ok ? rowsA[i] : 0;
    int c = ok ? colsA[i] : L;
    av[k] = a; cv_[k] = c;
    if (ok) {
      int b0 = a >> S0;
      int b1 = NB0 + ((c - L) >> s1);
      l0[k] = atomicAdd(&cnt[b0], 1);
      l1[k] = atomicAdd(&cnt[b1], 1);
    } else { l0[k] = 0; l1[k] = 0; }
  }
  __syncthreads();
  if (t < NBtot) gbase[t] = cnt[t] ? atomicAdd(&gcur[t], cnt[t]) : 0;
  __syncthreads();
  #pragma unroll
  for (int k = 0; k < BCHUNK; k++) {
    long long i = base + (long long)k * 256 + t;
    if (i < E) {
      int a = av[k], c = cv_[k];
      int b0 = a >> S0;
      int b1 = NB0 + ((c - L) >> s1);
      binned[gbase[b0] + l0[k]] = ((a & ((1 << S0) - 1)) << 17) | c;
      binned[gbase[b1] + l1[k]] = (((c - L) & ((1 << s1) - 1)) << 17) | a;
    }
  }
}

__global__ __launch_bounds__(1024) void fine2_kernel(
    const int* __restrict__ binned, const int* __restrict__ bktbase,
    int* __restrict__ rp, int* __restrict__ cvout, float* __restrict__ scal,
    int L, int sideEnd, int s1, int NB0, int nfull) {
  __shared__ int cnt[1 << S0];
  int b = blockIdx.x, t = threadIdx.x;
  int rowbase, rowend;
  if (b < NB0) { rowbase = b << S0; rowend = min(rowbase + (1 << S0), L); }
  else { int bb = b - NB0; rowbase = L + (bb << s1); rowend = min(rowbase + (1 << s1), sideEnd); }
  int nrows = rowend - rowbase;
  int base = bktbase[b], end = bktbase[b + 1];
  cnt[t] = 0;
  __syncthreads();
  for (int i = base + t; i < end; i += 1024) atomicAdd(&cnt[binned[i] >> 17], 1);
  __syncthreads();
  int deg = cnt[t];
  for (int off = 1; off < 1024; off <<= 1) {
    int x = (t >= off) ? cnt[t - off] : 0;
    __syncthreads();
    cnt[t] += x;
    __syncthreads();
  }
  int excl = (t == 0) ? 0 : cnt[t - 1];
  int pos = base + excl;
  __syncthreads();
  cnt[t] = pos;            // reuse as row cursor
  if (t < nrows) {
    rp[rowbase + t] = pos;
    scal[rowbase + t] = 1.0f / (sqrtf((float)deg) + 1e-8f);
  }
  if (b == gridDim.x - 1 && t == 0) rp[nfull] = end;
  __syncthreads();
  for (int i = base + t; i < end; i += 1024) {
    int w = binned[i];
    int p = atomicAdd(&cnt[w >> 17], 1);
    cvout[p] = w & 0x1FFFF;
  }
}

__global__ __launch_bounds__(256) void scatter_ca_kernel(
    const int* __restrict__ rows, const int* __restrict__ cols,
    int* __restrict__ rowcur, int* __restrict__ cv, long long ne) {
  long long e = (long long)blockIdx.x * blockDim.x + threadIdx.x;
  if (e >= ne) return;
  int p = atomicAdd(&rowcur[rows[e]], 1);
  cv[p] = cols[e];
}

// ============================ bf16 table conversion ============================
__global__ __launch_bounds__(256) void cvt_all_kernel(
    const float* __restrict__ learners, const float* __restrict__ courses,
    const float* __restrict__ concepts, const float* __restrict__ scal,
    unsigned short* __restrict__ g0, int Lr, int Ncg, int Rtot) {
  long long q = (long long)blockIdx.x * blockDim.x + threadIdx.x;
  long long stride = (long long)gridDim.x * blockDim.x;
  long long nq = (long long)Rtot * 16;   // 4 elems per quad
  for (; q < nq; q += stride) {
    int row = (int)(q >> 4);
    int sub = ((int)q & 15) * 4;
    const float* src;
    if (row < Ncg) src = (row < Lr) ? learners + (long long)row * D
                                    : courses + (long long)(row - Lr) * D;
    else {
      int r = row - Ncg;
      src = (r < Lr) ? learners + (long long)r * D
                     : concepts + (long long)(r - Lr) * D;
    }
    float sg = scal[row];
    float4 v = *(const float4*)(src + sub);
    unsigned int lo = f2bf(v.x * sg) | (f2bf(v.y * sg) << 16);
    unsigned int hi = f2bf(v.z * sg) | (f2bf(v.w * sg) << 16);
    *(uint2*)(g0 + (long long)row * D + sub) = make_uint2(lo, hi);
  }
}

// ============================ pull SpMM (16-edge MLP bf16 gather) ============================
// One wave per row. Wave = 4 groups x 16 lanes. Main loop: 16 edges per wave
// iteration; group g hoists 4 independent cols loads then issues 4 independent
// uint2 gathers (MLP=4 in-flight). Accumulation order per group identical to R9.
// shfl_xor(16,32) combines groups, shfl_xor(1..8) forms the row norm.
// MODE 0: g1[row] = bf16(sigma_row^2 * s); MODE 1: no g1 write.
// INITA/INITB: init epilogue base from feat0 (scaled) vs accumulate from acc.
template <int MODE, int INITA, int INITB>
__global__ __launch_bounds__(256) void pull4_kernel(
    const int* __restrict__ rowptr, const int* __restrict__ cols,
    const unsigned short* __restrict__ gt, unsigned short* __restrict__ g1,
    const float* __restrict__ sigRow,
    float* __restrict__ accA, float* __restrict__ accB, int splitAcc,
    const float* __restrict__ i0A, const float* __restrict__ i0B, int i0Split,
    float i0ScaleA, float i0ScaleB, int nrows) {
  int row = blockIdx.x * 4 + (threadIdx.x >> 6);
  if (row >= nrows) return;
  int lane = threadIdx.x & 63;
  int sub = lane & 15;     // dim quad: dims [4*sub, 4*sub+4)
  int grp = lane >> 4;     // edge group 0..3
  int e0 = rowptr[row], e1 = rowptr[row + 1];
  float sx = 0.f, sy = 0.f, sz = 0.f, sw = 0.f;
  long long dimoff = (long long)(sub << 2);
  int e = e0;
  for (; e + 16 <= e1; e += 16) {
    int c0 = cols[e + grp];
    int c1 = cols[e + 4 + grp];
    int c2 = cols[e + 8 + grp];
    int c3 = cols[e + 12 + grp];
    uint2 v0 = *(const uint2*)(gt + ((long long)c0 << 6) + dimoff);
    uint2 v1 = *(const uint2*)(gt + ((long long)c1 << 6) + dimoff);
    uint2 v2 = *(const uint2*)(gt + ((long long)c2 << 6) + dimoff);
    uint2 v3 = *(const uint2*)(gt + ((long long)c3 << 6) + dimoff);
    sx += __uint_as_float(v0.x << 16);
    sy += __uint_as_float(v0.x & 0xFFFF0000u);
    sz += __uint_as_float(v0.y << 16);
    sw += __uint_as_float(v0.y & 0xFFFF0000u);
    sx += __uint_as_float(v1.x << 16);
    sy += __uint_as_float(v1.x & 0xFFFF0000u);
    sz += __uint_as_float(v1.y << 16);
    sw += __uint_as_float(v1.y & 0xFFFF0000u);
    sx += __uint_as_float(v2.x << 16);
    sy += __uint_as_float(v2.x & 0xFFFF0000u);
    sz += __uint_as_float(v2.y << 16);
    sw += __uint_as_float(v2.y & 0xFFFF0000u);
    sx += __uint_as_float(v3.x << 16);
    sy += __uint_as_float(v3.x & 0xFFFF0000u);
    sz += __uint_as_float(v3.y << 16);
    sw += __uint_as_float(v3.y & 0xFFFF0000u);
  }
  for (int ee = e + grp; ee < e1; ee += 4) {
    int c = cols[ee];
    uint2 v = *(const uint2*)(gt + ((long long)c << 6) + dimoff);
    sx += __uint_as_float(v.x << 16);
    sy += __uint_as_float(v.x & 0xFFFF0000u);
    sz += __uint_as_float(v.y << 16);
    sw += __uint_as_float(v.y & 0xFFFF0000u);
  }
  #pragma unroll
  for (int off = 16; off <= 32; off <<= 1) {
    sx += __shfl_xor(sx, off);
    sy += __shfl_xor(sy, off);
    sz += __shfl_xor(sz, off);
    sw += __shfl_xor(sw, off);
  }
  float q = sx * sx + sy * sy + sz * sz + sw * sw;
  #pragma unroll
  for (int off = 1; off <= 8; off <<= 1) q += __shfl_xor(q, off);
  float r = 1.0f / fmaxf(sqrtf(q), 1e-12f);

  if (grp == 0) {
    long long off4 = dimoff;
    if (MODE == 0) {
      float sg = sigRow[row];
      float f = sg * sg;
      unsigned int lo = f2bf(f * sx) | (f2bf(f * sy) << 16);
      unsigned int hi = f2bf(f * sz) | (f2bf(f * sw) << 16);
      *(uint2*)(g1 + ((long long)row << 6) + (sub << 2)) = make_uint2(lo, hi);
    }
    float4 base;
    float* dst;
    if (row < splitAcc) {
      dst = accA + ((long long)row << 6);
      if (INITA) {
        bool lo_ = row < i0Split;
        const float* src = lo_ ? i0A + ((long long)row << 6)
                               : i0B + ((long long)(row - i0Split) << 6);
        float sc = lo_ ? i0ScaleA : i0ScaleB;
        float4 v = *(const float4*)(src + off4);
        base = make_float4(sc * v.x, sc * v.y, sc * v.z, sc * v.w);
      } else base = *(const float4*)(dst + off4);
    } else {
      dst = accB + ((long long)(row - splitAcc) << 6);
      if (INITB) {
        const float* src = i0B + ((long long)(row - i0Split) << 6);
        float4 v = *(const float4*)(src + off4);
        base = make_float4(i0ScaleB * v.x, i0ScaleB * v.y, i0ScaleB * v.z, i0ScaleB * v.w);
      } else base = *(const float4*)(dst + off4);
    }
    *(float4*)(dst + off4) = make_float4(base.x + sx * r, base.y + sy * r,
                                         base.z + sz * r, base.w + sw * r);
  }
}

// ca aggregation: out_course += invdeg[row] * sum(acck[col])  (f32 gather, small)
__global__ __launch_bounds__(256) void pull_ca_kernel(
    const int* __restrict__ rowptr, const int* __restrict__ cols,
    const float* __restrict__ invdeg, const float* __restrict__ feat,
    float* __restrict__ acc, int nrows) {
  int row = blockIdx.x * 4 + (threadIdx.x >> 6);
  if (row >= nrows) return;
  int lane = threadIdx.x & 63;
  int e0 = rowptr[row], e1 = rowptr[row + 1];
  float s = 0.f;
  for (int e = e0; e < e1; ++e) s += feat[((long long)cols[e] << 6) + lane];
  acc[((long long)row << 6) + lane] += invdeg[row] * s;
}

// ============================ fallback (atomic push path) ============================

__global__ __launch_bounds__(256) void spmm_atomic_kernel(
    const int* __restrict__ rows, const int* __restrict__ cols,
    const float* __restrict__ vals, const float* __restrict__ feat,
    float* __restrict__ outp, long long ne) {
  long long t = (long long)blockIdx.x * blockDim.x + threadIdx.x;
  long long e = t >> 4;
  if (e >= ne) return;
  int lane = (int)(t & 15);
  int r = rows[e];
  int c = cols[e];
  float v = vals[e];
  const float4 f = *(const float4*)(feat + (long long)c * D + lane * 4);
  float* o = outp + (long long)r * D + lane * 4;
  atomicAdd(o + 0, v * f.x);
  atomicAdd(o + 1, v * f.y);
  atomicAdd(o + 2, v * f.z);
  atomicAdd(o + 3, v * f.w);
}

__global__ __launch_bounds__(256) void norm_acc_kernel(const float* __restrict__ feat,
                                                       float* __restrict__ acc,
                                                       int nrows) {
  int row = blockIdx.x * 4 + (threadIdx.x >> 6);
  if (row >= nrows) return;
  int lane = threadIdx.x & 63;
  float x = feat[(long long)row * D + lane];
  float s = x * x;
  #pragma unroll
  for (int off = 32; off; off >>= 1) s += __shfl_xor(s, off);
  float sc = 1.0f / fmaxf(sqrtf(s), 1e-12f);
  acc[(long long)row * D + lane] += x * sc;
}

// ============================ launch ============================

extern "C" void kernel_launch(void* const* d_in, const int* in_sizes, int n_in,
                              void* d_out, int out_size, void* d_ws, size_t ws_size,
                              hipStream_t stream) {
  const float* learners = (const float*)d_in[0];
  const float* courses  = (const float*)d_in[1];
  const float* concepts = (const float*)d_in[2];
  const int*   cg_rows  = (const int*)d_in[3];
  const int*   cg_cols  = (const int*)d_in[4];
  const int*   kg_rows  = (const int*)d_in[6];
  const int*   kg_cols  = (const int*)d_in[7];
  const int*   ca_rows  = (const int*)d_in[9];
  const int*   ca_cols  = (const int*)d_in[10];
  const float* cg_vals  = (const float*)d_in[5];
  const float* kg_vals  = (const float*)d_in[8];
  const float* ca_vals  = (const float*)d_in[11];

  const long long Lr  = in_sizes[0] / D;
  const long long Cr  = in_sizes[1] / D;
  const long long Kr  = in_sizes[2] / D;
  const long long Ecg = in_sizes[3];
  const long long Ekg = in_sizes[6];
  const long long Eca = in_sizes[9];
  const long long EcgH = Ecg / 2;
  const long long EkgH = Ekg / 2;
  const long long Ncg = Lr + Cr;
  const long long Nkg = Lr + Kr;

  float* out = (float*)d_out;

  const int NB0   = (int)((Lr + (1 << S0) - 1) >> S0);
  const int s1cg  = 8;
  const int s1kg  = 6;
  const int NBcg  = NB0 + (int)((Cr + (1 << s1cg) - 1) >> s1cg);
  const int NBkg  = NB0 + (int)((Kr + (1 << s1kg) - 1) >> s1kg);

  // ---- workspace layout (words) ----
  long long maxE = (Ecg > Ekg ? Ecg : Ekg);
  long long maxN = (Ncg > Nkg ? Ncg : Nkg);
  long long shareW = maxE > maxN * 32 ? maxE : maxN * 32;  // binned (ints) / g1 (ushorts)
  size_t need = 0;
  auto walloc = [&](long long elems) { size_t off = need; need += ((size_t)elems + 3) & ~(size_t)3; return off; };
  int* wsbase = (int*)d_ws;
  size_t o_share = walloc(shareW);                  // binned scratch, then g1
  size_t o_g0    = walloc((Ncg + Nkg) * 32);        // bf16 sigma-scaled feat0 tables
  size_t o_acck  = walloc(Kr * D);
  size_t o_rp0   = walloc(Ncg + 1);
  size_t o_rp1   = walloc(Nkg + 1);
  size_t o_rp2   = walloc(Cr + 1);
  size_t o_cv0   = walloc(Ecg);
  size_t o_cv1   = walloc(Ekg);
  size_t o_cv2   = walloc(Eca);
  size_t o_bkt   = walloc(BKT_WORDS);
  size_t o_cadeg = walloc(Cr);
  size_t o_scal  = walloc(Ncg + Nkg + Cr);
  size_t o_part  = walloc(512);
  size_t o_cacur = walloc(Cr);

  auto axcopy = [&](float* dst, const float* src, long long n, float s) {
    long long n4 = n / 4;
    long long b = (n4 + 255) / 256;
    int blocks = (int)(b < 2048 ? b : 2048);
    axcopy_kernel<<<blocks, 256, 0, stream>>>(dst, src, n4, s);
  };

  bool packable = (Ncg <= 131072) && (Nkg <= 131072) &&
                  (NBcg <= 256) && (NBkg <= 256) &&
                  (Ecg % 2 == 0) && (Ekg % 2 == 0);
  if (need * 4 > ws_size || !packable) {
    // -------- fallback: atomic push path (correct for any shape) --------
    float* buf0 = (float*)d_ws;
    float* buf1 = buf0 + Ncg * D;
    float* acck = buf1 + Ncg * D;
    auto spmm = [&](const int* r, const int* c, const float* v, const float* f,
                    float* o, long long ne) {
      long long threads = ne * 16;
      int blocks = (int)((threads + 255) / 256);
      spmm_atomic_kernel<<<blocks, 256, 0, stream>>>(r, c, v, f, o, ne);
    };
    auto normacc = [&](const float* f, float* a, long long nrows) {
      int blocks = (int)((nrows + 3) / 4);
      norm_acc_kernel<<<blocks, 256, 0, stream>>>(f, a, (int)nrows);
    };
    axcopy(buf0, learners, Lr * D, 1.f);
    axcopy(buf0 + Lr * D, courses, Cr * D, 1.f);
    axcopy(out, learners, Lr * D, 2.f);
    axcopy(out + Lr * D, courses, Cr * D, 1.f);
    hipMemsetAsync(buf1, 0, (size_t)(Ncg * D) * sizeof(float), stream);
    spmm(cg_rows, cg_cols, cg_vals, buf0, buf1, Ecg);
    normacc(buf1, out, Ncg);
    hipMemsetAsync(buf0, 0, (size_t)(Ncg * D) * sizeof(float), stream);
    spmm(cg_rows, cg_cols, cg_vals, buf1, buf0, Ecg);
    normacc(buf0, out, Ncg);
    axcopy(buf0, learners, Lr * D, 1.f);
    axcopy(buf0 + Lr * D, concepts, Kr * D, 1.f);
    axcopy(acck, concepts, Kr * D, 1.f);
    hipMemsetAsync(buf1, 0, (size_t)(Nkg * D) * sizeof(float), stream);
    spmm(kg_rows, kg_cols, kg_vals, buf0, buf1, Ekg);
    normacc(buf1, out, Lr);
    normacc(buf1 + Lr * D, acck, Kr);
    hipMemsetAsync(buf0, 0, (size_t)(Nkg * D) * sizeof(float), stream);
    spmm(kg_rows, kg_cols, kg_vals, buf1, buf0, Ekg);
    normacc(buf0, out, Lr);
    normacc(buf0 + Lr * D, acck, Kr);
    spmm(ca_rows, ca_cols, ca_vals, acck, out + Lr * D, Eca);
    return;
  }

  int*            binned = wsbase + o_share;
  unsigned short* g1     = (unsigned short*)(wsbase + o_share);  // disjoint lifetime
  unsigned short* g0     = (unsigned short*)(wsbase + o_g0);
  float* acck   = (float*)(wsbase + o_acck);
  int*   rp0    = wsbase + o_rp0;
  int*   rp1    = wsbase + o_rp1;
  int*   rp2    = wsbase + o_rp2;
  int*   cv0    = wsbase + o_cv0;
  int*   cv1    = wsbase + o_cv1;
  int*   cv2    = wsbase + o_cv2;
  int*   bkt    = wsbase + o_bkt;
  int*   cadeg  = wsbase + o_cadeg;
  float* scal   = (float*)(wsbase + o_scal);
  int*   part   = wsbase + o_part;
  int*   cacur  = wsbase + o_cacur;

  // ---- build ----
  hipMemsetAsync(bkt, 0, (size_t)(BKT_WORDS + ((Cr + 3) & ~3LL)) * sizeof(int), stream);
  bincnt_kernel<<<512, 1024, 0, stream>>>(cg_rows, cg_cols, EcgH, kg_rows, kg_cols, EkgH,
                                          ca_rows, Eca, bkt, cadeg,
                                          (int)Lr, NB0, s1cg, s1kg);
  bktscan_kernel<<<1, 256, 0, stream>>>(bkt, NBcg, NBkg);

  const int nbca = (int)((Cr + 1023) / 1024);
  ca_scan1_kernel<<<nbca, 256, 0, stream>>>(cadeg, rp2, scal + Ncg + Nkg, part, (int)Cr);
  ca_scan2_kernel<<<1, 256, 0, stream>>>(part, nbca);
  ca_scan3_kernel<<<nbca, 256, 0, stream>>>(rp2, part, cacur, (int)Cr, (int)Eca);

  {
    int blocks = (int)((EcgH + 256 * BCHUNK - 1) / (256 * BCHUNK));
    bin_kernel<<<blocks, 256, 0, stream>>>(cg_rows, cg_cols, EcgH, (int)Lr, s1cg, NB0, NBcg,
                                           bkt + BKT_CURCG, binned);
    fine2_kernel<<<NBcg, 1024, 0, stream>>>(binned, bkt + BKT_BASECG, rp0, cv0, scal,
                                            (int)Lr, (int)Ncg, s1cg, NB0, (int)Ncg);
  }
  {
    int blocks = (int)((EkgH + 256 * BCHUNK - 1) / (256 * BCHUNK));
    bin_kernel<<<blocks, 256, 0, stream>>>(kg_rows, kg_cols, EkgH, (int)Lr, s1kg, NB0, NBkg,
                                           bkt + BKT_CURKG, binned);
    fine2_kernel<<<NBkg, 1024, 0, stream>>>(binned, bkt + BKT_BASEKG, rp1, cv1, scal + Ncg,
                                            (int)Lr, (int)Nkg, s1kg, NB0, (int)Nkg);
  }
  scatter_ca_kernel<<<(int)((Eca + 255) / 256), 256, 0, stream>>>(ca_rows, ca_cols, cacur, cv2, Eca);

  // ---- bf16 sigma-scaled tables (after build: needs scal) ----
  cvt_all_kernel<<<4096, 256, 0, stream>>>(learners, courses, concepts, scal,
                                           g0, (int)Lr, (int)Ncg, (int)(Ncg + Nkg));

  const unsigned short* g0cg = g0;
  const unsigned short* g0kg = g0 + (long long)Ncg * D;
  const float* sig_cg = scal;
  const float* sig_kg = scal + Ncg;
  const float* inv_ca = scal + Ncg + Nkg;

  // ---- course-grained view ----
  {
    int blocks = (int)((Ncg + 3) / 4);
    // L1: out = feat0-init + unit(sraw); g1 = bf16(sigma^2 * sraw)
    pull4_kernel<0, 1, 1><<<blocks, 256, 0, stream>>>(
        rp0, cv0, g0cg, g1, sig_cg,
        out, out, (int)Ncg,
        learners, courses, (int)Lr, 2.0f, 1.0f, (int)Ncg);
    // L2: out += unit(sraw2)
    pull4_kernel<1, 0, 0><<<blocks, 256, 0, stream>>>(
        rp0, cv0, g1, nullptr, nullptr,
        out, out, (int)Ncg,
        nullptr, nullptr, 0, 0.f, 0.f, (int)Ncg);
  }

  // ---- concept-grained view ----
  {
    int blocks = (int)((Nkg + 3) / 4);
    // L1: learner rows out += unit; concept rows acck = concepts + unit; g1 = sigma^2*sraw
    pull4_kernel<0, 0, 1><<<blocks, 256, 0, stream>>>(
        rp1, cv1, g0kg, g1, sig_kg,
        out, acck, (int)Lr,
        nullptr, concepts, (int)Lr, 0.f, 1.0f, (int)Nkg);
    // L2: out += unit; acck += unit
    pull4_kernel<1, 0, 0><<<blocks, 256, 0, stream>>>(
        rp1, cv1, g1, nullptr, nullptr,
        out, acck, (int)Lr,
        nullptr, nullptr, 0, 0.f, 0.f, (int)Nkg);
  }

  // ---- aggregate concept features into course rows ----
  {
    int blocks = (int)((Cr + 3) / 4);
    pull_ca_kernel<<<blocks, 256, 0, stream>>>(rp2, cv2, inv_ca, acck,
                                               out + Lr * D, (int)Cr);
  }
}